// Round 1
// baseline (6148.798 us; speedup 1.0000x reference)
//
#include <hip/hip_runtime.h>
#include <hip/hip_bf16.h>
#include <math.h>

#define B_    4096
#define DIN_  512
#define DH_   1024
#define DOUT_ 256
#define DFF_  4096
#define STEPS_ 30
#define GAMMA_ 0.17677669529663687f
#define LN_EPS_ 1e-5f

typedef __attribute__((ext_vector_type(8))) short short8;
typedef __attribute__((ext_vector_type(4))) float f32x4;

__device__ inline void gload_lds16(const void* g, void* l) {
  __builtin_amdgcn_global_load_lds(
      (const __attribute__((address_space(1))) unsigned int*)g,
      (__attribute__((address_space(3))) unsigned int*)l, 16, 0, 0);
}

// ---------------------------------------------------------------------------
// m97-style bf16 GEMM: C[M,N] = A[M,K] * Bm[N,K]^T  (+bias, fused epilogues)
// epi: 0 = EMBED (write f32out=x_emb and f32out2=h)
//      1 = TANH  (write bf16out = bf16(tanh(v)))
//      2 = RESID (f32out=h updated in place: (1-g)*h + g*(v + resid_add))
//      3 = PLAIN (write f32out)
// ---------------------------------------------------------------------------
__global__ __launch_bounds__(256) void gemm_bt(
    const __hip_bfloat16* __restrict__ A, const __hip_bfloat16* __restrict__ Bm,
    int M, int N, int K, const float* __restrict__ bias, int epi,
    float* __restrict__ f32out, float* __restrict__ f32out2,
    const float* __restrict__ resid_add, __hip_bfloat16* __restrict__ bf16out) {
  __shared__ __align__(16) short As[128 * 32];
  __shared__ __align__(16) short Bs[128 * 32];
  const int tid = threadIdx.x;
  const int lane = tid & 63;
  const int wid = tid >> 6;
  const int wr = wid >> 1, wc = wid & 1;
  const int m0 = blockIdx.y * 128, n0 = blockIdx.x * 128;
  const int ldsrow = lane >> 2;      // 0..15 within a 16-row segment
  const int col8 = (lane & 3) * 8;   // k offset 0/8/16/24

  f32x4 acc[4][4];
  const f32x4 zero = {0.f, 0.f, 0.f, 0.f};
#pragma unroll
  for (int i = 0; i < 4; ++i)
#pragma unroll
    for (int j = 0; j < 4; ++j) acc[i][j] = zero;

  for (int kt = 0; kt < K; kt += 32) {
#pragma unroll
    for (int i = 0; i < 2; ++i) {
      const int seg = wid * 2 + i;  // wave-uniform 0..7
      gload_lds16(A + (size_t)(m0 + seg * 16 + ldsrow) * K + kt + col8,
                  (void*)(As + seg * 512));
      gload_lds16(Bm + (size_t)(n0 + seg * 16 + ldsrow) * K + kt + col8,
                  (void*)(Bs + seg * 512));
    }
    __syncthreads();
    short8 a[4], b[4];
#pragma unroll
    for (int mf = 0; mf < 4; ++mf)
      a[mf] = *(const short8*)&As[(wr * 64 + mf * 16 + (lane & 15)) * 32 + (lane >> 4) * 8];
#pragma unroll
    for (int nf = 0; nf < 4; ++nf)
      b[nf] = *(const short8*)&Bs[(wc * 64 + nf * 16 + (lane & 15)) * 32 + (lane >> 4) * 8];
#pragma unroll
    for (int mf = 0; mf < 4; ++mf)
#pragma unroll
      for (int nf = 0; nf < 4; ++nf)
        acc[mf][nf] = __builtin_amdgcn_mfma_f32_16x16x32_bf16(a[mf], b[nf], acc[mf][nf], 0, 0, 0);
    __syncthreads();
  }

  const int rbase = (lane >> 4) * 4;
  const int cin = lane & 15;
#pragma unroll
  for (int mf = 0; mf < 4; ++mf) {
#pragma unroll
    for (int nf = 0; nf < 4; ++nf) {
      const int col = n0 + wc * 64 + nf * 16 + cin;
      const float bv = bias[col];
#pragma unroll
      for (int j = 0; j < 4; ++j) {
        const int row = m0 + wr * 64 + mf * 16 + rbase + j;
        const float v = acc[mf][nf][j] + bv;
        const size_t idx = (size_t)row * N + col;
        if (epi == 0) {
          f32out[idx] = v;
          f32out2[idx] = v;
        } else if (epi == 1) {
          bf16out[idx] = __float2bfloat16(tanhf(v));
        } else if (epi == 2) {
          const float hv = f32out[idx];
          f32out[idx] = (1.f - GAMMA_) * hv + GAMMA_ * (v + resid_add[idx]);
        } else {
          f32out[idx] = v;
        }
      }
    }
  }
}

// ---------------------------------------------------------------------------
// LayerNorm over DH=1024 + cast to bf16. One block (256 thr) per row.
// ---------------------------------------------------------------------------
__global__ __launch_bounds__(256) void ln_cast_kernel(
    const float* __restrict__ h, const float* __restrict__ g,
    const float* __restrict__ be, __hip_bfloat16* __restrict__ hn) {
  const int row = blockIdx.x;
  const int tid = threadIdx.x;
  const float4 v = ((const float4*)(h + (size_t)row * DH_))[tid];
  float s = v.x + v.y + v.z + v.w;
  float ss = v.x * v.x + v.y * v.y + v.z * v.z + v.w * v.w;
#pragma unroll
  for (int o = 32; o > 0; o >>= 1) {
    s += __shfl_down(s, o, 64);
    ss += __shfl_down(ss, o, 64);
  }
  __shared__ float rs_[4], rss_[4];
  const int lane = tid & 63, wid = tid >> 6;
  if (lane == 0) { rs_[wid] = s; rss_[wid] = ss; }
  __syncthreads();
  const float tot = rs_[0] + rs_[1] + rs_[2] + rs_[3];
  const float tots = rss_[0] + rss_[1] + rss_[2] + rss_[3];
  const float mu = tot * (1.f / DH_);
  const float var = tots * (1.f / DH_) - mu * mu;
  const float rstd = rsqrtf(var + LN_EPS_);
  const float4 gv = ((const float4*)g)[tid];
  const float4 bv = ((const float4*)be)[tid];
  __hip_bfloat16* out = hn + (size_t)row * DH_ + tid * 4;
  out[0] = __float2bfloat16((v.x - mu) * rstd * gv.x + bv.x);
  out[1] = __float2bfloat16((v.y - mu) * rstd * gv.y + bv.y);
  out[2] = __float2bfloat16((v.z - mu) * rstd * gv.z + bv.z);
  out[3] = __float2bfloat16((v.w - mu) * rstd * gv.w + bv.w);
}

// ---------------------------------------------------------------------------
// fp32 matvec y = W x, wave per row (W row-major [rows][cols], cols % 256 == 0)
// ---------------------------------------------------------------------------
__global__ __launch_bounds__(256) void matvec_kernel(
    const float* __restrict__ W, const float* __restrict__ x,
    float* __restrict__ y, int rows, int cols) {
  const int gw = (int)(blockIdx.x * 256 + threadIdx.x) >> 6;
  const int lane = threadIdx.x & 63;
  if (gw >= rows) return;
  const float4* wr = (const float4*)(W + (size_t)gw * cols);
  const float4* xv = (const float4*)x;
  const int n4 = cols >> 2;
  float s = 0.f;
  for (int c = lane; c < n4; c += 64) {
    const float4 wv = wr[c];
    const float4 vv = xv[c];
    s += wv.x * vv.x + wv.y * vv.y + wv.z * vv.z + wv.w * vv.w;
  }
#pragma unroll
  for (int o = 32; o > 0; o >>= 1) s += __shfl_down(s, o, 64);
  if (lane == 0) y[gw] = s;
}

__global__ __launch_bounds__(256) void transpose_kernel(
    const float* __restrict__ in, float* __restrict__ out, int R, int C) {
  __shared__ float t[32][33];
  const int lx = threadIdx.x & 31, ly = threadIdx.x >> 5;  // ly 0..7
  const int r0 = blockIdx.y * 32, c0 = blockIdx.x * 32;
#pragma unroll
  for (int j = 0; j < 32; j += 8) t[ly + j][lx] = in[(size_t)(r0 + ly + j) * C + c0 + lx];
  __syncthreads();
#pragma unroll
  for (int j = 0; j < 32; j += 8) out[(size_t)(c0 + ly + j) * R + r0 + lx] = t[lx][ly + j];
}

__global__ void init_v_kernel(float* v1, float* v2) {
  const int i = blockIdx.x * 256 + threadIdx.x;
  if (i < 1024) v1[i] = 0.03125f;    // 1/sqrt(1024)
  if (i < 4096) v2[i] = 0.015625f;   // 1/sqrt(4096)
}

__global__ __launch_bounds__(256) void cast_kernel(
    const float* __restrict__ s, __hip_bfloat16* __restrict__ d, int n) {
  const int b = (blockIdx.x * 256 + threadIdx.x) * 4;
  if (b < n) {
    const float4 v = *(const float4*)(s + b);
    d[b] = __float2bfloat16(v.x);
    d[b + 1] = __float2bfloat16(v.y);
    d[b + 2] = __float2bfloat16(v.z);
    d[b + 3] = __float2bfloat16(v.w);
  }
}

__global__ __launch_bounds__(256) void cast_scaled_kernel(
    const float* __restrict__ s, __hip_bfloat16* __restrict__ d, int n,
    const float* __restrict__ rs) {
  const float r = rs[0];
  const int b = (blockIdx.x * 256 + threadIdx.x) * 4;
  if (b < n) {
    const float4 v = *(const float4*)(s + b);
    d[b] = __float2bfloat16(v.x * r);
    d[b + 1] = __float2bfloat16(v.y * r);
    d[b + 2] = __float2bfloat16(v.z * r);
    d[b + 3] = __float2bfloat16(v.w * r);
  }
}

// rs = |c| / |d|  (= 1/sigma)
__global__ __launch_bounds__(256) void sigma_rs_kernel(
    const float* __restrict__ c, int m, const float* __restrict__ dv, int n,
    float* __restrict__ rs) {
  const int tid = threadIdx.x;
  float sc = 0.f, sd = 0.f;
  for (int i = tid; i < m; i += 256) { const float v = c[i]; sc += v * v; }
  for (int i = tid; i < n; i += 256) { const float v = dv[i]; sd += v * v; }
#pragma unroll
  for (int o = 32; o > 0; o >>= 1) {
    sc += __shfl_down(sc, o, 64);
    sd += __shfl_down(sd, o, 64);
  }
  __shared__ float a[4], b[4];
  const int lane = tid & 63, wid = tid >> 6;
  if (lane == 0) { a[wid] = sc; b[wid] = sd; }
  __syncthreads();
  if (tid == 0) {
    const float tc = a[0] + a[1] + a[2] + a[3];
    const float td = b[0] + b[1] + b[2] + b[3];
    rs[0] = sqrtf(tc / td);
  }
}

extern "C" void kernel_launch(void* const* d_in, const int* in_sizes, int n_in,
                              void* d_out, int out_size, void* d_ws, size_t ws_size,
                              hipStream_t stream) {
  const float* x       = (const float*)d_in[0];
  const float* embed_w = (const float*)d_in[1];
  const float* embed_b = (const float*)d_in[2];
  const float* W1      = (const float*)d_in[3];
  const float* b1      = (const float*)d_in[4];
  const float* W2      = (const float*)d_in[5];
  const float* b2      = (const float*)d_in[6];
  const float* ln_g    = (const float*)d_in[7];
  const float* ln_b    = (const float*)d_in[8];
  const float* head_w  = (const float*)d_in[9];
  const float* head_b  = (const float*)d_in[10];
  float* out = (float*)d_out;

  char* p = (char*)d_ws;
  auto carve = [&](size_t bytes) {
    char* r = p;
    p += (bytes + 255) & ~(size_t)255;
    return (void*)r;
  };
  float* h     = (float*)carve((size_t)B_ * DH_ * 4);
  float* x_emb = (float*)carve((size_t)B_ * DH_ * 4);
  float* W1T   = (float*)carve((size_t)DFF_ * DH_ * 4);
  float* W2T   = (float*)carve((size_t)DH_ * DFF_ * 4);
  __hip_bfloat16* hn   = (__hip_bfloat16*)carve((size_t)B_ * DH_ * 2);
  __hip_bfloat16* hid  = (__hip_bfloat16*)carve((size_t)B_ * DFF_ * 2);
  __hip_bfloat16* W1n  = (__hip_bfloat16*)carve((size_t)DFF_ * DH_ * 2);
  __hip_bfloat16* W2n  = (__hip_bfloat16*)carve((size_t)DH_ * DFF_ * 2);
  __hip_bfloat16* xbf  = (__hip_bfloat16*)carve((size_t)B_ * DIN_ * 2);
  __hip_bfloat16* ewbf = (__hip_bfloat16*)carve((size_t)DH_ * DIN_ * 2);
  __hip_bfloat16* hwbf = (__hip_bfloat16*)carve((size_t)DOUT_ * DH_ * 2);
  __hip_bfloat16* hbf  = (__hip_bfloat16*)carve((size_t)B_ * DH_ * 2);
  float* v1a = (float*)carve(4096 * 4);
  float* v1b = (float*)carve(4096 * 4);
  float* c1  = (float*)carve(4096 * 4);
  float* v2a = (float*)carve(4096 * 4);
  float* v2b = (float*)carve(4096 * 4);
  float* c2  = (float*)carve(4096 * 4);
  float* rs1 = (float*)carve(256);
  float* rs2 = (float*)carve(256);

  // --- transposes + init + input casts (independent prep) ---
  transpose_kernel<<<dim3(DH_ / 32, DFF_ / 32), 256, 0, stream>>>(W1, W1T, DFF_, DH_);
  transpose_kernel<<<dim3(DFF_ / 32, DH_ / 32), 256, 0, stream>>>(W2, W2T, DH_, DFF_);
  init_v_kernel<<<16, 256, 0, stream>>>(v1a, v2a);
  cast_kernel<<<(B_ * DIN_ / 4) / 256, 256, 0, stream>>>(x, xbf, B_ * DIN_);
  cast_kernel<<<(DH_ * DIN_ / 4) / 256, 256, 0, stream>>>(embed_w, ewbf, DH_ * DIN_);
  cast_kernel<<<(DOUT_ * DH_ / 4) / 256, 256, 0, stream>>>(head_w, hwbf, DOUT_ * DH_);

  // --- x_emb = x @ embed_w^T + embed_b ; h = x_emb ---
  gemm_bt<<<dim3(DH_ / 128, B_ / 128), 256, 0, stream>>>(
      xbf, ewbf, B_, DH_, DIN_, embed_b, 0, x_emb, h, nullptr, nullptr);

  // --- power iteration (unnormalized): 15x (c = W v; v' = W^T c) ---
  for (int it = 0; it < 15; ++it) {
    const float* vin1 = (it & 1) ? v1b : v1a;
    float* vout1 = (it & 1) ? v1a : v1b;
    matvec_kernel<<<(DFF_ * 64) / 256, 256, 0, stream>>>(W1, vin1, c1, DFF_, DH_);
    matvec_kernel<<<(DH_ * 64) / 256, 256, 0, stream>>>(W1T, c1, vout1, DH_, DFF_);
    const float* vin2 = (it & 1) ? v2b : v2a;
    float* vout2 = (it & 1) ? v2a : v2b;
    matvec_kernel<<<(DH_ * 64) / 256, 256, 0, stream>>>(W2, vin2, c2, DH_, DFF_);
    matvec_kernel<<<(DFF_ * 64) / 256, 256, 0, stream>>>(W2T, c2, vout2, DFF_, DH_);
  }
  // after 15 iterations: c holds W v14, v*b holds W^T W v14 -> sigma = |d|/|c|
  sigma_rs_kernel<<<1, 256, 0, stream>>>(c1, DFF_, v1b, DH_, rs1);
  sigma_rs_kernel<<<1, 256, 0, stream>>>(c2, DH_, v2b, DFF_, rs2);
  cast_scaled_kernel<<<(DFF_ * DH_ / 4) / 256, 256, 0, stream>>>(W1, W1n, DFF_ * DH_, rs1);
  cast_scaled_kernel<<<(DH_ * DFF_ / 4) / 256, 256, 0, stream>>>(W2, W2n, DH_ * DFF_, rs2);

  // --- 30 equilibrium steps ---
  for (int s = 0; s < STEPS_; ++s) {
    ln_cast_kernel<<<B_, 256, 0, stream>>>(h, ln_g, ln_b, hn);
    gemm_bt<<<dim3(DFF_ / 128, B_ / 128), 256, 0, stream>>>(
        hn, W1n, B_, DFF_, DH_, b1, 1, nullptr, nullptr, nullptr, hid);
    gemm_bt<<<dim3(DH_ / 128, B_ / 128), 256, 0, stream>>>(
        hid, W2n, B_, DH_, DFF_, b2, 2, h, nullptr, x_emb, nullptr);
  }

  // --- head ---
  cast_kernel<<<(B_ * DH_ / 4) / 256, 256, 0, stream>>>(h, hbf, B_ * DH_);
  gemm_bt<<<dim3(DOUT_ / 128, B_ / 128), 256, 0, stream>>>(
      hbf, hwbf, B_, DOUT_, DH_, head_b, 3, out, nullptr, nullptr, nullptr);
}

// Round 3
// 4880.395 us; speedup vs baseline: 1.2599x; 1.2599x over previous
//
#include <hip/hip_runtime.h>
#include <hip/hip_bf16.h>
#include <math.h>

#define B_    4096
#define DIN_  512
#define DH_   1024
#define DOUT_ 256
#define DFF_  4096
#define STEPS_ 30
#define GAMMA_ 0.17677669529663687f
#define LN_EPS_ 1e-5f

typedef __attribute__((ext_vector_type(8))) short short8;
typedef __attribute__((ext_vector_type(4))) float f32x4;

__device__ inline void gload_lds16(const void* g, void* l) {
  __builtin_amdgcn_global_load_lds(
      (const __attribute__((address_space(1))) unsigned int*)g,
      (__attribute__((address_space(3))) unsigned int*)l, 16, 0, 0);
}

__device__ inline float fast_tanh(float v) {
  // tanh(v) = 1 - 2/(exp(2v)+1).  exp overflow -> inf -> rcp -> 0 -> +1; v<<0 -> -1.
  const float e = __expf(2.f * v);
  return 1.f - 2.f * __builtin_amdgcn_rcpf(e + 1.f);
}

// ---------------------------------------------------------------------------
// m97-style bf16 GEMM: C[M,N] = A[M,K] * Bm[N,K]^T  (+optional bias, epilogues)
// epi: 0 = EMBED  (write f32out=x_emb and f32out2=h)
//      1 = TANH   (write bf16out = bf16(fast_tanh(v)))
//      3 = PLAIN  (write f32out)
//      4 = PARTIAL(write f32out + blockIdx.z*M*N, no bias)
// K-split: blockIdx.z selects K-chunk [z*kc, z*kc+kc); lda = full K stride.
// ---------------------------------------------------------------------------
__global__ __launch_bounds__(256) void gemm_bt(
    const __hip_bfloat16* __restrict__ A, const __hip_bfloat16* __restrict__ Bm,
    int M, int N, int K, int kc, const float* __restrict__ bias, int epi,
    float* __restrict__ f32out, float* __restrict__ f32out2,
    __hip_bfloat16* __restrict__ bf16out) {
  __shared__ __align__(16) short As[128 * 32];
  __shared__ __align__(16) short Bs[128 * 32];
  const int tid = threadIdx.x;
  const int lane = tid & 63;
  const int wid = tid >> 6;
  const int wr = wid >> 1, wc = wid & 1;

  // XCD-aware swizzle over the x-y plane (all grids have nwg % 8 == 0)
  const int gx = gridDim.x;
  const int nwg = gx * gridDim.y;
  const int wg = blockIdx.y * gx + blockIdx.x;
  const int cpx = nwg >> 3;
  const int swz = (wg & 7) * cpx + (wg >> 3);
  const int bx = swz % gx, by = swz / gx;

  const int z = blockIdx.z;
  const int m0 = by * 128, n0 = bx * 128;
  const int ldsrow = lane >> 2;
  const int col8 = (lane & 3) * 8;
  const int k0 = z * kc, k1 = z * kc + kc;

  f32x4 acc[4][4];
  const f32x4 zero = {0.f, 0.f, 0.f, 0.f};
#pragma unroll
  for (int i = 0; i < 4; ++i)
#pragma unroll
    for (int j = 0; j < 4; ++j) acc[i][j] = zero;

  for (int kt = k0; kt < k1; kt += 32) {
#pragma unroll
    for (int i = 0; i < 2; ++i) {
      const int seg = wid * 2 + i;  // wave-uniform 0..7
      gload_lds16(A + (size_t)(m0 + seg * 16 + ldsrow) * K + kt + col8,
                  (void*)(As + seg * 512));
      gload_lds16(Bm + (size_t)(n0 + seg * 16 + ldsrow) * K + kt + col8,
                  (void*)(Bs + seg * 512));
    }
    __syncthreads();
    short8 a[4], b[4];
#pragma unroll
    for (int mf = 0; mf < 4; ++mf)
      a[mf] = *(const short8*)&As[(wr * 64 + mf * 16 + (lane & 15)) * 32 + (lane >> 4) * 8];
#pragma unroll
    for (int nf = 0; nf < 4; ++nf)
      b[nf] = *(const short8*)&Bs[(wc * 64 + nf * 16 + (lane & 15)) * 32 + (lane >> 4) * 8];
#pragma unroll
    for (int mf = 0; mf < 4; ++mf)
#pragma unroll
      for (int nf = 0; nf < 4; ++nf)
        acc[mf][nf] = __builtin_amdgcn_mfma_f32_16x16x32_bf16(a[mf], b[nf], acc[mf][nf], 0, 0, 0);
    __syncthreads();
  }

  if (epi == 4) f32out += (size_t)z * M * N;
  const int rbase = (lane >> 4) * 4;
  const int cin = lane & 15;
#pragma unroll
  for (int mf = 0; mf < 4; ++mf) {
#pragma unroll
    for (int nf = 0; nf < 4; ++nf) {
      const int col = n0 + wc * 64 + nf * 16 + cin;
      const float bv = (epi == 4) ? 0.f : bias[col];
#pragma unroll
      for (int j = 0; j < 4; ++j) {
        const int row = m0 + wr * 64 + mf * 16 + rbase + j;
        const float v = acc[mf][nf][j] + bv;
        const size_t idx = (size_t)row * N + col;
        if (epi == 0) {
          f32out[idx] = v;
          f32out2[idx] = v;
        } else if (epi == 1) {
          bf16out[idx] = __float2bfloat16(fast_tanh(v));
        } else {
          f32out[idx] = v;
        }
      }
    }
  }
}

// ---------------------------------------------------------------------------
// Fused: h = (1-g)h + g*(ps0+ps1+b2+x_emb); then LN+cast->outbf (do_ln)
// or plain bf16 cast of new h (last step, feeds head GEMM).
// One block (256 thr) per row of 1024.
// ---------------------------------------------------------------------------
__global__ __launch_bounds__(256) void reduce_ln_kernel(
    const float* __restrict__ ps, const float* __restrict__ b2,
    const float* __restrict__ xe, float* __restrict__ h,
    const float* __restrict__ g, const float* __restrict__ be,
    __hip_bfloat16* __restrict__ outbf, int do_ln) {
  const int row = blockIdx.x, tid = threadIdx.x;
  const size_t base = (size_t)row * DH_;
  const size_t slab = (size_t)B_ * DH_;
  const float4 p0 = ((const float4*)(ps + base))[tid];
  const float4 p1 = ((const float4*)(ps + slab + base))[tid];
  const float4 xv = ((const float4*)(xe + base))[tid];
  const float4 hv = ((const float4*)(h + base))[tid];
  const float4 bv = ((const float4*)b2)[tid];
  float4 nv;
  nv.x = (1.f - GAMMA_) * hv.x + GAMMA_ * (p0.x + p1.x + bv.x + xv.x);
  nv.y = (1.f - GAMMA_) * hv.y + GAMMA_ * (p0.y + p1.y + bv.y + xv.y);
  nv.z = (1.f - GAMMA_) * hv.z + GAMMA_ * (p0.z + p1.z + bv.z + xv.z);
  nv.w = (1.f - GAMMA_) * hv.w + GAMMA_ * (p0.w + p1.w + bv.w + xv.w);
  ((float4*)(h + base))[tid] = nv;

  __hip_bfloat16* out = outbf + base + tid * 4;
  if (!do_ln) {
    out[0] = __float2bfloat16(nv.x);
    out[1] = __float2bfloat16(nv.y);
    out[2] = __float2bfloat16(nv.z);
    out[3] = __float2bfloat16(nv.w);
    return;
  }
  float s = nv.x + nv.y + nv.z + nv.w;
  float ss = nv.x * nv.x + nv.y * nv.y + nv.z * nv.z + nv.w * nv.w;
#pragma unroll
  for (int o = 32; o > 0; o >>= 1) {
    s += __shfl_down(s, o, 64);
    ss += __shfl_down(ss, o, 64);
  }
  __shared__ float rs_[4], rss_[4];
  const int lane = tid & 63, wid = tid >> 6;
  if (lane == 0) { rs_[wid] = s; rss_[wid] = ss; }
  __syncthreads();
  const float tot = rs_[0] + rs_[1] + rs_[2] + rs_[3];
  const float tots = rss_[0] + rss_[1] + rss_[2] + rss_[3];
  const float mu = tot * (1.f / DH_);
  const float var = tots * (1.f / DH_) - mu * mu;
  const float rstd = rsqrtf(var + LN_EPS_);
  const float4 gv = ((const float4*)g)[tid];
  const float4 bev = ((const float4*)be)[tid];
  out[0] = __float2bfloat16((nv.x - mu) * rstd * gv.x + bev.x);
  out[1] = __float2bfloat16((nv.y - mu) * rstd * gv.y + bev.y);
  out[2] = __float2bfloat16((nv.z - mu) * rstd * gv.z + bev.z);
  out[3] = __float2bfloat16((nv.w - mu) * rstd * gv.w + bev.w);
}

// ---------------------------------------------------------------------------
// LayerNorm over DH=1024 + cast to bf16 (step 0 only). Block per row.
// ---------------------------------------------------------------------------
__global__ __launch_bounds__(256) void ln_cast_kernel(
    const float* __restrict__ h, const float* __restrict__ g,
    const float* __restrict__ be, __hip_bfloat16* __restrict__ hn) {
  const int row = blockIdx.x;
  const int tid = threadIdx.x;
  const float4 v = ((const float4*)(h + (size_t)row * DH_))[tid];
  float s = v.x + v.y + v.z + v.w;
  float ss = v.x * v.x + v.y * v.y + v.z * v.z + v.w * v.w;
#pragma unroll
  for (int o = 32; o > 0; o >>= 1) {
    s += __shfl_down(s, o, 64);
    ss += __shfl_down(ss, o, 64);
  }
  __shared__ float rs_[4], rss_[4];
  const int lane = tid & 63, wid = tid >> 6;
  if (lane == 0) { rs_[wid] = s; rss_[wid] = ss; }
  __syncthreads();
  const float tot = rs_[0] + rs_[1] + rs_[2] + rs_[3];
  const float tots = rss_[0] + rss_[1] + rss_[2] + rss_[3];
  const float mu = tot * (1.f / DH_);
  const float var = tots * (1.f / DH_) - mu * mu;
  const float rstd = rsqrtf(var + LN_EPS_);
  const float4 gv = ((const float4*)g)[tid];
  const float4 bv = ((const float4*)be)[tid];
  __hip_bfloat16* out = hn + (size_t)row * DH_ + tid * 4;
  out[0] = __float2bfloat16((v.x - mu) * rstd * gv.x + bv.x);
  out[1] = __float2bfloat16((v.y - mu) * rstd * gv.y + bv.y);
  out[2] = __float2bfloat16((v.z - mu) * rstd * gv.z + bv.z);
  out[3] = __float2bfloat16((v.w - mu) * rstd * gv.w + bv.w);
}

// ---------------------------------------------------------------------------
// Paired fp32 matvec: ya = Wa xa (rowsA x colsA), yb = Wb xb — one dispatch.
// Wave per row; cols % 256 == 0.
// ---------------------------------------------------------------------------
__global__ __launch_bounds__(256) void matvec2_kernel(
    const float* __restrict__ Wa, const float* __restrict__ xa,
    float* __restrict__ ya, int rowsA, int colsA,
    const float* __restrict__ Wb, const float* __restrict__ xb,
    float* __restrict__ yb, int rowsB, int colsB) {
  const int gw = (int)(blockIdx.x * 256 + threadIdx.x) >> 6;
  const int lane = threadIdx.x & 63;
  const float* W;
  const float* x;
  float* y;
  int row, cols;
  if (gw < rowsA) {
    W = Wa; x = xa; y = ya; row = gw; cols = colsA;
  } else {
    row = gw - rowsA;
    if (row >= rowsB) return;
    W = Wb; x = xb; y = yb; cols = colsB;
  }
  const float4* wr = (const float4*)(W + (size_t)row * cols);
  const float4* xv = (const float4*)x;
  const int n4 = cols >> 2;
  float s = 0.f;
  for (int c = lane; c < n4; c += 64) {
    const float4 wv = wr[c];
    const float4 vv = xv[c];
    s += wv.x * vv.x + wv.y * vv.y + wv.z * vv.z + wv.w * vv.w;
  }
#pragma unroll
  for (int o = 32; o > 0; o >>= 1) s += __shfl_down(s, o, 64);
  if (lane == 0) y[row] = s;
}

__global__ __launch_bounds__(256) void transpose_kernel(
    const float* __restrict__ in, float* __restrict__ out, int R, int C) {
  __shared__ float t[32][33];
  const int lx = threadIdx.x & 31, ly = threadIdx.x >> 5;
  const int r0 = blockIdx.y * 32, c0 = blockIdx.x * 32;
#pragma unroll
  for (int j = 0; j < 32; j += 8) t[ly + j][lx] = in[(size_t)(r0 + ly + j) * C + c0 + lx];
  __syncthreads();
#pragma unroll
  for (int j = 0; j < 32; j += 8) out[(size_t)(c0 + ly + j) * R + r0 + lx] = t[lx][ly + j];
}

__global__ void init_v_kernel(float* v1, float* v2) {
  const int i = blockIdx.x * 256 + threadIdx.x;
  if (i < 1024) v1[i] = 0.03125f;
  if (i < 4096) v2[i] = 0.015625f;
}

__global__ __launch_bounds__(256) void cast_kernel(
    const float* __restrict__ s, __hip_bfloat16* __restrict__ d, int n) {
  const int b = (blockIdx.x * 256 + threadIdx.x) * 4;
  if (b < n) {
    const float4 v = *(const float4*)(s + b);
    d[b] = __float2bfloat16(v.x);
    d[b + 1] = __float2bfloat16(v.y);
    d[b + 2] = __float2bfloat16(v.z);
    d[b + 3] = __float2bfloat16(v.w);
  }
}

__global__ __launch_bounds__(256) void cast_scaled_kernel(
    const float* __restrict__ s, __hip_bfloat16* __restrict__ d, int n,
    const float* __restrict__ rs) {
  const float r = rs[0];
  const int b = (blockIdx.x * 256 + threadIdx.x) * 4;
  if (b < n) {
    const float4 v = *(const float4*)(s + b);
    d[b] = __float2bfloat16(v.x * r);
    d[b + 1] = __float2bfloat16(v.y * r);
    d[b + 2] = __float2bfloat16(v.z * r);
    d[b + 3] = __float2bfloat16(v.w * r);
  }
}

// rs = |c| / |d|  (= 1/sigma)
__global__ __launch_bounds__(256) void sigma_rs_kernel(
    const float* __restrict__ c, int m, const float* __restrict__ dv, int n,
    float* __restrict__ rs) {
  const int tid = threadIdx.x;
  float sc = 0.f, sd = 0.f;
  for (int i = tid; i < m; i += 256) { const float v = c[i]; sc += v * v; }
  for (int i = tid; i < n; i += 256) { const float v = dv[i]; sd += v * v; }
#pragma unroll
  for (int o = 32; o > 0; o >>= 1) {
    sc += __shfl_down(sc, o, 64);
    sd += __shfl_down(sd, o, 64);
  }
  __shared__ float a[4], b[4];
  const int lane = tid & 63, wid = tid >> 6;
  if (lane == 0) { a[wid] = sc; b[wid] = sd; }
  __syncthreads();
  if (tid == 0) {
    const float tc = a[0] + a[1] + a[2] + a[3];
    const float td = b[0] + b[1] + b[2] + b[3];
    rs[0] = sqrtf(tc / td);
  }
}

extern "C" void kernel_launch(void* const* d_in, const int* in_sizes, int n_in,
                              void* d_out, int out_size, void* d_ws, size_t ws_size,
                              hipStream_t stream) {
  const float* x       = (const float*)d_in[0];
  const float* embed_w = (const float*)d_in[1];
  const float* embed_b = (const float*)d_in[2];
  const float* W1      = (const float*)d_in[3];
  const float* b1      = (const float*)d_in[4];
  const float* W2      = (const float*)d_in[5];
  const float* b2      = (const float*)d_in[6];
  const float* ln_g    = (const float*)d_in[7];
  const float* ln_b    = (const float*)d_in[8];
  const float* head_w  = (const float*)d_in[9];
  const float* head_b  = (const float*)d_in[10];
  float* out = (float*)d_out;

  char* p = (char*)d_ws;
  auto carve = [&](size_t bytes) {
    char* r = p;
    p += (bytes + 255) & ~(size_t)255;
    return (void*)r;
  };
  float* h     = (float*)carve((size_t)B_ * DH_ * 4);
  float* x_emb = (float*)carve((size_t)B_ * DH_ * 4);
  // W1T/W2T are dead after the power iteration; the two K-split partial slabs
  // (each B_*DH_ fp32 = 16.8 MB, contiguous) alias this region during steps.
  float* W1T   = (float*)carve((size_t)DFF_ * DH_ * 4);
  float* W2T   = (float*)carve((size_t)DH_ * DFF_ * 4);
  float* ps    = W1T;  // [2][B_][DH_] fp32
  __hip_bfloat16* hn   = (__hip_bfloat16*)carve((size_t)B_ * DH_ * 2);
  __hip_bfloat16* hid  = (__hip_bfloat16*)carve((size_t)B_ * DFF_ * 2);
  __hip_bfloat16* W1n  = (__hip_bfloat16*)carve((size_t)DFF_ * DH_ * 2);
  __hip_bfloat16* W2n  = (__hip_bfloat16*)carve((size_t)DH_ * DFF_ * 2);
  __hip_bfloat16* xbf  = (__hip_bfloat16*)carve((size_t)B_ * DIN_ * 2);
  __hip_bfloat16* ewbf = (__hip_bfloat16*)carve((size_t)DH_ * DIN_ * 2);
  __hip_bfloat16* hwbf = (__hip_bfloat16*)carve((size_t)DOUT_ * DH_ * 2);
  __hip_bfloat16* hbf  = (__hip_bfloat16*)carve((size_t)B_ * DH_ * 2);
  float* v1a = (float*)carve(4096 * 4);
  float* v1b = (float*)carve(4096 * 4);
  float* c1  = (float*)carve(4096 * 4);
  float* v2a = (float*)carve(4096 * 4);
  float* v2b = (float*)carve(4096 * 4);
  float* c2  = (float*)carve(4096 * 4);
  float* rs1 = (float*)carve(256);
  float* rs2 = (float*)carve(256);

  // --- prep: transposes, inits, input casts ---
  transpose_kernel<<<dim3(DH_ / 32, DFF_ / 32), 256, 0, stream>>>(W1, W1T, DFF_, DH_);
  transpose_kernel<<<dim3(DFF_ / 32, DH_ / 32), 256, 0, stream>>>(W2, W2T, DH_, DFF_);
  init_v_kernel<<<16, 256, 0, stream>>>(v1a, v2a);
  cast_kernel<<<(B_ * DIN_ / 4) / 256, 256, 0, stream>>>(x, xbf, B_ * DIN_);
  cast_kernel<<<(DH_ * DIN_ / 4) / 256, 256, 0, stream>>>(embed_w, ewbf, DH_ * DIN_);
  cast_kernel<<<(DOUT_ * DH_ / 4) / 256, 256, 0, stream>>>(head_w, hwbf, DOUT_ * DH_);

  // --- x_emb = x @ embed_w^T + embed_b ; h = x_emb ---
  gemm_bt<<<dim3(DH_ / 128, B_ / 128), 256, 0, stream>>>(
      xbf, ewbf, B_, DH_, DIN_, DIN_, embed_b, 0, x_emb, h, nullptr);

  // --- power iteration (unnormalized): 15x (c = W v; v' = W^T c), W1 & W2 paired ---
  for (int it = 0; it < 15; ++it) {
    const float* vin1 = (it & 1) ? v1b : v1a;
    float* vout1 = (it & 1) ? v1a : v1b;
    const float* vin2 = (it & 1) ? v2b : v2a;
    float* vout2 = (it & 1) ? v2a : v2b;
    matvec2_kernel<<<((DFF_ + DH_) * 64) / 256, 256, 0, stream>>>(
        W1, vin1, c1, DFF_, DH_, W2, vin2, c2, DH_, DFF_);
    matvec2_kernel<<<((DH_ + DFF_) * 64) / 256, 256, 0, stream>>>(
        W1T, c1, vout1, DH_, DFF_, W2T, c2, vout2, DFF_, DH_);
  }
  sigma_rs_kernel<<<1, 256, 0, stream>>>(c1, DFF_, v1b, DH_, rs1);
  sigma_rs_kernel<<<1, 256, 0, stream>>>(c2, DH_, v2b, DFF_, rs2);
  cast_scaled_kernel<<<(DFF_ * DH_ / 4) / 256, 256, 0, stream>>>(W1, W1n, DFF_ * DH_, rs1);
  cast_scaled_kernel<<<(DH_ * DFF_ / 4) / 256, 256, 0, stream>>>(W2, W2n, DH_ * DFF_, rs2);
  // (W1T/W2T dead from here; ps aliases them)

  // --- step 0 LN (h == x_emb) ---
  ln_cast_kernel<<<B_, 256, 0, stream>>>(h, ln_g, ln_b, hn);

  // --- 30 equilibrium steps ---
  for (int s = 0; s < STEPS_; ++s) {
    gemm_bt<<<dim3(DFF_ / 128, B_ / 128), 256, 0, stream>>>(
        hn, W1n, B_, DFF_, DH_, DH_, b1, 1, nullptr, nullptr, hid);
    gemm_bt<<<dim3(DH_ / 128, B_ / 128, 2), 256, 0, stream>>>(
        hid, W2n, B_, DH_, DFF_, DFF_ / 2, nullptr, 4, ps, nullptr, nullptr);
    const int last = (s == STEPS_ - 1);
    reduce_ln_kernel<<<B_, 256, 0, stream>>>(
        ps, b2, x_emb, h, ln_g, ln_b, last ? hbf : hn, last ? 0 : 1);
  }

  // --- head ---
  gemm_bt<<<dim3(DOUT_ / 128, B_ / 128), 256, 0, stream>>>(
      hbf, hwbf, B_, DOUT_, DH_, DH_, head_b, 3, out, nullptr, nullptr);
}

// Round 4
// 3527.314 us; speedup vs baseline: 1.7432x; 1.3836x over previous
//
#include <hip/hip_runtime.h>
#include <hip/hip_bf16.h>
#include <math.h>

#define B_    4096
#define DIN_  512
#define DH_   1024
#define DOUT_ 256
#define DFF_  4096
#define STEPS_ 30
#define GAMMA_ 0.17677669529663687f
#define LN_EPS_ 1e-5f

typedef __attribute__((ext_vector_type(8))) short short8;
typedef __attribute__((ext_vector_type(4))) float f32x4;

__device__ inline void gload_lds16(const void* g, void* l) {
  __builtin_amdgcn_global_load_lds(
      (const __attribute__((address_space(1))) unsigned int*)g,
      (__attribute__((address_space(3))) unsigned int*)l, 16, 0, 0);
}

__device__ inline float fast_tanh(float v) {
  const float e = __expf(2.f * v);
  return 1.f - 2.f * __builtin_amdgcn_rcpf(e + 1.f);
}

__device__ inline float bf2f(unsigned short u) {
  return __uint_as_float((unsigned)u << 16);
}

// ---------------------------------------------------------------------------
// 256x256-tile bf16 GEMM, 8 waves (2Mx4N), BK=64, 128 KiB LDS double-buffer,
// depth-2 prefetch with counted vmcnt(8), st_16x32 XOR swizzle (inverse-swizzled
// global source + swizzled ds_read), setprio around MFMA clusters.
// C[M,N] = A[M,K] @ Bm[N,K]^T.  K-chunk per blockIdx.z: [z*kc, z*kc + nt*64).
// epi: 1 = bf16out = bf16(tanh(v + bias));  4 = bf16 partial (no bias),
//      slab z at bf16out + z*M*N.
// ---------------------------------------------------------------------------
__global__ __launch_bounds__(512, 2) void gemm256(
    const __hip_bfloat16* __restrict__ A, const __hip_bfloat16* __restrict__ Bm,
    int M, int N, int K, int kc, int nt, const float* __restrict__ bias,
    int epi, __hip_bfloat16* __restrict__ bf16out) {
  __shared__ __align__(16) char lds[2][65536];  // [buf][A 32K | B 32K]
  const int tid = threadIdx.x;
  const int lane = tid & 63;
  const int wid = tid >> 6;
  const int wr = wid >> 2;      // 0..1  (M half)
  const int wc = wid & 3;       // 0..3  (N quarter)

  // XCD-aware bijective swizzle over x-y plane (nwg % 8 == 0 in all uses)
  const int gx = gridDim.x;
  const int nwg = gx * gridDim.y;
  const int wg = blockIdx.y * gx + blockIdx.x;
  const int cpx = nwg >> 3;
  const int swz = (wg & 7) * cpx + (wg >> 3);
  const int bx = swz % gx, by = swz / gx;
  const int m0 = by * 256, n0 = bx * 256;
  const int zk = blockIdx.z * kc;

  // staging geometry: chunk c = wid*8+j covers 8 rows x 64 cols (1 KiB subtile).
  // inverse st_16x32 swizzle on the global source: lane>=32 swaps 16B pairs.
  const int u = (lane < 32) ? lane : (lane ^ 2);
  const int rr = u >> 3;          // row within 8-row subtile
  const int ccb = (u & 7) * 8;    // bf16 col offset

  f32x4 acc[8][4];
  const f32x4 zero = {0.f, 0.f, 0.f, 0.f};
#pragma unroll
  for (int i = 0; i < 8; ++i)
#pragma unroll
    for (int j = 0; j < 4; ++j) acc[i][j] = zero;

  auto STAGE = [&](int t, int buf) {
    const int kt = zk + t * 64;
#pragma unroll
    for (int j = 0; j < 8; ++j) {
      const int c = wid * 8 + j;        // wave-uniform
      const int cm = c & 31;
      const int row = cm * 8 + rr;      // row within 256-row tile
      const __hip_bfloat16* src =
          (c < 32) ? A + (size_t)(m0 + row) * K + kt + ccb
                   : Bm + (size_t)(n0 + row) * K + kt + ccb;
      gload_lds16((const void*)src, (void*)(&lds[buf][c * 1024]));
    }
  };

  STAGE(0, 0);
  STAGE(1, 1);

  const int ar = lane & 15;             // fragment row
  const int kq = (lane >> 4) * 16;      // k-slot byte offset
  const int brow0 = (wc & 1) * 64;

  for (int t = 0; t < nt; ++t) {
    const int buf = t & 1;
    if (t == nt - 1) {
      asm volatile("s_waitcnt vmcnt(0)" ::: "memory");
    } else {
      asm volatile("s_waitcnt vmcnt(8)" ::: "memory");  // tile t done; t+1 in flight
    }
    __builtin_amdgcn_s_barrier();
    __builtin_amdgcn_sched_barrier(0);

    const char* Ah = &lds[buf][wr * 16384];
    const char* Bh = &lds[buf][32768 + (wc >> 1) * 16384];
#pragma unroll
    for (int ks = 0; ks < 2; ++ks) {
      short8 av[8], bv[4];
#pragma unroll
      for (int mf = 0; mf < 8; ++mf) {
        int off = (mf * 16 + ar) * 128 + ks * 64 + kq;
        off ^= ((off >> 9) & 1) << 5;   // st_16x32 read swizzle
        av[mf] = *(const short8*)(Ah + off);
      }
#pragma unroll
      for (int nf = 0; nf < 4; ++nf) {
        int off = (brow0 + nf * 16 + ar) * 128 + ks * 64 + kq;
        off ^= ((off >> 9) & 1) << 5;
        bv[nf] = *(const short8*)(Bh + off);
      }
      __builtin_amdgcn_s_setprio(1);
#pragma unroll
      for (int mf = 0; mf < 8; ++mf)
#pragma unroll
        for (int nf = 0; nf < 4; ++nf)
          acc[mf][nf] = __builtin_amdgcn_mfma_f32_16x16x32_bf16(av[mf], bv[nf], acc[mf][nf], 0, 0, 0);
      __builtin_amdgcn_s_setprio(0);
    }

    __builtin_amdgcn_sched_barrier(0);
    __builtin_amdgcn_s_barrier();       // all waves done reading lds[buf]
    __builtin_amdgcn_sched_barrier(0);
    if (t + 2 < nt) STAGE(t + 2, buf);  // overwrite safe past the barrier
  }

  if (epi == 4) bf16out += (size_t)blockIdx.z * ((size_t)M * N);
  const int rb = (lane >> 4) * 4;
#pragma unroll
  for (int mf = 0; mf < 8; ++mf) {
#pragma unroll
    for (int nf = 0; nf < 4; ++nf) {
      const int col = n0 + wc * 64 + nf * 16 + ar;
      const float bvs = bias ? bias[col] : 0.f;
#pragma unroll
      for (int j = 0; j < 4; ++j) {
        const int row = m0 + wr * 128 + mf * 16 + rb + j;
        float v = acc[mf][nf][j] + bvs;
        if (epi == 1) v = fast_tanh(v);
        bf16out[(size_t)row * N + col] = __float2bfloat16(v);
      }
    }
  }
}

// ---------------------------------------------------------------------------
// m97-style 128x128 bf16 GEMM (kept for the one-shot embed/head GEMMs).
// epi: 0 = EMBED (write f32out=x_emb and f32out2=h); 3 = PLAIN (f32out).
// ---------------------------------------------------------------------------
__global__ __launch_bounds__(256) void gemm_bt(
    const __hip_bfloat16* __restrict__ A, const __hip_bfloat16* __restrict__ Bm,
    int M, int N, int K, const float* __restrict__ bias, int epi,
    float* __restrict__ f32out, float* __restrict__ f32out2) {
  __shared__ __align__(16) short As[128 * 32];
  __shared__ __align__(16) short Bs[128 * 32];
  const int tid = threadIdx.x;
  const int lane = tid & 63;
  const int wid = tid >> 6;
  const int wr = wid >> 1, wc = wid & 1;

  const int gx = gridDim.x;
  const int nwg = gx * gridDim.y;
  const int wg = blockIdx.y * gx + blockIdx.x;
  const int cpx = nwg >> 3;
  const int swz = (wg & 7) * cpx + (wg >> 3);
  const int bx = swz % gx, by = swz / gx;

  const int m0 = by * 128, n0 = bx * 128;
  const int ldsrow = lane >> 2;
  const int col8 = (lane & 3) * 8;

  f32x4 acc[4][4];
  const f32x4 zero = {0.f, 0.f, 0.f, 0.f};
#pragma unroll
  for (int i = 0; i < 4; ++i)
#pragma unroll
    for (int j = 0; j < 4; ++j) acc[i][j] = zero;

  for (int kt = 0; kt < K; kt += 32) {
#pragma unroll
    for (int i = 0; i < 2; ++i) {
      const int seg = wid * 2 + i;
      gload_lds16(A + (size_t)(m0 + seg * 16 + ldsrow) * K + kt + col8,
                  (void*)(As + seg * 512));
      gload_lds16(Bm + (size_t)(n0 + seg * 16 + ldsrow) * K + kt + col8,
                  (void*)(Bs + seg * 512));
    }
    __syncthreads();
    short8 a[4], b[4];
#pragma unroll
    for (int mf = 0; mf < 4; ++mf)
      a[mf] = *(const short8*)&As[(wr * 64 + mf * 16 + (lane & 15)) * 32 + (lane >> 4) * 8];
#pragma unroll
    for (int nf = 0; nf < 4; ++nf)
      b[nf] = *(const short8*)&Bs[(wc * 64 + nf * 16 + (lane & 15)) * 32 + (lane >> 4) * 8];
#pragma unroll
    for (int mf = 0; mf < 4; ++mf)
#pragma unroll
      for (int nf = 0; nf < 4; ++nf)
        acc[mf][nf] = __builtin_amdgcn_mfma_f32_16x16x32_bf16(a[mf], b[nf], acc[mf][nf], 0, 0, 0);
    __syncthreads();
  }

  const int rbase = (lane >> 4) * 4;
  const int cin = lane & 15;
#pragma unroll
  for (int mf = 0; mf < 4; ++mf) {
#pragma unroll
    for (int nf = 0; nf < 4; ++nf) {
      const int col = n0 + wc * 64 + nf * 16 + cin;
      const float bv = bias[col];
#pragma unroll
      for (int j = 0; j < 4; ++j) {
        const int row = m0 + wr * 64 + mf * 16 + rbase + j;
        const float v = acc[mf][nf][j] + bv;
        const size_t idx = (size_t)row * N + col;
        if (epi == 0) {
          f32out[idx] = v;
          f32out2[idx] = v;
        } else {
          f32out[idx] = v;
        }
      }
    }
  }
}

// ---------------------------------------------------------------------------
// Fused: h = (1-g)h + g*(sum of 4 bf16 partial slabs + b2 + x_emb);
// then LN+cast (do_ln) or plain bf16 cast (last step). Block per row.
// ---------------------------------------------------------------------------
__global__ __launch_bounds__(256) void reduce_ln_kernel(
    const __hip_bfloat16* __restrict__ ps, const float* __restrict__ b2,
    const float* __restrict__ xe, float* __restrict__ h,
    const float* __restrict__ g, const float* __restrict__ be,
    __hip_bfloat16* __restrict__ outbf, int do_ln) {
  const int row = blockIdx.x, tid = threadIdx.x;
  const size_t base = (size_t)row * DH_;
  const size_t slab = (size_t)B_ * DH_;
  float pv0 = 0.f, pv1 = 0.f, pv2 = 0.f, pv3 = 0.f;
#pragma unroll
  for (int z = 0; z < 4; ++z) {
    const ushort4 q = ((const ushort4*)(ps + z * slab + base))[tid];
    pv0 += bf2f(q.x); pv1 += bf2f(q.y); pv2 += bf2f(q.z); pv3 += bf2f(q.w);
  }
  const float4 xv = ((const float4*)(xe + base))[tid];
  const float4 hv = ((const float4*)(h + base))[tid];
  const float4 bv = ((const float4*)b2)[tid];
  float4 nv;
  nv.x = (1.f - GAMMA_) * hv.x + GAMMA_ * (pv0 + bv.x + xv.x);
  nv.y = (1.f - GAMMA_) * hv.y + GAMMA_ * (pv1 + bv.y + xv.y);
  nv.z = (1.f - GAMMA_) * hv.z + GAMMA_ * (pv2 + bv.z + xv.z);
  nv.w = (1.f - GAMMA_) * hv.w + GAMMA_ * (pv3 + bv.w + xv.w);
  ((float4*)(h + base))[tid] = nv;

  __hip_bfloat16* out = outbf + base + tid * 4;
  if (!do_ln) {
    out[0] = __float2bfloat16(nv.x);
    out[1] = __float2bfloat16(nv.y);
    out[2] = __float2bfloat16(nv.z);
    out[3] = __float2bfloat16(nv.w);
    return;
  }
  float s = nv.x + nv.y + nv.z + nv.w;
  float ss = nv.x * nv.x + nv.y * nv.y + nv.z * nv.z + nv.w * nv.w;
#pragma unroll
  for (int o = 32; o > 0; o >>= 1) {
    s += __shfl_down(s, o, 64);
    ss += __shfl_down(ss, o, 64);
  }
  __shared__ float rs_[4], rss_[4];
  const int lane = tid & 63, wid = tid >> 6;
  if (lane == 0) { rs_[wid] = s; rss_[wid] = ss; }
  __syncthreads();
  const float tot = rs_[0] + rs_[1] + rs_[2] + rs_[3];
  const float tots = rss_[0] + rss_[1] + rss_[2] + rss_[3];
  const float mu = tot * (1.f / DH_);
  const float var = tots * (1.f / DH_) - mu * mu;
  const float rstd = rsqrtf(var + LN_EPS_);
  const float4 gv = ((const float4*)g)[tid];
  const float4 bev = ((const float4*)be)[tid];
  out[0] = __float2bfloat16((nv.x - mu) * rstd * gv.x + bev.x);
  out[1] = __float2bfloat16((nv.y - mu) * rstd * gv.y + bev.y);
  out[2] = __float2bfloat16((nv.z - mu) * rstd * gv.z + bev.z);
  out[3] = __float2bfloat16((nv.w - mu) * rstd * gv.w + bev.w);
}

// ---------------------------------------------------------------------------
// LayerNorm + cast (step 0 only).
// ---------------------------------------------------------------------------
__global__ __launch_bounds__(256) void ln_cast_kernel(
    const float* __restrict__ h, const float* __restrict__ g,
    const float* __restrict__ be, __hip_bfloat16* __restrict__ hn) {
  const int row = blockIdx.x;
  const int tid = threadIdx.x;
  const float4 v = ((const float4*)(h + (size_t)row * DH_))[tid];
  float s = v.x + v.y + v.z + v.w;
  float ss = v.x * v.x + v.y * v.y + v.z * v.z + v.w * v.w;
#pragma unroll
  for (int o = 32; o > 0; o >>= 1) {
    s += __shfl_down(s, o, 64);
    ss += __shfl_down(ss, o, 64);
  }
  __shared__ float rs_[4], rss_[4];
  const int lane = tid & 63, wid = tid >> 6;
  if (lane == 0) { rs_[wid] = s; rss_[wid] = ss; }
  __syncthreads();
  const float tot = rs_[0] + rs_[1] + rs_[2] + rs_[3];
  const float tots = rss_[0] + rss_[1] + rss_[2] + rss_[3];
  const float mu = tot * (1.f / DH_);
  const float var = tots * (1.f / DH_) - mu * mu;
  const float rstd = rsqrtf(var + LN_EPS_);
  const float4 gv = ((const float4*)g)[tid];
  const float4 bv = ((const float4*)be)[tid];
  __hip_bfloat16* out = hn + (size_t)row * DH_ + tid * 4;
  out[0] = __float2bfloat16((v.x - mu) * rstd * gv.x + bv.x);
  out[1] = __float2bfloat16((v.y - mu) * rstd * gv.y + bv.y);
  out[2] = __float2bfloat16((v.z - mu) * rstd * gv.z + bv.z);
  out[3] = __float2bfloat16((v.w - mu) * rstd * gv.w + bv.w);
}

// ---------------------------------------------------------------------------
// Paired fp32 matvec (power iteration).
// ---------------------------------------------------------------------------
__global__ __launch_bounds__(256) void matvec2_kernel(
    const float* __restrict__ Wa, const float* __restrict__ xa,
    float* __restrict__ ya, int rowsA, int colsA,
    const float* __restrict__ Wb, const float* __restrict__ xb,
    float* __restrict__ yb, int rowsB, int colsB) {
  const int gw = (int)(blockIdx.x * 256 + threadIdx.x) >> 6;
  const int lane = threadIdx.x & 63;
  const float* W;
  const float* x;
  float* y;
  int row, cols;
  if (gw < rowsA) {
    W = Wa; x = xa; y = ya; row = gw; cols = colsA;
  } else {
    row = gw - rowsA;
    if (row >= rowsB) return;
    W = Wb; x = xb; y = yb; cols = colsB;
  }
  const float4* wr = (const float4*)(W + (size_t)row * cols);
  const float4* xv = (const float4*)x;
  const int n4 = cols >> 2;
  float s = 0.f;
  for (int c = lane; c < n4; c += 64) {
    const float4 wv = wr[c];
    const float4 vv = xv[c];
    s += wv.x * vv.x + wv.y * vv.y + wv.z * vv.z + wv.w * vv.w;
  }
#pragma unroll
  for (int o = 32; o > 0; o >>= 1) s += __shfl_down(s, o, 64);
  if (lane == 0) y[row] = s;
}

__global__ __launch_bounds__(256) void transpose_kernel(
    const float* __restrict__ in, float* __restrict__ out, int R, int C) {
  __shared__ float t[32][33];
  const int lx = threadIdx.x & 31, ly = threadIdx.x >> 5;
  const int r0 = blockIdx.y * 32, c0 = blockIdx.x * 32;
#pragma unroll
  for (int j = 0; j < 32; j += 8) t[ly + j][lx] = in[(size_t)(r0 + ly + j) * C + c0 + lx];
  __syncthreads();
#pragma unroll
  for (int j = 0; j < 32; j += 8) out[(size_t)(c0 + ly + j) * R + r0 + lx] = t[lx][ly + j];
}

__global__ void init_v_kernel(float* v1, float* v2) {
  const int i = blockIdx.x * 256 + threadIdx.x;
  if (i < 1024) v1[i] = 0.03125f;
  if (i < 4096) v2[i] = 0.015625f;
}

__global__ __launch_bounds__(256) void cast_kernel(
    const float* __restrict__ s, __hip_bfloat16* __restrict__ d, int n) {
  const int b = (blockIdx.x * 256 + threadIdx.x) * 4;
  if (b < n) {
    const float4 v = *(const float4*)(s + b);
    d[b] = __float2bfloat16(v.x);
    d[b + 1] = __float2bfloat16(v.y);
    d[b + 2] = __float2bfloat16(v.z);
    d[b + 3] = __float2bfloat16(v.w);
  }
}

__global__ __launch_bounds__(256) void cast_scaled_kernel(
    const float* __restrict__ s, __hip_bfloat16* __restrict__ d, int n,
    const float* __restrict__ rs) {
  const float r = rs[0];
  const int b = (blockIdx.x * 256 + threadIdx.x) * 4;
  if (b < n) {
    const float4 v = *(const float4*)(s + b);
    d[b] = __float2bfloat16(v.x * r);
    d[b + 1] = __float2bfloat16(v.y * r);
    d[b + 2] = __float2bfloat16(v.z * r);
    d[b + 3] = __float2bfloat16(v.w * r);
  }
}

// rs = |c| / |d|  (= 1/sigma)
__global__ __launch_bounds__(256) void sigma_rs_kernel(
    const float* __restrict__ c, int m, const float* __restrict__ dv, int n,
    float* __restrict__ rs) {
  const int tid = threadIdx.x;
  float sc = 0.f, sd = 0.f;
  for (int i = tid; i < m; i += 256) { const float v = c[i]; sc += v * v; }
  for (int i = tid; i < n; i += 256) { const float v = dv[i]; sd += v * v; }
#pragma unroll
  for (int o = 32; o > 0; o >>= 1) {
    sc += __shfl_down(sc, o, 64);
    sd += __shfl_down(sd, o, 64);
  }
  __shared__ float a[4], b[4];
  const int lane = tid & 63, wid = tid >> 6;
  if (lane == 0) { a[wid] = sc; b[wid] = sd; }
  __syncthreads();
  if (tid == 0) {
    const float tc = a[0] + a[1] + a[2] + a[3];
    const float td = b[0] + b[1] + b[2] + b[3];
    rs[0] = sqrtf(tc / td);
  }
}

extern "C" void kernel_launch(void* const* d_in, const int* in_sizes, int n_in,
                              void* d_out, int out_size, void* d_ws, size_t ws_size,
                              hipStream_t stream) {
  const float* x       = (const float*)d_in[0];
  const float* embed_w = (const float*)d_in[1];
  const float* embed_b = (const float*)d_in[2];
  const float* W1      = (const float*)d_in[3];
  const float* b1      = (const float*)d_in[4];
  const float* W2      = (const float*)d_in[5];
  const float* b2      = (const float*)d_in[6];
  const float* ln_g    = (const float*)d_in[7];
  const float* ln_b    = (const float*)d_in[8];
  const float* head_w  = (const float*)d_in[9];
  const float* head_b  = (const float*)d_in[10];
  float* out = (float*)d_out;

  char* p = (char*)d_ws;
  auto carve = [&](size_t bytes) {
    char* r = p;
    p += (bytes + 255) & ~(size_t)255;
    return (void*)r;
  };
  float* h     = (float*)carve((size_t)B_ * DH_ * 4);
  float* x_emb = (float*)carve((size_t)B_ * DH_ * 4);
  // W1T/W2T (33.6 MB) are dead after the power iteration; the 4 bf16 K-split
  // partial slabs (4 x 8.4 MB = 33.6 MB) alias this region during the steps.
  float* W1T   = (float*)carve((size_t)DFF_ * DH_ * 4);
  float* W2T   = (float*)carve((size_t)DH_ * DFF_ * 4);
  __hip_bfloat16* ps = (__hip_bfloat16*)W1T;  // [4][B_][DH_] bf16
  __hip_bfloat16* hn   = (__hip_bfloat16*)carve((size_t)B_ * DH_ * 2);
  __hip_bfloat16* hid  = (__hip_bfloat16*)carve((size_t)B_ * DFF_ * 2);
  __hip_bfloat16* W1n  = (__hip_bfloat16*)carve((size_t)DFF_ * DH_ * 2);
  __hip_bfloat16* W2n  = (__hip_bfloat16*)carve((size_t)DH_ * DFF_ * 2);
  __hip_bfloat16* xbf  = (__hip_bfloat16*)carve((size_t)B_ * DIN_ * 2);
  __hip_bfloat16* ewbf = (__hip_bfloat16*)carve((size_t)DH_ * DIN_ * 2);
  __hip_bfloat16* hwbf = (__hip_bfloat16*)carve((size_t)DOUT_ * DH_ * 2);
  __hip_bfloat16* hbf  = (__hip_bfloat16*)carve((size_t)B_ * DH_ * 2);
  float* v1a = (float*)carve(4096 * 4);
  float* v1b = (float*)carve(4096 * 4);
  float* c1  = (float*)carve(4096 * 4);
  float* v2a = (float*)carve(4096 * 4);
  float* v2b = (float*)carve(4096 * 4);
  float* c2  = (float*)carve(4096 * 4);
  float* rs1 = (float*)carve(256);
  float* rs2 = (float*)carve(256);

  // --- prep: transposes, inits, input casts ---
  transpose_kernel<<<dim3(DH_ / 32, DFF_ / 32), 256, 0, stream>>>(W1, W1T, DFF_, DH_);
  transpose_kernel<<<dim3(DFF_ / 32, DH_ / 32), 256, 0, stream>>>(W2, W2T, DH_, DFF_);
  init_v_kernel<<<16, 256, 0, stream>>>(v1a, v2a);
  cast_kernel<<<(B_ * DIN_ / 4) / 256, 256, 0, stream>>>(x, xbf, B_ * DIN_);
  cast_kernel<<<(DH_ * DIN_ / 4) / 256, 256, 0, stream>>>(embed_w, ewbf, DH_ * DIN_);
  cast_kernel<<<(DOUT_ * DH_ / 4) / 256, 256, 0, stream>>>(head_w, hwbf, DOUT_ * DH_);

  // --- x_emb = x @ embed_w^T + embed_b ; h = x_emb ---
  gemm_bt<<<dim3(DH_ / 128, B_ / 128), 256, 0, stream>>>(
      xbf, ewbf, B_, DH_, DIN_, embed_b, 0, x_emb, h);

  // --- power iteration (unnormalized), W1 & W2 paired ---
  for (int it = 0; it < 15; ++it) {
    const float* vin1 = (it & 1) ? v1b : v1a;
    float* vout1 = (it & 1) ? v1a : v1b;
    const float* vin2 = (it & 1) ? v2b : v2a;
    float* vout2 = (it & 1) ? v2a : v2b;
    matvec2_kernel<<<((DFF_ + DH_) * 64) / 256, 256, 0, stream>>>(
        W1, vin1, c1, DFF_, DH_, W2, vin2, c2, DH_, DFF_);
    matvec2_kernel<<<((DH_ + DFF_) * 64) / 256, 256, 0, stream>>>(
        W1T, c1, vout1, DH_, DFF_, W2T, c2, vout2, DFF_, DH_);
  }
  sigma_rs_kernel<<<1, 256, 0, stream>>>(c1, DFF_, v1b, DH_, rs1);
  sigma_rs_kernel<<<1, 256, 0, stream>>>(c2, DH_, v2b, DFF_, rs2);
  cast_scaled_kernel<<<(DFF_ * DH_ / 4) / 256, 256, 0, stream>>>(W1, W1n, DFF_ * DH_, rs1);
  cast_scaled_kernel<<<(DH_ * DFF_ / 4) / 256, 256, 0, stream>>>(W2, W2n, DH_ * DFF_, rs2);
  // (W1T/W2T dead from here; ps aliases them)

  // --- step 0 LN (h == x_emb) ---
  ln_cast_kernel<<<B_, 256, 0, stream>>>(h, ln_g, ln_b, hn);

  // --- 30 equilibrium steps ---
  for (int s = 0; s < STEPS_; ++s) {
    // hid = tanh(hn @ W1n^T + b1)   [4096 x 4096, K=1024]
    gemm256<<<dim3(DFF_ / 256, B_ / 256, 1), 512, 0, stream>>>(
        hn, W1n, B_, DFF_, DH_, DH_, DH_ / 64, b1, 1, hid);
    // ps[z] = hid @ W2n^T (K-chunk z) [4096 x 1024, K=4096, split 4]
    gemm256<<<dim3(DH_ / 256, B_ / 256, 4), 512, 0, stream>>>(
        hid, W2n, B_, DH_, DFF_, DFF_ / 4, DFF_ / 4 / 64, nullptr, 4, ps);
    const int last = (s == STEPS_ - 1);
    reduce_ln_kernel<<<B_, 256, 0, stream>>>(
        ps, b2, x_emb, h, ln_g, ln_b, last ? hbf : hn, last ? 0 : 1);
  }

  // --- head ---
  gemm_bt<<<dim3(DOUT_ / 128, B_ / 128), 256, 0, stream>>>(
      hbf, hwbf, B_, DOUT_, DH_, head_b, 3, out, nullptr);
}

// Round 5
// 3340.421 us; speedup vs baseline: 1.8407x; 1.0559x over previous
//
#include <hip/hip_runtime.h>
#include <hip/hip_bf16.h>
#include <math.h>

#define B_    4096
#define DIN_  512
#define DH_   1024
#define DOUT_ 256
#define DFF_  4096
#define STEPS_ 30
#define GAMMA_ 0.17677669529663687f
#define LN_EPS_ 1e-5f

typedef __attribute__((ext_vector_type(8))) short short8;
typedef __attribute__((ext_vector_type(4))) float f32x4;

__device__ inline void gload_lds16(const void* g, void* l) {
  __builtin_amdgcn_global_load_lds(
      (const __attribute__((address_space(1))) unsigned int*)g,
      (__attribute__((address_space(3))) unsigned int*)l, 16, 0, 0);
}

__device__ inline float fast_tanh(float v) {
  const float e = __expf(2.f * v);
  return 1.f - 2.f * __builtin_amdgcn_rcpf(e + 1.f);
}

__device__ inline float bf2f(unsigned short u) {
  return __uint_as_float((unsigned)u << 16);
}

// ---------------------------------------------------------------------------
// 256x256-tile bf16 GEMM, 8 waves (2Mx4N), BK=32, FOUR 32KiB LDS buffers,
// prefetch depth 3 K-tiles, counted vmcnt(8) (never 0 in steady state),
// one barrier + one 32-MFMA setprio cluster per K-tile.
// Layout [256][32] bf16 (64B rows) is bank-conflict-free for the
// (row=lane&15, chunk=lane>>4) ds_read_b128 pattern: quad = 4*(row&1)+chunk
// covers all 8 bank-quads uniformly. No swizzle anywhere; staging linear.
// C[M,N] = A[M,K] @ Bm[N,K]^T.  K-chunk per blockIdx.z: [z*kc, z*kc+nt*32).
// epi: 1 = bf16out = bf16(tanh(v + bias)); 4 = bf16 partial slab z (no bias).
// ---------------------------------------------------------------------------
__global__ __launch_bounds__(512, 2) void gemm256(
    const __hip_bfloat16* __restrict__ A, const __hip_bfloat16* __restrict__ Bm,
    int M, int N, int K, int kc, int nt, const float* __restrict__ bias,
    int epi, __hip_bfloat16* __restrict__ bf16out) {
  __shared__ __align__(16) char lds[4][32768];  // [buf][A 16K | B 16K]
  const int tid = threadIdx.x;
  const int lane = tid & 63;
  const int wid = tid >> 6;
  const int wr = wid >> 2;      // 0..1  (M half)
  const int wc = wid & 3;       // 0..3  (N quarter)

  // XCD-aware bijective swizzle over x-y plane (nwg % 8 == 0 in all uses)
  const int gx = gridDim.x;
  const int nwg = gx * gridDim.y;
  const int wg = blockIdx.y * gx + blockIdx.x;
  const int cpx = nwg >> 3;
  const int swz = (wg & 7) * cpx + (wg >> 3);
  const int bx = swz % gx, by = swz / gx;
  const int m0 = by * 256, n0 = bx * 256;
  const int zk = blockIdx.z * kc;

  // staging: half-tile = 128 rows x 32 cols bf16 = 8KB = 512 thr x 16B.
  const int srow = wid * 16 + (lane >> 2);  // row within 128-row half
  const int scol = (lane & 3) * 8;          // bf16 col offset (16B chunks)

  f32x4 acc[8][4];
  const f32x4 zero = {0.f, 0.f, 0.f, 0.f};
#pragma unroll
  for (int i = 0; i < 8; ++i)
#pragma unroll
    for (int j = 0; j < 4; ++j) acc[i][j] = zero;

  auto STAGE = [&](int t) {
    const int kt = zk + t * 32;
    char* base = &lds[t & 3][0];
#pragma unroll
    for (int q = 0; q < 4; ++q) {  // A rows 0-127, A 128-255, B 0-127, B 128-255
      const __hip_bfloat16* src =
          (q < 2) ? A + (size_t)(m0 + q * 128 + srow) * K + kt + scol
                  : Bm + (size_t)(n0 + (q - 2) * 128 + srow) * K + kt + scol;
      // dest is wave-uniform; HW adds lane*16
      gload_lds16((const void*)src, (void*)(base + q * 8192 + wid * 1024));
    }
  };

  STAGE(0);
  STAGE(1);
  STAGE(2);

  const int ar = lane & 15;          // fragment row
  const int hb = (lane >> 4) * 16;   // k-chunk byte offset

  for (int t = 0; t < nt; ++t) {
    const char* base = &lds[t & 3][0];
    // tiles t+1, t+2 may stay in flight (4 loads each)
    if (t + 3 <= nt) {
      asm volatile("s_waitcnt vmcnt(8)" ::: "memory");
    } else if (t + 2 == nt) {
      asm volatile("s_waitcnt vmcnt(4)" ::: "memory");
    } else {
      asm volatile("s_waitcnt vmcnt(0)" ::: "memory");
    }
    __builtin_amdgcn_s_barrier();
    __builtin_amdgcn_sched_barrier(0);

    short8 av[8], bv[4];
#pragma unroll
    for (int mf = 0; mf < 8; ++mf)
      av[mf] = *(const short8*)(base + (wr * 128 + mf * 16 + ar) * 64 + hb);
#pragma unroll
    for (int nf = 0; nf < 4; ++nf)
      bv[nf] = *(const short8*)(base + 16384 + (wc * 64 + nf * 16 + ar) * 64 + hb);

    if (t + 3 < nt) STAGE(t + 3);  // overwrites buf of tile t-1 (safe past barrier)

    asm volatile("s_waitcnt lgkmcnt(0)" ::: "memory");
    __builtin_amdgcn_sched_barrier(0);
    __builtin_amdgcn_s_setprio(1);
#pragma unroll
    for (int mf = 0; mf < 8; ++mf)
#pragma unroll
      for (int nf = 0; nf < 4; ++nf)
        acc[mf][nf] = __builtin_amdgcn_mfma_f32_16x16x32_bf16(av[mf], bv[nf], acc[mf][nf], 0, 0, 0);
    __builtin_amdgcn_s_setprio(0);
    __builtin_amdgcn_sched_barrier(0);
  }

  if (epi == 4) bf16out += (size_t)blockIdx.z * ((size_t)M * N);
  const int rb = (lane >> 4) * 4;
#pragma unroll
  for (int mf = 0; mf < 8; ++mf) {
#pragma unroll
    for (int nf = 0; nf < 4; ++nf) {
      const int col = n0 + wc * 64 + nf * 16 + ar;
      const float bvs = bias ? bias[col] : 0.f;
#pragma unroll
      for (int j = 0; j < 4; ++j) {
        const int row = m0 + wr * 128 + mf * 16 + rb + j;
        float v = acc[mf][nf][j] + bvs;
        if (epi == 1) v = fast_tanh(v);
        bf16out[(size_t)row * N + col] = __float2bfloat16(v);
      }
    }
  }
}

// ---------------------------------------------------------------------------
// m97-style 128x128 bf16 GEMM (kept for the one-shot embed/head GEMMs).
// epi: 0 = EMBED (write f32out=x_emb and f32out2=h); 3 = PLAIN (f32out).
// ---------------------------------------------------------------------------
__global__ __launch_bounds__(256) void gemm_bt(
    const __hip_bfloat16* __restrict__ A, const __hip_bfloat16* __restrict__ Bm,
    int M, int N, int K, const float* __restrict__ bias, int epi,
    float* __restrict__ f32out, float* __restrict__ f32out2) {
  __shared__ __align__(16) short As[128 * 32];
  __shared__ __align__(16) short Bs[128 * 32];
  const int tid = threadIdx.x;
  const int lane = tid & 63;
  const int wid = tid >> 6;
  const int wr = wid >> 1, wc = wid & 1;

  const int gx = gridDim.x;
  const int nwg = gx * gridDim.y;
  const int wg = blockIdx.y * gx + blockIdx.x;
  const int cpx = nwg >> 3;
  const int swz = (wg & 7) * cpx + (wg >> 3);
  const int bx = swz % gx, by = swz / gx;

  const int m0 = by * 128, n0 = bx * 128;
  const int ldsrow = lane >> 2;
  const int col8 = (lane & 3) * 8;

  f32x4 acc[4][4];
  const f32x4 zero = {0.f, 0.f, 0.f, 0.f};
#pragma unroll
  for (int i = 0; i < 4; ++i)
#pragma unroll
    for (int j = 0; j < 4; ++j) acc[i][j] = zero;

  for (int kt = 0; kt < K; kt += 32) {
#pragma unroll
    for (int i = 0; i < 2; ++i) {
      const int seg = wid * 2 + i;
      gload_lds16(A + (size_t)(m0 + seg * 16 + ldsrow) * K + kt + col8,
                  (void*)(As + seg * 512));
      gload_lds16(Bm + (size_t)(n0 + seg * 16 + ldsrow) * K + kt + col8,
                  (void*)(Bs + seg * 512));
    }
    __syncthreads();
    short8 a[4], b[4];
#pragma unroll
    for (int mf = 0; mf < 4; ++mf)
      a[mf] = *(const short8*)&As[(wr * 64 + mf * 16 + (lane & 15)) * 32 + (lane >> 4) * 8];
#pragma unroll
    for (int nf = 0; nf < 4; ++nf)
      b[nf] = *(const short8*)&Bs[(wc * 64 + nf * 16 + (lane & 15)) * 32 + (lane >> 4) * 8];
#pragma unroll
    for (int mf = 0; mf < 4; ++mf)
#pragma unroll
      for (int nf = 0; nf < 4; ++nf)
        acc[mf][nf] = __builtin_amdgcn_mfma_f32_16x16x32_bf16(a[mf], b[nf], acc[mf][nf], 0, 0, 0);
    __syncthreads();
  }

  const int rbase = (lane >> 4) * 4;
  const int cin = lane & 15;
#pragma unroll
  for (int mf = 0; mf < 4; ++mf) {
#pragma unroll
    for (int nf = 0; nf < 4; ++nf) {
      const int col = n0 + wc * 64 + nf * 16 + cin;
      const float bv = bias[col];
#pragma unroll
      for (int j = 0; j < 4; ++j) {
        const int row = m0 + wr * 64 + mf * 16 + rbase + j;
        const float v = acc[mf][nf][j] + bv;
        const size_t idx = (size_t)row * N + col;
        if (epi == 0) {
          f32out[idx] = v;
          f32out2[idx] = v;
        } else {
          f32out[idx] = v;
        }
      }
    }
  }
}

// ---------------------------------------------------------------------------
// Fused: h = (1-g)h + g*(sum of 4 bf16 partial slabs + b2 + x_emb);
// then LN+cast (do_ln) or plain bf16 cast (last step). Block per row.
// ---------------------------------------------------------------------------
__global__ __launch_bounds__(256) void reduce_ln_kernel(
    const __hip_bfloat16* __restrict__ ps, const float* __restrict__ b2,
    const float* __restrict__ xe, float* __restrict__ h,
    const float* __restrict__ g, const float* __restrict__ be,
    __hip_bfloat16* __restrict__ outbf, int do_ln) {
  const int row = blockIdx.x, tid = threadIdx.x;
  const size_t base = (size_t)row * DH_;
  const size_t slab = (size_t)B_ * DH_;
  float pv0 = 0.f, pv1 = 0.f, pv2 = 0.f, pv3 = 0.f;
#pragma unroll
  for (int z = 0; z < 4; ++z) {
    const ushort4 q = ((const ushort4*)(ps + z * slab + base))[tid];
    pv0 += bf2f(q.x); pv1 += bf2f(q.y); pv2 += bf2f(q.z); pv3 += bf2f(q.w);
  }
  const float4 xv = ((const float4*)(xe + base))[tid];
  const float4 hv = ((const float4*)(h + base))[tid];
  const float4 bv = ((const float4*)b2)[tid];
  float4 nv;
  nv.x = (1.f - GAMMA_) * hv.x + GAMMA_ * (pv0 + bv.x + xv.x);
  nv.y = (1.f - GAMMA_) * hv.y + GAMMA_ * (pv1 + bv.y + xv.y);
  nv.z = (1.f - GAMMA_) * hv.z + GAMMA_ * (pv2 + bv.z + xv.z);
  nv.w = (1.f - GAMMA_) * hv.w + GAMMA_ * (pv3 + bv.w + xv.w);
  ((float4*)(h + base))[tid] = nv;

  __hip_bfloat16* out = outbf + base + tid * 4;
  if (!do_ln) {
    out[0] = __float2bfloat16(nv.x);
    out[1] = __float2bfloat16(nv.y);
    out[2] = __float2bfloat16(nv.z);
    out[3] = __float2bfloat16(nv.w);
    return;
  }
  float s = nv.x + nv.y + nv.z + nv.w;
  float ss = nv.x * nv.x + nv.y * nv.y + nv.z * nv.z + nv.w * nv.w;
#pragma unroll
  for (int o = 32; o > 0; o >>= 1) {
    s += __shfl_down(s, o, 64);
    ss += __shfl_down(ss, o, 64);
  }
  __shared__ float rs_[4], rss_[4];
  const int lane = tid & 63, wid = tid >> 6;
  if (lane == 0) { rs_[wid] = s; rss_[wid] = ss; }
  __syncthreads();
  const float tot = rs_[0] + rs_[1] + rs_[2] + rs_[3];
  const float tots = rss_[0] + rss_[1] + rss_[2] + rss_[3];
  const float mu = tot * (1.f / DH_);
  const float var = tots * (1.f / DH_) - mu * mu;
  const float rstd = rsqrtf(var + LN_EPS_);
  const float4 gv = ((const float4*)g)[tid];
  const float4 bev = ((const float4*)be)[tid];
  out[0] = __float2bfloat16((nv.x - mu) * rstd * gv.x + bev.x);
  out[1] = __float2bfloat16((nv.y - mu) * rstd * gv.y + bev.y);
  out[2] = __float2bfloat16((nv.z - mu) * rstd * gv.z + bev.z);
  out[3] = __float2bfloat16((nv.w - mu) * rstd * gv.w + bev.w);
}

// ---------------------------------------------------------------------------
// LayerNorm + cast (step 0 only).
// ---------------------------------------------------------------------------
__global__ __launch_bounds__(256) void ln_cast_kernel(
    const float* __restrict__ h, const float* __restrict__ g,
    const float* __restrict__ be, __hip_bfloat16* __restrict__ hn) {
  const int row = blockIdx.x;
  const int tid = threadIdx.x;
  const float4 v = ((const float4*)(h + (size_t)row * DH_))[tid];
  float s = v.x + v.y + v.z + v.w;
  float ss = v.x * v.x + v.y * v.y + v.z * v.z + v.w * v.w;
#pragma unroll
  for (int o = 32; o > 0; o >>= 1) {
    s += __shfl_down(s, o, 64);
    ss += __shfl_down(ss, o, 64);
  }
  __shared__ float rs_[4], rss_[4];
  const int lane = tid & 63, wid = tid >> 6;
  if (lane == 0) { rs_[wid] = s; rss_[wid] = ss; }
  __syncthreads();
  const float tot = rs_[0] + rs_[1] + rs_[2] + rs_[3];
  const float tots = rss_[0] + rss_[1] + rss_[2] + rss_[3];
  const float mu = tot * (1.f / DH_);
  const float var = tots * (1.f / DH_) - mu * mu;
  const float rstd = rsqrtf(var + LN_EPS_);
  const float4 gv = ((const float4*)g)[tid];
  const float4 bv = ((const float4*)be)[tid];
  __hip_bfloat16* out = hn + (size_t)row * DH_ + tid * 4;
  out[0] = __float2bfloat16((v.x - mu) * rstd * gv.x + bv.x);
  out[1] = __float2bfloat16((v.y - mu) * rstd * gv.y + bv.y);
  out[2] = __float2bfloat16((v.z - mu) * rstd * gv.z + bv.z);
  out[3] = __float2bfloat16((v.w - mu) * rstd * gv.w + bv.w);
}

// ---------------------------------------------------------------------------
// Paired fp32 matvec (power iteration).
// ---------------------------------------------------------------------------
__global__ __launch_bounds__(256) void matvec2_kernel(
    const float* __restrict__ Wa, const float* __restrict__ xa,
    float* __restrict__ ya, int rowsA, int colsA,
    const float* __restrict__ Wb, const float* __restrict__ xb,
    float* __restrict__ yb, int rowsB, int colsB) {
  const int gw = (int)(blockIdx.x * 256 + threadIdx.x) >> 6;
  const int lane = threadIdx.x & 63;
  const float* W;
  const float* x;
  float* y;
  int row, cols;
  if (gw < rowsA) {
    W = Wa; x = xa; y = ya; row = gw; cols = colsA;
  } else {
    row = gw - rowsA;
    if (row >= rowsB) return;
    W = Wb; x = xb; y = yb; cols = colsB;
  }
  const float4* wr = (const float4*)(W + (size_t)row * cols);
  const float4* xv = (const float4*)x;
  const int n4 = cols >> 2;
  float s = 0.f;
  for (int c = lane; c < n4; c += 64) {
    const float4 wv = wr[c];
    const float4 vv = xv[c];
    s += wv.x * vv.x + wv.y * vv.y + wv.z * vv.z + wv.w * vv.w;
  }
#pragma unroll
  for (int o = 32; o > 0; o >>= 1) s += __shfl_down(s, o, 64);
  if (lane == 0) y[row] = s;
}

__global__ __launch_bounds__(256) void transpose_kernel(
    const float* __restrict__ in, float* __restrict__ out, int R, int C) {
  __shared__ float t[32][33];
  const int lx = threadIdx.x & 31, ly = threadIdx.x >> 5;
  const int r0 = blockIdx.y * 32, c0 = blockIdx.x * 32;
#pragma unroll
  for (int j = 0; j < 32; j += 8) t[ly + j][lx] = in[(size_t)(r0 + ly + j) * C + c0 + lx];
  __syncthreads();
#pragma unroll
  for (int j = 0; j < 32; j += 8) out[(size_t)(c0 + ly + j) * R + r0 + lx] = t[lx][ly + j];
}

__global__ void init_v_kernel(float* v1, float* v2) {
  const int i = blockIdx.x * 256 + threadIdx.x;
  if (i < 1024) v1[i] = 0.03125f;
  if (i < 4096) v2[i] = 0.015625f;
}

__global__ __launch_bounds__(256) void cast_kernel(
    const float* __restrict__ s, __hip_bfloat16* __restrict__ d, int n) {
  const int b = (blockIdx.x * 256 + threadIdx.x) * 4;
  if (b < n) {
    const float4 v = *(const float4*)(s + b);
    d[b] = __float2bfloat16(v.x);
    d[b + 1] = __float2bfloat16(v.y);
    d[b + 2] = __float2bfloat16(v.z);
    d[b + 3] = __float2bfloat16(v.w);
  }
}

__global__ __launch_bounds__(256) void cast_scaled_kernel(
    const float* __restrict__ s, __hip_bfloat16* __restrict__ d, int n,
    const float* __restrict__ rs) {
  const float r = rs[0];
  const int b = (blockIdx.x * 256 + threadIdx.x) * 4;
  if (b < n) {
    const float4 v = *(const float4*)(s + b);
    d[b] = __float2bfloat16(v.x * r);
    d[b + 1] = __float2bfloat16(v.y * r);
    d[b + 2] = __float2bfloat16(v.z * r);
    d[b + 3] = __float2bfloat16(v.w * r);
  }
}

// rs = |c| / |d|  (= 1/sigma)
__global__ __launch_bounds__(256) void sigma_rs_kernel(
    const float* __restrict__ c, int m, const float* __restrict__ dv, int n,
    float* __restrict__ rs) {
  const int tid = threadIdx.x;
  float sc = 0.f, sd = 0.f;
  for (int i = tid; i < m; i += 256) { const float v = c[i]; sc += v * v; }
  for (int i = tid; i < n; i += 256) { const float v = dv[i]; sd += v * v; }
#pragma unroll
  for (int o = 32; o > 0; o >>= 1) {
    sc += __shfl_down(sc, o, 64);
    sd += __shfl_down(sd, o, 64);
  }
  __shared__ float a[4], b[4];
  const int lane = tid & 63, wid = tid >> 6;
  if (lane == 0) { a[wid] = sc; b[wid] = sd; }
  __syncthreads();
  if (tid == 0) {
    const float tc = a[0] + a[1] + a[2] + a[3];
    const float td = b[0] + b[1] + b[2] + b[3];
    rs[0] = sqrtf(tc / td);
  }
}

extern "C" void kernel_launch(void* const* d_in, const int* in_sizes, int n_in,
                              void* d_out, int out_size, void* d_ws, size_t ws_size,
                              hipStream_t stream) {
  const float* x       = (const float*)d_in[0];
  const float* embed_w = (const float*)d_in[1];
  const float* embed_b = (const float*)d_in[2];
  const float* W1      = (const float*)d_in[3];
  const float* b1      = (const float*)d_in[4];
  const float* W2      = (const float*)d_in[5];
  const float* b2      = (const float*)d_in[6];
  const float* ln_g    = (const float*)d_in[7];
  const float* ln_b    = (const float*)d_in[8];
  const float* head_w  = (const float*)d_in[9];
  const float* head_b  = (const float*)d_in[10];
  float* out = (float*)d_out;

  char* p = (char*)d_ws;
  auto carve = [&](size_t bytes) {
    char* r = p;
    p += (bytes + 255) & ~(size_t)255;
    return (void*)r;
  };
  float* h     = (float*)carve((size_t)B_ * DH_ * 4);
  float* x_emb = (float*)carve((size_t)B_ * DH_ * 4);
  // W1T/W2T (33.6 MB) are dead after the power iteration; the 4 bf16 K-split
  // partial slabs (4 x 8.4 MB = 33.6 MB) alias this region during the steps.
  float* W1T   = (float*)carve((size_t)DFF_ * DH_ * 4);
  float* W2T   = (float*)carve((size_t)DH_ * DFF_ * 4);
  __hip_bfloat16* ps = (__hip_bfloat16*)W1T;  // [4][B_][DH_] bf16
  __hip_bfloat16* hn   = (__hip_bfloat16*)carve((size_t)B_ * DH_ * 2);
  __hip_bfloat16* hid  = (__hip_bfloat16*)carve((size_t)B_ * DFF_ * 2);
  __hip_bfloat16* W1n  = (__hip_bfloat16*)carve((size_t)DFF_ * DH_ * 2);
  __hip_bfloat16* W2n  = (__hip_bfloat16*)carve((size_t)DH_ * DFF_ * 2);
  __hip_bfloat16* xbf  = (__hip_bfloat16*)carve((size_t)B_ * DIN_ * 2);
  __hip_bfloat16* ewbf = (__hip_bfloat16*)carve((size_t)DH_ * DIN_ * 2);
  __hip_bfloat16* hwbf = (__hip_bfloat16*)carve((size_t)DOUT_ * DH_ * 2);
  __hip_bfloat16* hbf  = (__hip_bfloat16*)carve((size_t)B_ * DH_ * 2);
  float* v1a = (float*)carve(4096 * 4);
  float* v1b = (float*)carve(4096 * 4);
  float* c1  = (float*)carve(4096 * 4);
  float* v2a = (float*)carve(4096 * 4);
  float* v2b = (float*)carve(4096 * 4);
  float* c2  = (float*)carve(4096 * 4);
  float* rs1 = (float*)carve(256);
  float* rs2 = (float*)carve(256);

  // --- prep: transposes, inits, input casts ---
  transpose_kernel<<<dim3(DH_ / 32, DFF_ / 32), 256, 0, stream>>>(W1, W1T, DFF_, DH_);
  transpose_kernel<<<dim3(DFF_ / 32, DH_ / 32), 256, 0, stream>>>(W2, W2T, DH_, DFF_);
  init_v_kernel<<<16, 256, 0, stream>>>(v1a, v2a);
  cast_kernel<<<(B_ * DIN_ / 4) / 256, 256, 0, stream>>>(x, xbf, B_ * DIN_);
  cast_kernel<<<(DH_ * DIN_ / 4) / 256, 256, 0, stream>>>(embed_w, ewbf, DH_ * DIN_);
  cast_kernel<<<(DOUT_ * DH_ / 4) / 256, 256, 0, stream>>>(head_w, hwbf, DOUT_ * DH_);

  // --- x_emb = x @ embed_w^T + embed_b ; h = x_emb ---
  gemm_bt<<<dim3(DH_ / 128, B_ / 128), 256, 0, stream>>>(
      xbf, ewbf, B_, DH_, DIN_, embed_b, 0, x_emb, h);

  // --- power iteration (unnormalized), W1 & W2 paired ---
  for (int it = 0; it < 15; ++it) {
    const float* vin1 = (it & 1) ? v1b : v1a;
    float* vout1 = (it & 1) ? v1a : v1b;
    const float* vin2 = (it & 1) ? v2b : v2a;
    float* vout2 = (it & 1) ? v2a : v2b;
    matvec2_kernel<<<((DFF_ + DH_) * 64) / 256, 256, 0, stream>>>(
        W1, vin1, c1, DFF_, DH_, W2, vin2, c2, DH_, DFF_);
    matvec2_kernel<<<((DH_ + DFF_) * 64) / 256, 256, 0, stream>>>(
        W1T, c1, vout1, DH_, DFF_, W2T, c2, vout2, DFF_, DH_);
  }
  sigma_rs_kernel<<<1, 256, 0, stream>>>(c1, DFF_, v1b, DH_, rs1);
  sigma_rs_kernel<<<1, 256, 0, stream>>>(c2, DH_, v2b, DFF_, rs2);
  cast_scaled_kernel<<<(DFF_ * DH_ / 4) / 256, 256, 0, stream>>>(W1, W1n, DFF_ * DH_, rs1);
  cast_scaled_kernel<<<(DH_ * DFF_ / 4) / 256, 256, 0, stream>>>(W2, W2n, DH_ * DFF_, rs2);
  // (W1T/W2T dead from here; ps aliases them)

  // --- step 0 LN (h == x_emb) ---
  ln_cast_kernel<<<B_, 256, 0, stream>>>(h, ln_g, ln_b, hn);

  // --- 30 equilibrium steps ---
  for (int s = 0; s < STEPS_; ++s) {
    // hid = tanh(hn @ W1n^T + b1)   [4096 x 4096, K=1024]
    gemm256<<<dim3(DFF_ / 256, B_ / 256, 1), 512, 0, stream>>>(
        hn, W1n, B_, DFF_, DH_, DH_, DH_ / 32, b1, 1, hid);
    // ps[z] = hid @ W2n^T (K-chunk z) [4096 x 1024, K=4096, split 4]
    gemm256<<<dim3(DH_ / 256, B_ / 256, 4), 512, 0, stream>>>(
        hid, W2n, B_, DH_, DFF_, DFF_ / 4, DFF_ / 4 / 32, nullptr, 4, ps);
    const int last = (s == STEPS_ - 1);
    reduce_ln_kernel<<<B_, 256, 0, stream>>>(
        ps, b2, x_emb, h, ln_g, ln_b, last ? hbf : hn, last ? 0 : 1);
  }

  // --- head ---
  gemm_bt<<<dim3(DOUT_ / 128, B_ / 128), 256, 0, stream>>>(
      hbf, hwbf, B_, DOUT_, DH_, head_b, 3, out, nullptr);
}

// Round 7
// 3327.404 us; speedup vs baseline: 1.8479x; 1.0039x over previous
//
#include <hip/hip_runtime.h>
#include <hip/hip_bf16.h>
#include <math.h>

#define B_    4096
#define DIN_  512
#define DH_   1024
#define DOUT_ 256
#define DFF_  4096
#define STEPS_ 30
#define GAMMA_ 0.17677669529663687f
#define LN_EPS_ 1e-5f

typedef __attribute__((ext_vector_type(8))) short short8;
typedef __attribute__((ext_vector_type(4))) float f32x4;

__device__ inline void gload_lds16(const void* g, void* l) {
  __builtin_amdgcn_global_load_lds(
      (const __attribute__((address_space(1))) unsigned int*)g,
      (__attribute__((address_space(3))) unsigned int*)l, 16, 0, 0);
}

__device__ inline float fast_tanh(float v) {
  const float e = __expf(2.f * v);
  return 1.f - 2.f * __builtin_amdgcn_rcpf(e + 1.f);
}

__device__ inline float bf2f(unsigned short u) {
  return __uint_as_float((unsigned)u << 16);
}

// ---------------------------------------------------------------------------
// 256x256-tile bf16 GEMM, 8 waves (2Mx4N), BK=64, 2x64KiB LDS double-buffer,
// 4 MFMA phases per K-tile (phase-split schedule), counted vmcnt(8),
// XOR chunk-swizzle applied BOTH sides: global source pre-swizzled
// (chunk = (lane&7)^(lane>>3)), ds_read uses p = c ^ (row&7).
// Per wave per tile: 24 ds_read_b128 (minimum), 64 MFMA, 8 gload_lds.
// C[M,N] = A[M,K] @ Bm[N,K]^T.  K-chunk per blockIdx.z: [z*kc, z*kc+nt*64).
// epi: 1 = bf16out = bf16(tanh(v + bias)); 4 = bf16 partial slab z (no bias).
// ---------------------------------------------------------------------------
__global__ __launch_bounds__(512, 2) void gemm256(
    const __hip_bfloat16* __restrict__ A, const __hip_bfloat16* __restrict__ Bm,
    int M, int N, int K, int kc, int nt, const float* __restrict__ bias,
    int epi, __hip_bfloat16* __restrict__ bf16out) {
  __shared__ __align__(16) char lds[131072];  // A[2][256][64]bf16 @0, B @65536
  const int tid = threadIdx.x;
  const int lane = tid & 63;
  const int wid = tid >> 6;
  const int wr = wid >> 2;      // 0..1  (M half: rows wr*128..+128)
  const int wc = wid & 3;       // 0..3  (N quarter: cols wc*64..+64)

  // XCD-aware bijective swizzle over x-y plane (nwg % 8 == 0 in all uses)
  const int gx = gridDim.x;
  const int nwg = gx * gridDim.y;
  const int wg = blockIdx.y * gx + blockIdx.x;
  const int cpx = nwg >> 3;
  const int swz = (wg & 7) * cpx + (wg >> 3);
  const int bx = swz % gx, by = swz / gx;
  const int m0 = by * 256, n0 = bx * 256;
  const int zk = blockIdx.z * kc;

  // stage: per instr 8 rows x 64 cols (1KB). lane l -> row +l>>3, phys chunk
  // l&7. Source column pre-inverse-swizzled so LDS phys (r,p) holds logical
  // chunk c = p ^ (r&7):
  const int scol = ((lane & 7) ^ (lane >> 3)) * 8;  // bf16 col
  const int srow = lane >> 3;

  f32x4 acc[8][4];
  const f32x4 zero = {0.f, 0.f, 0.f, 0.f};
#pragma unroll
  for (int i = 0; i < 8; ++i)
#pragma unroll
    for (int j = 0; j < 4; ++j) acc[i][j] = zero;

  auto STAGE = [&](int t) {
    const int kt = zk + t * 64;
    char* ab = &lds[(t & 1) * 32768];
    char* bb = &lds[65536 + (t & 1) * 32768];
#pragma unroll
    for (int i = 0; i < 4; ++i) {
      const int rbase = wid * 32 + i * 8;           // wave-uniform, mult of 8
      const int r = rbase + srow;
      gload_lds16(A + (size_t)(m0 + r) * K + kt + scol, ab + rbase * 128);
      gload_lds16(Bm + (size_t)(n0 + r) * K + kt + scol, bb + rbase * 128);
    }
  };

  STAGE(0);
  STAGE(1);

  const int ar = lane & 15;
  const int hi = lane >> 4;
  const int a7 = ar & 7;
  // per-lane column byte offsets for ks=0/1 (swizzled)
  const int co0 = ((0 * 4 + hi) ^ a7) * 16;
  const int co1 = ((1 * 4 + hi) ^ a7) * 16;

  for (int t = 0; t < nt; ++t) {
    const int buf = t & 1;
    const char* Ab = &lds[buf * 32768];
    const char* Bb = &lds[65536 + buf * 32768];
    const int arow = (wr * 128 + ar) * 128;
    const int brow = (wc * 64 + ar) * 128;

    if (t == nt - 1) {
      asm volatile("s_waitcnt vmcnt(0)" ::: "memory");
    } else {
      asm volatile("s_waitcnt vmcnt(8)" ::: "memory");  // tile t landed; t+1 in flight
    }
    __builtin_amdgcn_s_barrier();
    __builtin_amdgcn_sched_barrier(0);

    short8 a[4][2], b[4][2];
    // ---- P0: read A mf=0..3 + B nf=0..1; MFMA acc[0..3][0..1] ----
#pragma unroll
    for (int i = 0; i < 4; ++i) {
      a[i][0] = *(const short8*)(Ab + arow + i * 2048 + co0);
      a[i][1] = *(const short8*)(Ab + arow + i * 2048 + co1);
    }
#pragma unroll
    for (int j = 0; j < 2; ++j) {
      b[j][0] = *(const short8*)(Bb + brow + j * 2048 + co0);
      b[j][1] = *(const short8*)(Bb + brow + j * 2048 + co1);
    }
    asm volatile("s_waitcnt lgkmcnt(0)" ::: "memory");
    __builtin_amdgcn_sched_barrier(0);
    __builtin_amdgcn_s_setprio(1);
#pragma unroll
    for (int i = 0; i < 4; ++i)
#pragma unroll
      for (int j = 0; j < 2; ++j)
#pragma unroll
        for (int ks = 0; ks < 2; ++ks)
          acc[i][j] = __builtin_amdgcn_mfma_f32_16x16x32_bf16(a[i][ks], b[j][ks], acc[i][j], 0, 0, 0);
    __builtin_amdgcn_s_setprio(0);
    __builtin_amdgcn_sched_barrier(0);
    // ---- P1: read B nf=2..3; MFMA acc[0..3][2..3] ----
#pragma unroll
    for (int j = 0; j < 2; ++j) {
      b[2 + j][0] = *(const short8*)(Bb + brow + (2 + j) * 2048 + co0);
      b[2 + j][1] = *(const short8*)(Bb + brow + (2 + j) * 2048 + co1);
    }
    asm volatile("s_waitcnt lgkmcnt(0)" ::: "memory");
    __builtin_amdgcn_sched_barrier(0);
    __builtin_amdgcn_s_setprio(1);
#pragma unroll
    for (int i = 0; i < 4; ++i)
#pragma unroll
      for (int j = 0; j < 2; ++j)
#pragma unroll
        for (int ks = 0; ks < 2; ++ks)
          acc[i][2 + j] = __builtin_amdgcn_mfma_f32_16x16x32_bf16(a[i][ks], b[2 + j][ks], acc[i][2 + j], 0, 0, 0);
    __builtin_amdgcn_s_setprio(0);
    __builtin_amdgcn_sched_barrier(0);
    // ---- P2: read A mf=4..7; MFMA acc[4..7][2..3] ----
#pragma unroll
    for (int i = 0; i < 4; ++i) {
      a[i][0] = *(const short8*)(Ab + arow + (4 + i) * 2048 + co0);
      a[i][1] = *(const short8*)(Ab + arow + (4 + i) * 2048 + co1);
    }
    asm volatile("s_waitcnt lgkmcnt(0)" ::: "memory");
    __builtin_amdgcn_sched_barrier(0);
    __builtin_amdgcn_s_setprio(1);
#pragma unroll
    for (int i = 0; i < 4; ++i)
#pragma unroll
      for (int j = 0; j < 2; ++j)
#pragma unroll
        for (int ks = 0; ks < 2; ++ks)
          acc[4 + i][2 + j] = __builtin_amdgcn_mfma_f32_16x16x32_bf16(a[i][ks], b[2 + j][ks], acc[4 + i][2 + j], 0, 0, 0);
    __builtin_amdgcn_s_setprio(0);
    __builtin_amdgcn_sched_barrier(0);
    // ---- P3: no reads; MFMA acc[4..7][0..1] ----
    __builtin_amdgcn_s_setprio(1);
#pragma unroll
    for (int i = 0; i < 4; ++i)
#pragma unroll
      for (int j = 0; j < 2; ++j)
#pragma unroll
        for (int ks = 0; ks < 2; ++ks)
          acc[4 + i][j] = __builtin_amdgcn_mfma_f32_16x16x32_bf16(a[i][ks], b[j][ks], acc[4 + i][j], 0, 0, 0);
    __builtin_amdgcn_s_setprio(0);
    __builtin_amdgcn_sched_barrier(0);
    __builtin_amdgcn_s_barrier();      // all waves done reading lds[buf]
    __builtin_amdgcn_sched_barrier(0);
    if (t + 2 < nt) STAGE(t + 2);      // overwrite safe past the barrier
  }

  if (epi == 4) bf16out += (size_t)blockIdx.z * ((size_t)M * N);
  const int rb = hi * 4;
#pragma unroll
  for (int mf = 0; mf < 8; ++mf) {
#pragma unroll
    for (int nf = 0; nf < 4; ++nf) {
      const int col = n0 + wc * 64 + nf * 16 + ar;
      const float bvs = bias ? bias[col] : 0.f;
#pragma unroll
      for (int j = 0; j < 4; ++j) {
        const int row = m0 + wr * 128 + mf * 16 + rb + j;
        float v = acc[mf][nf][j] + bvs;
        if (epi == 1) v = fast_tanh(v);
        bf16out[(size_t)row * N + col] = __float2bfloat16(v);
      }
    }
  }
}

// ---------------------------------------------------------------------------
// m97-style 128x128 bf16 GEMM (kept for the one-shot embed/head GEMMs).
// epi: 0 = EMBED (write f32out=x_emb and f32out2=h); 3 = PLAIN (f32out).
// ---------------------------------------------------------------------------
__global__ __launch_bounds__(256) void gemm_bt(
    const __hip_bfloat16* __restrict__ A, const __hip_bfloat16* __restrict__ Bm,
    int M, int N, int K, const float* __restrict__ bias, int epi,
    float* __restrict__ f32out, float* __restrict__ f32out2) {
  __shared__ __align__(16) short As[128 * 32];
  __shared__ __align__(16) short Bs[128 * 32];
  const int tid = threadIdx.x;
  const int lane = tid & 63;
  const int wid = tid >> 6;
  const int wr = wid >> 1, wc = wid & 1;

  const int gx = gridDim.x;
  const int nwg = gx * gridDim.y;
  const int wg = blockIdx.y * gx + blockIdx.x;
  const int cpx = nwg >> 3;
  const int swz = (wg & 7) * cpx + (wg >> 3);
  const int bx = swz % gx, by = swz / gx;

  const int m0 = by * 128, n0 = bx * 128;
  const int ldsrow = lane >> 2;
  const int col8 = (lane & 3) * 8;

  f32x4 acc[4][4];
  const f32x4 zero = {0.f, 0.f, 0.f, 0.f};
#pragma unroll
  for (int i = 0; i < 4; ++i)
#pragma unroll
    for (int j = 0; j < 4; ++j) acc[i][j] = zero;

  for (int kt = 0; kt < K; kt += 32) {
#pragma unroll
    for (int i = 0; i < 2; ++i) {
      const int seg = wid * 2 + i;
      gload_lds16(A + (size_t)(m0 + seg * 16 + ldsrow) * K + kt + col8,
                  (void*)(As + seg * 512));
      gload_lds16(Bm + (size_t)(n0 + seg * 16 + ldsrow) * K + kt + col8,
                  (void*)(Bs + seg * 512));
    }
    __syncthreads();
    short8 a[4], b[4];
#pragma unroll
    for (int mf = 0; mf < 4; ++mf)
      a[mf] = *(const short8*)&As[(wr * 64 + mf * 16 + (lane & 15)) * 32 + (lane >> 4) * 8];
#pragma unroll
    for (int nf = 0; nf < 4; ++nf)
      b[nf] = *(const short8*)&Bs[(wc * 64 + nf * 16 + (lane & 15)) * 32 + (lane >> 4) * 8];
#pragma unroll
    for (int mf = 0; mf < 4; ++mf)
#pragma unroll
      for (int nf = 0; nf < 4; ++nf)
        acc[mf][nf] = __builtin_amdgcn_mfma_f32_16x16x32_bf16(a[mf], b[nf], acc[mf][nf], 0, 0, 0);
    __syncthreads();
  }

  const int rbase = (lane >> 4) * 4;
  const int cin = lane & 15;
#pragma unroll
  for (int mf = 0; mf < 4; ++mf) {
#pragma unroll
    for (int nf = 0; nf < 4; ++nf) {
      const int col = n0 + wc * 64 + nf * 16 + cin;
      const float bv = bias[col];
#pragma unroll
      for (int j = 0; j < 4; ++j) {
        const int row = m0 + wr * 64 + mf * 16 + rbase + j;
        const float v = acc[mf][nf][j] + bv;
        const size_t idx = (size_t)row * N + col;
        if (epi == 0) {
          f32out[idx] = v;
          f32out2[idx] = v;
        } else {
          f32out[idx] = v;
        }
      }
    }
  }
}

// ---------------------------------------------------------------------------
// Fused: h = (1-g)h + g*(sum of 4 bf16 partial slabs + b2 + x_emb);
// then LN+cast (do_ln) or plain bf16 cast (last step). Block per row.
// ---------------------------------------------------------------------------
__global__ __launch_bounds__(256) void reduce_ln_kernel(
    const __hip_bfloat16* __restrict__ ps, const float* __restrict__ b2,
    const float* __restrict__ xe, float* __restrict__ h,
    const float* __restrict__ g, const float* __restrict__ be,
    __hip_bfloat16* __restrict__ outbf, int do_ln) {
  const int row = blockIdx.x, tid = threadIdx.x;
  const size_t base = (size_t)row * DH_;
  const size_t slab = (size_t)B_ * DH_;
  float pv0 = 0.f, pv1 = 0.f, pv2 = 0.f, pv3 = 0.f;
#pragma unroll
  for (int z = 0; z < 4; ++z) {
    const ushort4 q = ((const ushort4*)(ps + z * slab + base))[tid];
    pv0 += bf2f(q.x); pv1 += bf2f(q.y); pv2 += bf2f(q.z); pv3 += bf2f(q.w);
  }
  const float4 xv = ((const float4*)(xe + base))[tid];
  const float4 hv = ((const float4*)(h + base))[tid];
  const float4 bv = ((const float4*)b2)[tid];
  float4 nv;
  nv.x = (1.f - GAMMA_) * hv.x + GAMMA_ * (pv0 + bv.x + xv.x);
  nv.y = (1.f - GAMMA_) * hv.y + GAMMA_ * (pv1 + bv.y + xv.y);
  nv.z = (1.f - GAMMA_) * hv.z + GAMMA_ * (pv2 + bv.z + xv.z);
  nv.w = (1.f - GAMMA_) * hv.w + GAMMA_ * (pv3 + bv.w + xv.w);
  ((float4*)(h + base))[tid] = nv;

  __hip_bfloat16* out = outbf + base + tid * 4;
  if (!do_ln) {
    out[0] = __float2bfloat16(nv.x);
    out[1] = __float2bfloat16(nv.y);
    out[2] = __float2bfloat16(nv.z);
    out[3] = __float2bfloat16(nv.w);
    return;
  }
  float s = nv.x + nv.y + nv.z + nv.w;
  float ss = nv.x * nv.x + nv.y * nv.y + nv.z * nv.z + nv.w * nv.w;
#pragma unroll
  for (int o = 32; o > 0; o >>= 1) {
    s += __shfl_down(s, o, 64);
    ss += __shfl_down(ss, o, 64);
  }
  __shared__ float rs_[4], rss_[4];
  const int lane = tid & 63, wid = tid >> 6;
  if (lane == 0) { rs_[wid] = s; rss_[wid] = ss; }
  __syncthreads();
  const float tot = rs_[0] + rs_[1] + rs_[2] + rs_[3];
  const float tots = rss_[0] + rss_[1] + rss_[2] + rss_[3];
  const float mu = tot * (1.f / DH_);
  const float var = tots * (1.f / DH_) - mu * mu;
  const float rstd = rsqrtf(var + LN_EPS_);
  const float4 gv = ((const float4*)g)[tid];
  const float4 bev = ((const float4*)be)[tid];
  out[0] = __float2bfloat16((nv.x - mu) * rstd * gv.x + bev.x);
  out[1] = __float2bfloat16((nv.y - mu) * rstd * gv.y + bev.y);
  out[2] = __float2bfloat16((nv.z - mu) * rstd * gv.z + bev.z);
  out[3] = __float2bfloat16((nv.w - mu) * rstd * gv.w + bev.w);
}

// ---------------------------------------------------------------------------
// LayerNorm + cast (step 0 only).
// ---------------------------------------------------------------------------
__global__ __launch_bounds__(256) void ln_cast_kernel(
    const float* __restrict__ h, const float* __restrict__ g,
    const float* __restrict__ be, __hip_bfloat16* __restrict__ hn) {
  const int row = blockIdx.x;
  const int tid = threadIdx.x;
  const float4 v = ((const float4*)(h + (size_t)row * DH_))[tid];
  float s = v.x + v.y + v.z + v.w;
  float ss = v.x * v.x + v.y * v.y + v.z * v.z + v.w * v.w;
#pragma unroll
  for (int o = 32; o > 0; o >>= 1) {
    s += __shfl_down(s, o, 64);
    ss += __shfl_down(ss, o, 64);
  }
  __shared__ float rs_[4], rss_[4];
  const int lane = tid & 63, wid = tid >> 6;
  if (lane == 0) { rs_[wid] = s; rss_[wid] = ss; }
  __syncthreads();
  const float tot = rs_[0] + rs_[1] + rs_[2] + rs_[3];
  const float tots = rss_[0] + rss_[1] + rss_[2] + rss_[3];
  const float mu = tot * (1.f / DH_);
  const float var = tots * (1.f / DH_) - mu * mu;
  const float rstd = rsqrtf(var + LN_EPS_);
  const float4 gv = ((const float4*)g)[tid];
  const float4 bv = ((const float4*)be)[tid];
  __hip_bfloat16* out = hn + (size_t)row * DH_ + tid * 4;
  out[0] = __float2bfloat16((v.x - mu) * rstd * gv.x + bv.x);
  out[1] = __float2bfloat16((v.y - mu) * rstd * gv.y + bv.y);
  out[2] = __float2bfloat16((v.z - mu) * rstd * gv.z + bv.z);
  out[3] = __float2bfloat16((v.w - mu) * rstd * gv.w + bv.w);
}

// ---------------------------------------------------------------------------
// Paired fp32 matvec (power iteration).
// ---------------------------------------------------------------------------
__global__ __launch_bounds__(256) void matvec2_kernel(
    const float* __restrict__ Wa, const float* __restrict__ xa,
    float* __restrict__ ya, int rowsA, int colsA,
    const float* __restrict__ Wb, const float* __restrict__ xb,
    float* __restrict__ yb, int rowsB, int colsB) {
  const int gw = (int)(blockIdx.x * 256 + threadIdx.x) >> 6;
  const int lane = threadIdx.x & 63;
  const float* W;
  const float* x;
  float* y;
  int row, cols;
  if (gw < rowsA) {
    W = Wa; x = xa; y = ya; row = gw; cols = colsA;
  } else {
    row = gw - rowsA;
    if (row >= rowsB) return;
    W = Wb; x = xb; y = yb; cols = colsB;
  }
  const float4* wr = (const float4*)(W + (size_t)row * cols);
  const float4* xv = (const float4*)x;
  const int n4 = cols >> 2;
  float s = 0.f;
  for (int c = lane; c < n4; c += 64) {
    const float4 wv = wr[c];
    const float4 vv = xv[c];
    s += wv.x * vv.x + wv.y * vv.y + wv.z * vv.z + wv.w * vv.w;
  }
#pragma unroll
  for (int o = 32; o > 0; o >>= 1) s += __shfl_down(s, o, 64);
  if (lane == 0) y[row] = s;
}

__global__ __launch_bounds__(256) void transpose_kernel(
    const float* __restrict__ in, float* __restrict__ out, int R, int C) {
  __shared__ float t[32][33];
  const int lx = threadIdx.x & 31, ly = threadIdx.x >> 5;
  const int r0 = blockIdx.y * 32, c0 = blockIdx.x * 32;
#pragma unroll
  for (int j = 0; j < 32; j += 8) t[ly + j][lx] = in[(size_t)(r0 + ly + j) * C + c0 + lx];
  __syncthreads();
#pragma unroll
  for (int j = 0; j < 32; j += 8) out[(size_t)(c0 + ly + j) * R + r0 + lx] = t[lx][ly + j];
}

__global__ void init_v_kernel(float* v1, float* v2) {
  const int i = blockIdx.x * 256 + threadIdx.x;
  if (i < 1024) v1[i] = 0.03125f;
  if (i < 4096) v2[i] = 0.015625f;
}

__global__ __launch_bounds__(256) void cast_kernel(
    const float* __restrict__ s, __hip_bfloat16* __restrict__ d, int n) {
  const int b = (blockIdx.x * 256 + threadIdx.x) * 4;
  if (b < n) {
    const float4 v = *(const float4*)(s + b);
    d[b] = __float2bfloat16(v.x);
    d[b + 1] = __float2bfloat16(v.y);
    d[b + 2] = __float2bfloat16(v.z);
    d[b + 3] = __float2bfloat16(v.w);
  }
}

__global__ __launch_bounds__(256) void cast_scaled_kernel(
    const float* __restrict__ s, __hip_bfloat16* __restrict__ d, int n,
    const float* __restrict__ rs) {
  const float r = rs[0];
  const int b = (blockIdx.x * 256 + threadIdx.x) * 4;
  if (b < n) {
    const float4 v = *(const float4*)(s + b);
    d[b] = __float2bfloat16(v.x * r);
    d[b + 1] = __float2bfloat16(v.y * r);
    d[b + 2] = __float2bfloat16(v.z * r);
    d[b + 3] = __float2bfloat16(v.w * r);
  }
}

// rs = |c| / |d|  (= 1/sigma)
__global__ __launch_bounds__(256) void sigma_rs_kernel(
    const float* __restrict__ c, int m, const float* __restrict__ dv, int n,
    float* __restrict__ rs) {
  const int tid = threadIdx.x;
  float sc = 0.f, sd = 0.f;
  for (int i = tid; i < m; i += 256) { const float v = c[i]; sc += v * v; }
  for (int i = tid; i < n; i += 256) { const float v = dv[i]; sd += v * v; }
#pragma unroll
  for (int o = 32; o > 0; o >>= 1) {
    sc += __shfl_down(sc, o, 64);
    sd += __shfl_down(sd, o, 64);
  }
  __shared__ float a[4], b[4];
  const int lane = tid & 63, wid = tid >> 6;
  if (lane == 0) { a[wid] = sc; b[wid] = sd; }
  __syncthreads();
  if (tid == 0) {
    const float tc = a[0] + a[1] + a[2] + a[3];
    const float td = b[0] + b[1] + b[2] + b[3];
    rs[0] = sqrtf(tc / td);
  }
}

extern "C" void kernel_launch(void* const* d_in, const int* in_sizes, int n_in,
                              void* d_out, int out_size, void* d_ws, size_t ws_size,
                              hipStream_t stream) {
  const float* x       = (const float*)d_in[0];
  const float* embed_w = (const float*)d_in[1];
  const float* embed_b = (const float*)d_in[2];
  const float* W1      = (const float*)d_in[3];
  const float* b1      = (const float*)d_in[4];
  const float* W2      = (const float*)d_in[5];
  const float* b2      = (const float*)d_in[6];
  const float* ln_g    = (const float*)d_in[7];
  const float* ln_b    = (const float*)d_in[8];
  const float* head_w  = (const float*)d_in[9];
  const float* head_b  = (const float*)d_in[10];
  float* out = (float*)d_out;

  char* p = (char*)d_ws;
  auto carve = [&](size_t bytes) {
    char* r = p;
    p += (bytes + 255) & ~(size_t)255;
    return (void*)r;
  };
  float* h     = (float*)carve((size_t)B_ * DH_ * 4);
  float* x_emb = (float*)carve((size_t)B_ * DH_ * 4);
  // W1T/W2T (33.6 MB) are dead after the power iteration; the 4 bf16 K-split
  // partial slabs (4 x 8.4 MB = 33.6 MB) alias this region during the steps.
  float* W1T   = (float*)carve((size_t)DFF_ * DH_ * 4);
  float* W2T   = (float*)carve((size_t)DH_ * DFF_ * 4);
  __hip_bfloat16* ps = (__hip_bfloat16*)W1T;  // [4][B_][DH_] bf16
  __hip_bfloat16* hn   = (__hip_bfloat16*)carve((size_t)B_ * DH_ * 2);
  __hip_bfloat16* hid  = (__hip_bfloat16*)carve((size_t)B_ * DFF_ * 2);
  __hip_bfloat16* W1n  = (__hip_bfloat16*)carve((size_t)DFF_ * DH_ * 2);
  __hip_bfloat16* W2n  = (__hip_bfloat16*)carve((size_t)DH_ * DFF_ * 2);
  __hip_bfloat16* xbf  = (__hip_bfloat16*)carve((size_t)B_ * DIN_ * 2);
  __hip_bfloat16* ewbf = (__hip_bfloat16*)carve((size_t)DH_ * DIN_ * 2);
  __hip_bfloat16* hwbf = (__hip_bfloat16*)carve((size_t)DOUT_ * DH_ * 2);
  __hip_bfloat16* hbf  = (__hip_bfloat16*)carve((size_t)B_ * DH_ * 2);
  float* v1a = (float*)carve(4096 * 4);
  float* v1b = (float*)carve(4096 * 4);
  float* c1  = (float*)carve(4096 * 4);
  float* v2a = (float*)carve(4096 * 4);
  float* v2b = (float*)carve(4096 * 4);
  float* c2  = (float*)carve(4096 * 4);
  float* rs1 = (float*)carve(256);
  float* rs2 = (float*)carve(256);

  // --- prep: transposes, inits, input casts ---
  transpose_kernel<<<dim3(DH_ / 32, DFF_ / 32), 256, 0, stream>>>(W1, W1T, DFF_, DH_);
  transpose_kernel<<<dim3(DFF_ / 32, DH_ / 32), 256, 0, stream>>>(W2, W2T, DH_, DFF_);
  init_v_kernel<<<16, 256, 0, stream>>>(v1a, v2a);
  cast_kernel<<<(B_ * DIN_ / 4) / 256, 256, 0, stream>>>(x, xbf, B_ * DIN_);
  cast_kernel<<<(DH_ * DIN_ / 4) / 256, 256, 0, stream>>>(embed_w, ewbf, DH_ * DIN_);
  cast_kernel<<<(DOUT_ * DH_ / 4) / 256, 256, 0, stream>>>(head_w, hwbf, DOUT_ * DH_);

  // --- x_emb = x @ embed_w^T + embed_b ; h = x_emb ---
  gemm_bt<<<dim3(DH_ / 128, B_ / 128), 256, 0, stream>>>(
      xbf, ewbf, B_, DH_, DIN_, embed_b, 0, x_emb, h);

  // --- power iteration (unnormalized), W1 & W2 paired ---
  for (int it = 0; it < 15; ++it) {
    const float* vin1 = (it & 1) ? v1b : v1a;
    float* vout1 = (it & 1) ? v1a : v1b;
    const float* vin2 = (it & 1) ? v2b : v2a;
    float* vout2 = (it & 1) ? v2a : v2b;
    matvec2_kernel<<<((DFF_ + DH_) * 64) / 256, 256, 0, stream>>>(
        W1, vin1, c1, DFF_, DH_, W2, vin2, c2, DH_, DFF_);
    matvec2_kernel<<<((DH_ + DFF_) * 64) / 256, 256, 0, stream>>>(
        W1T, c1, vout1, DH_, DFF_, W2T, c2, vout2, DFF_, DH_);
  }
  sigma_rs_kernel<<<1, 256, 0, stream>>>(c1, DFF_, v1b, DH_, rs1);
  sigma_rs_kernel<<<1, 256, 0, stream>>>(c2, DH_, v2b, DFF_, rs2);
  cast_scaled_kernel<<<(DFF_ * DH_ / 4) / 256, 256, 0, stream>>>(W1, W1n, DFF_ * DH_, rs1);
  cast_scaled_kernel<<<(DH_ * DFF_ / 4) / 256, 256, 0, stream>>>(W2, W2n, DH_ * DFF_, rs2);
  // (W1T/W2T dead from here; ps aliases them)

  // --- step 0 LN (h == x_emb) ---
  ln_cast_kernel<<<B_, 256, 0, stream>>>(h, ln_g, ln_b, hn);

  // --- 30 equilibrium steps ---
  for (int s = 0; s < STEPS_; ++s) {
    // hid = tanh(hn @ W1n^T + b1)   [4096 x 4096, K=1024]
    gemm256<<<dim3(DFF_ / 256, B_ / 256, 1), 512, 0, stream>>>(
        hn, W1n, B_, DFF_, DH_, DH_, DH_ / 64, b1, 1, hid);
    // ps[z] = hid @ W2n^T (K-chunk z) [4096 x 1024, K=4096, split 4]
    gemm256<<<dim3(DH_ / 256, B_ / 256, 4), 512, 0, stream>>>(
        hid, W2n, B_, DH_, DFF_, DFF_ / 4, DFF_ / 4 / 64, nullptr, 4, ps);
    const int last = (s == STEPS_ - 1);
    reduce_ln_kernel<<<B_, 256, 0, stream>>>(
        ps, b2, x_emb, h, ln_g, ln_b, last ? hbf : hn, last ? 0 : 1);
  }

  // --- head ---
  gemm_bt<<<dim3(DOUT_ / 128, B_ / 128), 256, 0, stream>>>(
      hbf, hwbf, B_, DOUT_, DH_, head_b, 3, out, nullptr);
}

// Round 8
// 3267.548 us; speedup vs baseline: 1.8818x; 1.0183x over previous
//
#include <hip/hip_runtime.h>
#include <hip/hip_bf16.h>
#include <math.h>

#define B_    4096
#define DIN_  512
#define DH_   1024
#define DOUT_ 256
#define DFF_  4096
#define STEPS_ 30
#define GAMMA_ 0.17677669529663687f
#define LN_EPS_ 1e-5f

typedef __attribute__((ext_vector_type(8))) short short8;
typedef __attribute__((ext_vector_type(4))) float f32x4;

__device__ inline void gload_lds16(const void* g, void* l) {
  __builtin_amdgcn_global_load_lds(
      (const __attribute__((address_space(1))) unsigned int*)g,
      (__attribute__((address_space(3))) unsigned int*)l, 16, 0, 0);
}

__device__ inline float fast_tanh(float v) {
  const float e = __expf(2.f * v);
  return 1.f - 2.f * __builtin_amdgcn_rcpf(e + 1.f);
}

__device__ inline float bf2f(unsigned short u) {
  return __uint_as_float((unsigned)u << 16);
}

// ---------------------------------------------------------------------------
// 256x256-tile bf16 GEMM, 8 waves (2Mx4N), BK=64, 2x64KiB LDS double-buffer,
// m201-style 8-phase schedule: each phase = {ds_read fragments, stage 1
// half-tile, [lgkmcnt(8) if 12 reads], BARRIER, lgkmcnt(0), setprio(1),
// 16 MFMA, setprio(0), BARRIER}.  Counted vmcnt(4) only at P4/P8 (vmcnt(0)
// at P4 of the last iteration).  XOR chunk-swizzle both sides (verified 0
// bank conflicts in r7).  2 K-tiles per iteration.
// C[M,N] = A[M,K] @ Bm[N,K]^T.  K-chunk per blockIdx.z: [z*kc, z*kc+nt*64).
// epi: 1 = bf16out = bf16(tanh(v + bias)); 4 = bf16 partial slab z (no bias).
// nt must be even and >= 4.
// ---------------------------------------------------------------------------
__global__ __launch_bounds__(512, 2) void gemm256(
    const __hip_bfloat16* __restrict__ A, const __hip_bfloat16* __restrict__ Bm,
    int M, int N, int K, int kc, int nt, const float* __restrict__ bias,
    int epi, __hip_bfloat16* __restrict__ bf16out) {
  // buf b at b*65536: A[256][64]bf16 at +0, B[256][64] at +32768
  __shared__ __align__(16) char lds[131072];
  const int tid = threadIdx.x;
  const int lane = tid & 63;
  const int wid = tid >> 6;
  const int wr = wid >> 2;      // 0..1  (M half: rows wr*128..+128)
  const int wc = wid & 3;       // 0..3  (N quarter: cols wc*64..+64)

  // XCD-aware bijective swizzle over x-y plane (nwg % 8 == 0 in all uses)
  const int gx = gridDim.x;
  const int nwg = gx * gridDim.y;
  const int wg = blockIdx.y * gx + blockIdx.x;
  const int cpx = nwg >> 3;
  const int swz = (wg & 7) * cpx + (wg >> 3);
  const int bx = swz % gx, by = swz / gx;
  const int m0 = by * 256, n0 = bx * 256;
  const int zk = blockIdx.z * kc;

  // stage addressing: per instr 8 rows x 64 cols (1KB). lane l -> row +(l>>3),
  // phys chunk l&7; global col pre-inverse-swizzled so LDS phys (r,p) holds
  // logical chunk c = p ^ (r&7).
  const int scol = ((lane & 7) ^ (lane >> 3)) * 8;  // bf16 col
  const int srow = lane >> 3;

  f32x4 acc[8][4];
  const f32x4 zero = {0.f, 0.f, 0.f, 0.f};
#pragma unroll
  for (int i = 0; i < 8; ++i)
#pragma unroll
    for (int j = 0; j < 4; ++j) acc[i][j] = zero;

  // stage one half-tile (128 rows) of K-tile t: hrow in {0,128}, isB selects B.
  // 2 gload_lds per wave (16 rows each).
  auto STG = [&](int t, int hrow, int isB) {
    if (t >= nt) return;
    const int kt = zk + t * 64;
    char* base = &lds[(t & 1) * 65536 + isB * 32768];
#pragma unroll
    for (int j = 0; j < 2; ++j) {
      const int rbase = hrow + wid * 16 + j * 8;   // wave-uniform, mult of 8
      const int r = rbase + srow;
      const __hip_bfloat16* s =
          isB ? Bm + (size_t)(n0 + r) * K + kt + scol
              : A + (size_t)(m0 + r) * K + kt + scol;
      gload_lds16((const void*)s, (void*)(base + rbase * 128));
    }
  };

  // prologue: tile0 fully + tile1's B (tile1's A staged at P1/P2 of iter 0)
  STG(0, 0, 1); STG(0, 128, 1); STG(0, 0, 0); STG(0, 128, 0);
  STG(1, 0, 1); STG(1, 128, 1);
  asm volatile("s_waitcnt vmcnt(0)" ::: "memory");
  __builtin_amdgcn_s_barrier();

  const int ar = lane & 15;
  const int hi = lane >> 4;
  const int a7 = ar & 7;
  const int co0 = (hi ^ a7) * 16;        // ks=0 chunk (swizzled)
  const int co1 = ((4 + hi) ^ a7) * 16;  // ks=1 chunk

  const char* Ab0 = &lds[0];
  const char* Bb0 = &lds[32768];
  const char* Ab1 = &lds[65536];
  const char* Bb1 = &lds[98304];
  const int arow = (wr * 128 + ar) * 128;
  const int brow = (wc * 64 + ar) * 128;

  const int niter = nt >> 1;
  for (int it = 0; it < niter; ++it) {
    const int t0 = it * 2;
    const bool lastit = (it == niter - 1);
    short8 a[4][2], b[4][2];

    // ======================= tile t0 (buf0) =======================
    // ---- P1: reads a0-3,b0-1; stage A-lo(t0+1); MFMA Q00 ----
#pragma unroll
    for (int i = 0; i < 4; ++i) {
      a[i][0] = *(const short8*)(Ab0 + arow + i * 2048 + co0);
      a[i][1] = *(const short8*)(Ab0 + arow + i * 2048 + co1);
    }
#pragma unroll
    for (int j = 0; j < 2; ++j) {
      b[j][0] = *(const short8*)(Bb0 + brow + j * 2048 + co0);
      b[j][1] = *(const short8*)(Bb0 + brow + j * 2048 + co1);
    }
    STG(t0 + 1, 0, 0);
    asm volatile("s_waitcnt lgkmcnt(8)" ::: "memory");
    __builtin_amdgcn_sched_barrier(0);
    __builtin_amdgcn_s_barrier();
    asm volatile("s_waitcnt lgkmcnt(0)" ::: "memory");
    __builtin_amdgcn_sched_barrier(0);
    __builtin_amdgcn_s_setprio(1);
#pragma unroll
    for (int i = 0; i < 4; ++i)
#pragma unroll
      for (int j = 0; j < 2; ++j)
#pragma unroll
        for (int ks = 0; ks < 2; ++ks)
          acc[i][j] = __builtin_amdgcn_mfma_f32_16x16x32_bf16(a[i][ks], b[j][ks], acc[i][j], 0, 0, 0);
    __builtin_amdgcn_s_setprio(0);
    __builtin_amdgcn_sched_barrier(0);
    __builtin_amdgcn_s_barrier();

    // ---- P2: reads b2-3; stage A-hi(t0+1); MFMA Q01 ----
#pragma unroll
    for (int j = 0; j < 2; ++j) {
      b[2 + j][0] = *(const short8*)(Bb0 + brow + (2 + j) * 2048 + co0);
      b[2 + j][1] = *(const short8*)(Bb0 + brow + (2 + j) * 2048 + co1);
    }
    STG(t0 + 1, 128, 0);
    __builtin_amdgcn_sched_barrier(0);
    __builtin_amdgcn_s_barrier();
    asm volatile("s_waitcnt lgkmcnt(0)" ::: "memory");
    __builtin_amdgcn_sched_barrier(0);
    __builtin_amdgcn_s_setprio(1);
#pragma unroll
    for (int i = 0; i < 4; ++i)
#pragma unroll
      for (int j = 0; j < 2; ++j)
#pragma unroll
        for (int ks = 0; ks < 2; ++ks)
          acc[i][2 + j] = __builtin_amdgcn_mfma_f32_16x16x32_bf16(a[i][ks], b[2 + j][ks], acc[i][2 + j], 0, 0, 0);
    __builtin_amdgcn_s_setprio(0);
    __builtin_amdgcn_sched_barrier(0);
    __builtin_amdgcn_s_barrier();

    // ---- P3: reads a4-7; stage B-lo(t0+2); MFMA Q11(hi) ----
#pragma unroll
    for (int i = 0; i < 4; ++i) {
      a[i][0] = *(const short8*)(Ab0 + arow + (4 + i) * 2048 + co0);
      a[i][1] = *(const short8*)(Ab0 + arow + (4 + i) * 2048 + co1);
    }
    STG(t0 + 2, 0, 1);
    __builtin_amdgcn_sched_barrier(0);
    __builtin_amdgcn_s_barrier();
    asm volatile("s_waitcnt lgkmcnt(0)" ::: "memory");
    __builtin_amdgcn_sched_barrier(0);
    __builtin_amdgcn_s_setprio(1);
#pragma unroll
    for (int i = 0; i < 4; ++i)
#pragma unroll
      for (int j = 0; j < 2; ++j)
#pragma unroll
        for (int ks = 0; ks < 2; ++ks)
          acc[4 + i][2 + j] = __builtin_amdgcn_mfma_f32_16x16x32_bf16(a[i][ks], b[2 + j][ks], acc[4 + i][2 + j], 0, 0, 0);
    __builtin_amdgcn_s_setprio(0);
    __builtin_amdgcn_sched_barrier(0);
    __builtin_amdgcn_s_barrier();

    // ---- P4: no reads; stage B-hi(t0+2); vmcnt gate for t0+1; MFMA Q10(lo) ----
    STG(t0 + 2, 128, 1);
    if (lastit) {
      asm volatile("s_waitcnt vmcnt(0)" ::: "memory");
    } else {
      asm volatile("s_waitcnt vmcnt(4)" ::: "memory");
    }
    __builtin_amdgcn_sched_barrier(0);
    __builtin_amdgcn_s_barrier();
    __builtin_amdgcn_s_setprio(1);
#pragma unroll
    for (int i = 0; i < 4; ++i)
#pragma unroll
      for (int j = 0; j < 2; ++j)
#pragma unroll
        for (int ks = 0; ks < 2; ++ks)
          acc[4 + i][j] = __builtin_amdgcn_mfma_f32_16x16x32_bf16(a[i][ks], b[j][ks], acc[4 + i][j], 0, 0, 0);
    __builtin_amdgcn_s_setprio(0);
    __builtin_amdgcn_sched_barrier(0);
    __builtin_amdgcn_s_barrier();

    // ======================= tile t0+1 (buf1) =======================
    // ---- P5: reads a0-3,b0-1; stage A-lo(t0+2); MFMA Q00 ----
#pragma unroll
    for (int i = 0; i < 4; ++i) {
      a[i][0] = *(const short8*)(Ab1 + arow + i * 2048 + co0);
      a[i][1] = *(const short8*)(Ab1 + arow + i * 2048 + co1);
    }
#pragma unroll
    for (int j = 0; j < 2; ++j) {
      b[j][0] = *(const short8*)(Bb1 + brow + j * 2048 + co0);
      b[j][1] = *(const short8*)(Bb1 + brow + j * 2048 + co1);
    }
    STG(t0 + 2, 0, 0);
    asm volatile("s_waitcnt lgkmcnt(8)" ::: "memory");
    __builtin_amdgcn_sched_barrier(0);
    __builtin_amdgcn_s_barrier();
    asm volatile("s_waitcnt lgkmcnt(0)" ::: "memory");
    __builtin_amdgcn_sched_barrier(0);
    __builtin_amdgcn_s_setprio(1);
#pragma unroll
    for (int i = 0; i < 4; ++i)
#pragma unroll
      for (int j = 0; j < 2; ++j)
#pragma unroll
        for (int ks = 0; ks < 2; ++ks)
          acc[i][j] = __builtin_amdgcn_mfma_f32_16x16x32_bf16(a[i][ks], b[j][ks], acc[i][j], 0, 0, 0);
    __builtin_amdgcn_s_setprio(0);
    __builtin_amdgcn_sched_barrier(0);
    __builtin_amdgcn_s_barrier();

    // ---- P6: reads b2-3; stage A-hi(t0+2); MFMA Q01 ----
#pragma unroll
    for (int j = 0; j < 2; ++j) {
      b[2 + j][0] = *(const short8*)(Bb1 + brow + (2 + j) * 2048 + co0);
      b[2 + j][1] = *(const short8*)(Bb1 + brow + (2 + j) * 2048 + co1);
    }
    STG(t0 + 2, 128, 0);
    __builtin_amdgcn_sched_barrier(0);
    __builtin_amdgcn_s_barrier();
    asm volatile("s_waitcnt lgkmcnt(0)" ::: "memory");
    __builtin_amdgcn_sched_barrier(0);
    __builtin_amdgcn_s_setprio(1);
#pragma unroll
    for (int i = 0; i < 4; ++i)
#pragma unroll
      for (int j = 0; j < 2; ++j)
#pragma unroll
        for (int ks = 0; ks < 2; ++ks)
          acc[i][2 + j] = __builtin_amdgcn_mfma_f32_16x16x32_bf16(a[i][ks], b[2 + j][ks], acc[i][2 + j], 0, 0, 0);
    __builtin_amdgcn_s_setprio(0);
    __builtin_amdgcn_sched_barrier(0);
    __builtin_amdgcn_s_barrier();

    // ---- P7: reads a4-7; stage B-lo(t0+3); MFMA Q11(hi) ----
#pragma unroll
    for (int i = 0; i < 4; ++i) {
      a[i][0] = *(const short8*)(Ab1 + arow + (4 + i) * 2048 + co0);
      a[i][1] = *(const short8*)(Ab1 + arow + (4 + i) * 2048 + co1);
    }
    STG(t0 + 3, 0, 1);
    __builtin_amdgcn_sched_barrier(0);
    __builtin_amdgcn_s_barrier();
    asm volatile("s_waitcnt lgkmcnt(0)" ::: "memory");
    __builtin_amdgcn_sched_barrier(0);
    __builtin_amdgcn_s_setprio(1);
#pragma unroll
    for (int i = 0; i < 4; ++i)
#pragma unroll
      for (int j = 0; j < 2; ++j)
#pragma unroll
        for (int ks = 0; ks < 2; ++ks)
          acc[4 + i][2 + j] = __builtin_amdgcn_mfma_f32_16x16x32_bf16(a[i][ks], b[2 + j][ks], acc[4 + i][2 + j], 0, 0, 0);
    __builtin_amdgcn_s_setprio(0);
    __builtin_amdgcn_sched_barrier(0);
    __builtin_amdgcn_s_barrier();

    // ---- P8: no reads; stage B-hi(t0+3); vmcnt gate for t0+2; MFMA Q10(lo) ----
    STG(t0 + 3, 128, 1);
    asm volatile("s_waitcnt vmcnt(4)" ::: "memory");
    __builtin_amdgcn_sched_barrier(0);
    __builtin_amdgcn_s_barrier();
    __builtin_amdgcn_s_setprio(1);
#pragma unroll
    for (int i = 0; i < 4; ++i)
#pragma unroll
      for (int j = 0; j < 2; ++j)
#pragma unroll
        for (int ks = 0; ks < 2; ++ks)
          acc[4 + i][j] = __builtin_amdgcn_mfma_f32_16x16x32_bf16(a[i][ks], b[j][ks], acc[4 + i][j], 0, 0, 0);
    __builtin_amdgcn_s_setprio(0);
    __builtin_amdgcn_sched_barrier(0);
    __builtin_amdgcn_s_barrier();
  }

  if (epi == 4) bf16out += (size_t)blockIdx.z * ((size_t)M * N);
  const int rb = hi * 4;
#pragma unroll
  for (int mf = 0; mf < 8; ++mf) {
#pragma unroll
    for (int nf = 0; nf < 4; ++nf) {
      const int col = n0 + wc * 64 + nf * 16 + ar;
      const float bvs = bias ? bias[col] : 0.f;
#pragma unroll
      for (int j = 0; j < 4; ++j) {
        const int row = m0 + wr * 128 + mf * 16 + rb + j;
        float v = acc[mf][nf][j] + bvs;
        if (epi == 1) v = fast_tanh(v);
        bf16out[(size_t)row * N + col] = __float2bfloat16(v);
      }
    }
  }
}

// ---------------------------------------------------------------------------
// m97-style 128x128 bf16 GEMM (kept for the one-shot embed/head GEMMs).
// epi: 0 = EMBED (write f32out=x_emb and f32out2=h); 3 = PLAIN (f32out).
// ---------------------------------------------------------------------------
__global__ __launch_bounds__(256) void gemm_bt(
    const __hip_bfloat16* __restrict__ A, const __hip_bfloat16* __restrict__ Bm,
    int M, int N, int K, const float* __restrict__ bias, int epi,
    float* __restrict__ f32out, float* __restrict__ f32out2) {
  __shared__ __align__(16) short As[128 * 32];
  __shared__ __align__(16) short Bs[128 * 32];
  const int tid = threadIdx.x;
  const int lane = tid & 63;
  const int wid = tid >> 6;
  const int wr = wid >> 1, wc = wid & 1;

  const int gx = gridDim.x;
  const int nwg = gx * gridDim.y;
  const int wg = blockIdx.y * gx + blockIdx.x;
  const int cpx = nwg >> 3;
  const int swz = (wg & 7) * cpx + (wg >> 3);
  const int bx = swz % gx, by = swz / gx;

  const int m0 = by * 128, n0 = bx * 128;
  const int ldsrow = lane >> 2;
  const int col8 = (lane & 3) * 8;

  f32x4 acc[4][4];
  const f32x4 zero = {0.f, 0.f, 0.f, 0.f};
#pragma unroll
  for (int i = 0; i < 4; ++i)
#pragma unroll
    for (int j = 0; j < 4; ++j) acc[i][j] = zero;

  for (int kt = 0; kt < K; kt += 32) {
#pragma unroll
    for (int i = 0; i < 2; ++i) {
      const int seg = wid * 2 + i;
      gload_lds16(A + (size_t)(m0 + seg * 16 + ldsrow) * K + kt + col8,
                  (void*)(As + seg * 512));
      gload_lds16(Bm + (size_t)(n0 + seg * 16 + ldsrow) * K + kt + col8,
                  (void*)(Bs + seg * 512));
    }
    __syncthreads();
    short8 a[4], b[4];
#pragma unroll
    for (int mf = 0; mf < 4; ++mf)
      a[mf] = *(const short8*)&As[(wr * 64 + mf * 16 + (lane & 15)) * 32 + (lane >> 4) * 8];
#pragma unroll
    for (int nf = 0; nf < 4; ++nf)
      b[nf] = *(const short8*)&Bs[(wc * 64 + nf * 16 + (lane & 15)) * 32 + (lane >> 4) * 8];
#pragma unroll
    for (int mf = 0; mf < 4; ++mf)
#pragma unroll
      for (int nf = 0; nf < 4; ++nf)
        acc[mf][nf] = __builtin_amdgcn_mfma_f32_16x16x32_bf16(a[mf], b[nf], acc[mf][nf], 0, 0, 0);
    __syncthreads();
  }

  const int rbase = (lane >> 4) * 4;
  const int cin = lane & 15;
#pragma unroll
  for (int mf = 0; mf < 4; ++mf) {
#pragma unroll
    for (int nf = 0; nf < 4; ++nf) {
      const int col = n0 + wc * 64 + nf * 16 + cin;
      const float bv = bias[col];
#pragma unroll
      for (int j = 0; j < 4; ++j) {
        const int row = m0 + wr * 64 + mf * 16 + rbase + j;
        const float v = acc[mf][nf][j] + bv;
        const size_t idx = (size_t)row * N + col;
        if (epi == 0) {
          f32out[idx] = v;
          f32out2[idx] = v;
        } else {
          f32out[idx] = v;
        }
      }
    }
  }
}

// ---------------------------------------------------------------------------
// Fused: h = (1-g)h + g*(sum of 4 bf16 partial slabs + b2 + x_emb);
// then LN+cast (do_ln) or plain bf16 cast (last step). Block per row.
// ---------------------------------------------------------------------------
__global__ __launch_bounds__(256) void reduce_ln_kernel(
    const __hip_bfloat16* __restrict__ ps, const float* __restrict__ b2,
    const float* __restrict__ xe, float* __restrict__ h,
    const float* __restrict__ g, const float* __restrict__ be,
    __hip_bfloat16* __restrict__ outbf, int do_ln) {
  const int row = blockIdx.x, tid = threadIdx.x;
  const size_t base = (size_t)row * DH_;
  const size_t slab = (size_t)B_ * DH_;
  float pv0 = 0.f, pv1 = 0.f, pv2 = 0.f, pv3 = 0.f;
#pragma unroll
  for (int z = 0; z < 4; ++z) {
    const ushort4 q = ((const ushort4*)(ps + z * slab + base))[tid];
    pv0 += bf2f(q.x); pv1 += bf2f(q.y); pv2 += bf2f(q.z); pv3 += bf2f(q.w);
  }
  const float4 xv = ((const float4*)(xe + base))[tid];
  const float4 hv = ((const float4*)(h + base))[tid];
  const float4 bv = ((const float4*)b2)[tid];
  float4 nv;
  nv.x = (1.f - GAMMA_) * hv.x + GAMMA_ * (pv0 + bv.x + xv.x);
  nv.y = (1.f - GAMMA_) * hv.y + GAMMA_ * (pv1 + bv.y + xv.y);
  nv.z = (1.f - GAMMA_) * hv.z + GAMMA_ * (pv2 + bv.z + xv.z);
  nv.w = (1.f - GAMMA_) * hv.w + GAMMA_ * (pv3 + bv.w + xv.w);
  ((float4*)(h + base))[tid] = nv;

  __hip_bfloat16* out = outbf + base + tid * 4;
  if (!do_ln) {
    out[0] = __float2bfloat16(nv.x);
    out[1] = __float2bfloat16(nv.y);
    out[2] = __float2bfloat16(nv.z);
    out[3] = __float2bfloat16(nv.w);
    return;
  }
  float s = nv.x + nv.y + nv.z + nv.w;
  float ss = nv.x * nv.x + nv.y * nv.y + nv.z * nv.z + nv.w * nv.w;
#pragma unroll
  for (int o = 32; o > 0; o >>= 1) {
    s += __shfl_down(s, o, 64);
    ss += __shfl_down(ss, o, 64);
  }
  __shared__ float rs_[4], rss_[4];
  const int lane = tid & 63, wid = tid >> 6;
  if (lane == 0) { rs_[wid] = s; rss_[wid] = ss; }
  __syncthreads();
  const float tot = rs_[0] + rs_[1] + rs_[2] + rs_[3];
  const float tots = rss_[0] + rss_[1] + rss_[2] + rss_[3];
  const float mu = tot * (1.f / DH_);
  const float var = tots * (1.f / DH_) - mu * mu;
  const float rstd = rsqrtf(var + LN_EPS_);
  const float4 gv = ((const float4*)g)[tid];
  const float4 bev = ((const float4*)be)[tid];
  out[0] = __float2bfloat16((nv.x - mu) * rstd * gv.x + bev.x);
  out[1] = __float2bfloat16((nv.y - mu) * rstd * gv.y + bev.y);
  out[2] = __float2bfloat16((nv.z - mu) * rstd * gv.z + bev.z);
  out[3] = __float2bfloat16((nv.w - mu) * rstd * gv.w + bev.w);
}

// ---------------------------------------------------------------------------
// LayerNorm + cast (step 0 only).
// ---------------------------------------------------------------------------
__global__ __launch_bounds__(256) void ln_cast_kernel(
    const float* __restrict__ h, const float* __restrict__ g,
    const float* __restrict__ be, __hip_bfloat16* __restrict__ hn) {
  const int row = blockIdx.x;
  const int tid = threadIdx.x;
  const float4 v = ((const float4*)(h + (size_t)row * DH_))[tid];
  float s = v.x + v.y + v.z + v.w;
  float ss = v.x * v.x + v.y * v.y + v.z * v.z + v.w * v.w;
#pragma unroll
  for (int o = 32; o > 0; o >>= 1) {
    s += __shfl_down(s, o, 64);
    ss += __shfl_down(ss, o, 64);
  }
  __shared__ float rs_[4], rss_[4];
  const int lane = tid & 63, wid = tid >> 6;
  if (lane == 0) { rs_[wid] = s; rss_[wid] = ss; }
  __syncthreads();
  const float tot = rs_[0] + rs_[1] + rs_[2] + rs_[3];
  const float tots = rss_[0] + rss_[1] + rss_[2] + rss_[3];
  const float mu = tot * (1.f / DH_);
  const float var = tots * (1.f / DH_) - mu * mu;
  const float rstd = rsqrtf(var + LN_EPS_);
  const float4 gv = ((const float4*)g)[tid];
  const float4 bv = ((const float4*)be)[tid];
  __hip_bfloat16* out = hn + (size_t)row * DH_ + tid * 4;
  out[0] = __float2bfloat16((v.x - mu) * rstd * gv.x + bv.x);
  out[1] = __float2bfloat16((v.y - mu) * rstd * gv.y + bv.y);
  out[2] = __float2bfloat16((v.z - mu) * rstd * gv.z + bv.z);
  out[3] = __float2bfloat16((v.w - mu) * rstd * gv.w + bv.w);
}

// ---------------------------------------------------------------------------
// Paired fp32 matvec (power iteration).
// ---------------------------------------------------------------------------
__global__ __launch_bounds__(256) void matvec2_kernel(
    const float* __restrict__ Wa, const float* __restrict__ xa,
    float* __restrict__ ya, int rowsA, int colsA,
    const float* __restrict__ Wb, const float* __restrict__ xb,
    float* __restrict__ yb, int rowsB, int colsB) {
  const int gw = (int)(blockIdx.x * 256 + threadIdx.x) >> 6;
  const int lane = threadIdx.x & 63;
  const float* W;
  const float* x;
  float* y;
  int row, cols;
  if (gw < rowsA) {
    W = Wa; x = xa; y = ya; row = gw; cols = colsA;
  } else {
    row = gw - rowsA;
    if (row >= rowsB) return;
    W = Wb; x = xb; y = yb; cols = colsB;
  }
  const float4* wr = (const float4*)(W + (size_t)row * cols);
  const float4* xv = (const float4*)x;
  const int n4 = cols >> 2;
  float s = 0.f;
  for (int c = lane; c < n4; c += 64) {
    const float4 wv = wr[c];
    const float4 vv = xv[c];
    s += wv.x * vv.x + wv.y * vv.y + wv.z * vv.z + wv.w * vv.w;
  }
#pragma unroll
  for (int o = 32; o > 0; o >>= 1) s += __shfl_down(s, o, 64);
  if (lane == 0) y[row] = s;
}

__global__ __launch_bounds__(256) void transpose_kernel(
    const float* __restrict__ in, float* __restrict__ out, int R, int C) {
  __shared__ float t[32][33];
  const int lx = threadIdx.x & 31, ly = threadIdx.x >> 5;
  const int r0 = blockIdx.y * 32, c0 = blockIdx.x * 32;
#pragma unroll
  for (int j = 0; j < 32; j += 8) t[ly + j][lx] = in[(size_t)(r0 + ly + j) * C + c0 + lx];
  __syncthreads();
#pragma unroll
  for (int j = 0; j < 32; j += 8) out[(size_t)(c0 + ly + j) * R + r0 + lx] = t[lx][ly + j];
}

__global__ void init_v_kernel(float* v1, float* v2) {
  const int i = blockIdx.x * 256 + threadIdx.x;
  if (i < 1024) v1[i] = 0.03125f;
  if (i < 4096) v2[i] = 0.015625f;
}

__global__ __launch_bounds__(256) void cast_kernel(
    const float* __restrict__ s, __hip_bfloat16* __restrict__ d, int n) {
  const int b = (blockIdx.x * 256 + threadIdx.x) * 4;
  if (b < n) {
    const float4 v = *(const float4*)(s + b);
    d[b] = __float2bfloat16(v.x);
    d[b + 1] = __float2bfloat16(v.y);
    d[b + 2] = __float2bfloat16(v.z);
    d[b + 3] = __float2bfloat16(v.w);
  }
}

__global__ __launch_bounds__(256) void cast_scaled_kernel(
    const float* __restrict__ s, __hip_bfloat16* __restrict__ d, int n,
    const float* __restrict__ rs) {
  const float r = rs[0];
  const int b = (blockIdx.x * 256 + threadIdx.x) * 4;
  if (b < n) {
    const float4 v = *(const float4*)(s + b);
    d[b] = __float2bfloat16(v.x * r);
    d[b + 1] = __float2bfloat16(v.y * r);
    d[b + 2] = __float2bfloat16(v.z * r);
    d[b + 3] = __float2bfloat16(v.w * r);
  }
}

// rs = |c| / |d|  (= 1/sigma)
__global__ __launch_bounds__(256) void sigma_rs_kernel(
    const float* __restrict__ c, int m, const float* __restrict__ dv, int n,
    float* __restrict__ rs) {
  const int tid = threadIdx.x;
  float sc = 0.f, sd = 0.f;
  for (int i = tid; i < m; i += 256) { const float v = c[i]; sc += v * v; }
  for (int i = tid; i < n; i += 256) { const float v = dv[i]; sd += v * v; }
#pragma unroll
  for (int o = 32; o > 0; o >>= 1) {
    sc += __shfl_down(sc, o, 64);
    sd += __shfl_down(sd, o, 64);
  }
  __shared__ float a[4], b[4];
  const int lane = tid & 63, wid = tid >> 6;
  if (lane == 0) { a[wid] = sc; b[wid] = sd; }
  __syncthreads();
  if (tid == 0) {
    const float tc = a[0] + a[1] + a[2] + a[3];
    const float td = b[0] + b[1] + b[2] + b[3];
    rs[0] = sqrtf(tc / td);
  }
}

extern "C" void kernel_launch(void* const* d_in, const int* in_sizes, int n_in,
                              void* d_out, int out_size, void* d_ws, size_t ws_size,
                              hipStream_t stream) {
  const float* x       = (const float*)d_in[0];
  const float* embed_w = (const float*)d_in[1];
  const float* embed_b = (const float*)d_in[2];
  const float* W1      = (const float*)d_in[3];
  const float* b1      = (const float*)d_in[4];
  const float* W2      = (const float*)d_in[5];
  const float* b2      = (const float*)d_in[6];
  const float* ln_g    = (const float*)d_in[7];
  const float* ln_b    = (const float*)d_in[8];
  const float* head_w  = (const float*)d_in[9];
  const float* head_b  = (const float*)d_in[10];
  float* out = (float*)d_out;

  char* p = (char*)d_ws;
  auto carve = [&](size_t bytes) {
    char* r = p;
    p += (bytes + 255) & ~(size_t)255;
    return (void*)r;
  };
  float* h     = (float*)carve((size_t)B_ * DH_ * 4);
  float* x_emb = (float*)carve((size_t)B_ * DH_ * 4);
  // W1T/W2T (33.6 MB) are dead after the power iteration; the 4 bf16 K-split
  // partial slabs (4 x 8.4 MB = 33.6 MB) alias this region during the steps.
  float* W1T   = (float*)carve((size_t)DFF_ * DH_ * 4);
  float* W2T   = (float*)carve((size_t)DH_ * DFF_ * 4);
  __hip_bfloat16* ps = (__hip_bfloat16*)W1T;  // [4][B_][DH_] bf16
  __hip_bfloat16* hn   = (__hip_bfloat16*)carve((size_t)B_ * DH_ * 2);
  __hip_bfloat16* hid  = (__hip_bfloat16*)carve((size_t)B_ * DFF_ * 2);
  __hip_bfloat16* W1n  = (__hip_bfloat16*)carve((size_t)DFF_ * DH_ * 2);
  __hip_bfloat16* W2n  = (__hip_bfloat16*)carve((size_t)DH_ * DFF_ * 2);
  __hip_bfloat16* xbf  = (__hip_bfloat16*)carve((size_t)B_ * DIN_ * 2);
  __hip_bfloat16* ewbf = (__hip_bfloat16*)carve((size_t)DH_ * DIN_ * 2);
  __hip_bfloat16* hwbf = (__hip_bfloat16*)carve((size_t)DOUT_ * DH_ * 2);
  __hip_bfloat16* hbf  = (__hip_bfloat16*)carve((size_t)B_ * DH_ * 2);
  float* v1a = (float*)carve(4096 * 4);
  float* v1b = (float*)carve(4096 * 4);
  float* c1  = (float*)carve(4096 * 4);
  float* v2a = (float*)carve(4096 * 4);
  float* v2b = (float*)carve(4096 * 4);
  float* c2  = (float*)carve(4096 * 4);
  float* rs1 = (float*)carve(256);
  float* rs2 = (float*)carve(256);

  // --- prep: transposes, inits, input casts ---
  transpose_kernel<<<dim3(DH_ / 32, DFF_ / 32), 256, 0, stream>>>(W1, W1T, DFF_, DH_);
  transpose_kernel<<<dim3(DFF_ / 32, DH_ / 32), 256, 0, stream>>>(W2, W2T, DH_, DFF_);
  init_v_kernel<<<16, 256, 0, stream>>>(v1a, v2a);
  cast_kernel<<<(B_ * DIN_ / 4) / 256, 256, 0, stream>>>(x, xbf, B_ * DIN_);
  cast_kernel<<<(DH_ * DIN_ / 4) / 256, 256, 0, stream>>>(embed_w, ewbf, DH_ * DIN_);
  cast_kernel<<<(DOUT_ * DH_ / 4) / 256, 256, 0, stream>>>(head_w, hwbf, DOUT_ * DH_);

  // --- x_emb = x @ embed_w^T + embed_b ; h = x_emb ---
  gemm_bt<<<dim3(DH_ / 128, B_ / 128), 256, 0, stream>>>(
      xbf, ewbf, B_, DH_, DIN_, embed_b, 0, x_emb, h);

  // --- power iteration (unnormalized), W1 & W2 paired ---
  for (int it = 0; it < 15; ++it) {
    const float* vin1 = (it & 1) ? v1b : v1a;
    float* vout1 = (it & 1) ? v1a : v1b;
    const float* vin2 = (it & 1) ? v2b : v2a;
    float* vout2 = (it & 1) ? v2a : v2b;
    matvec2_kernel<<<((DFF_ + DH_) * 64) / 256, 256, 0, stream>>>(
        W1, vin1, c1, DFF_, DH_, W2, vin2, c2, DH_, DFF_);
    matvec2_kernel<<<((DH_ + DFF_) * 64) / 256, 256, 0, stream>>>(
        W1T, c1, vout1, DH_, DFF_, W2T, c2, vout2, DFF_, DH_);
  }
  sigma_rs_kernel<<<1, 256, 0, stream>>>(c1, DFF_, v1b, DH_, rs1);
  sigma_rs_kernel<<<1, 256, 0, stream>>>(c2, DH_, v2b, DFF_, rs2);
  cast_scaled_kernel<<<(DFF_ * DH_ / 4) / 256, 256, 0, stream>>>(W1, W1n, DFF_ * DH_, rs1);
  cast_scaled_kernel<<<(DH_ * DFF_ / 4) / 256, 256, 0, stream>>>(W2, W2n, DH_ * DFF_, rs2);
  // (W1T/W2T dead from here; ps aliases them)

  // --- step 0 LN (h == x_emb) ---
  ln_cast_kernel<<<B_, 256, 0, stream>>>(h, ln_g, ln_b, hn);

  // --- 30 equilibrium steps ---
  for (int s = 0; s < STEPS_; ++s) {
    // hid = tanh(hn @ W1n^T + b1)   [4096 x 4096, K=1024, nt=16]
    gemm256<<<dim3(DFF_ / 256, B_ / 256, 1), 512, 0, stream>>>(
        hn, W1n, B_, DFF_, DH_, DH_, DH_ / 64, b1, 1, hid);
    // ps[z] = hid @ W2n^T (K-chunk z) [4096 x 1024, K=4096, split 4, nt=16]
    gemm256<<<dim3(DH_ / 256, B_ / 256, 4), 512, 0, stream>>>(
        hid, W2n, B_, DH_, DFF_, DFF_ / 4, DFF_ / 4 / 64, nullptr, 4, ps);
    const int last = (s == STEPS_ - 1);
    reduce_ln_kernel<<<B_, 256, 0, stream>>>(
        ps, b2, x_emb, h, ln_g, ln_b, last ? hbf : hn, last ? 0 : 1);
  }

  // --- head ---
  gemm_bt<<<dim3(DOUT_ / 128, B_ / 128), 256, 0, stream>>>(
      hbf, hwbf, B_, DOUT_, DH_, head_b, 3, out, nullptr);
}

// Round 9
// 3216.401 us; speedup vs baseline: 1.9117x; 1.0159x over previous
//
#include <hip/hip_runtime.h>
#include <hip/hip_bf16.h>
#include <math.h>

#define B_    4096
#define DIN_  512
#define DH_   1024
#define DOUT_ 256
#define DFF_  4096
#define STEPS_ 30
#define GAMMA_ 0.17677669529663687f
#define LN_EPS_ 1e-5f

typedef __attribute__((ext_vector_type(8))) short short8;
typedef __attribute__((ext_vector_type(4))) float f32x4;

__device__ inline void gload_lds16(const void* g, void* l) {
  __builtin_amdgcn_global_load_lds(
      (const __attribute__((address_space(1))) unsigned int*)g,
      (__attribute__((address_space(3))) unsigned int*)l, 16, 0, 0);
}

__device__ inline float fast_tanh(float v) {
  const float e = __expf(2.f * v);
  return 1.f - 2.f * __builtin_amdgcn_rcpf(e + 1.f);
}

__device__ inline float bf2f(unsigned short u) {
  return __uint_as_float((unsigned)u << 16);
}

// ---------------------------------------------------------------------------
// 256x256-tile bf16 GEMM, 8 waves (2Mx4N), BK=64, 2x64KiB LDS double-buffer,
// 8-phase schedule + cross-buffer B-prefetch: P4/P8 (zero-read phases)
// prefetch next tile's b0-1 fragments from the other buffer into alternating
// register sets pb0/pb1, so P1/P5 carry 8 reads instead of 12 (phase balance
// 8/4/8/4).  vmcnt ledger (invariant: B(t+1) outstanding entering tile t):
//   P4 vmcnt(4) drains B(t+1),A(t+1) -> prefetch pb(other buf) safe;
//   P8 vmcnt(4) drains B(t+2),A(t+2) -> symmetric.
// XOR chunk-swizzle both sides (0 bank conflicts, verified r7).
// C[M,N] = A[M,K] @ Bm[N,K]^T.  K-chunk per blockIdx.z: [z*kc, z*kc+nt*64).
// epi: 1 = bf16out = bf16(tanh(v + bias)); 4 = bf16 partial slab z (no bias).
// nt must be even and >= 4.
// ---------------------------------------------------------------------------
__global__ __launch_bounds__(512, 2) void gemm256(
    const __hip_bfloat16* __restrict__ A, const __hip_bfloat16* __restrict__ Bm,
    int M, int N, int K, int kc, int nt, const float* __restrict__ bias,
    int epi, __hip_bfloat16* __restrict__ bf16out) {
  // buf b at b*65536: A[256][64]bf16 at +0, B[256][64] at +32768
  __shared__ __align__(16) char lds[131072];
  const int tid = threadIdx.x;
  const int lane = tid & 63;
  const int wid = tid >> 6;
  const int wr = wid >> 2;      // 0..1  (M half)
  const int wc = wid & 3;       // 0..3  (N quarter)

  // XCD-aware bijective swizzle (nwg % 8 == 0 in all uses)
  const int gx = gridDim.x;
  const int nwg = gx * gridDim.y;
  const int wg = blockIdx.y * gx + blockIdx.x;
  const int cpx = nwg >> 3;
  const int swz = (wg & 7) * cpx + (wg >> 3);
  const int bx = swz % gx, by = swz / gx;
  const int m0 = by * 256, n0 = bx * 256;
  const int zk = blockIdx.z * kc;

  const int scol = ((lane & 7) ^ (lane >> 3)) * 8;  // inverse-swizzled src col
  const int srow = lane >> 3;

  f32x4 acc[8][4];
  const f32x4 zero = {0.f, 0.f, 0.f, 0.f};
#pragma unroll
  for (int i = 0; i < 8; ++i)
#pragma unroll
    for (int j = 0; j < 4; ++j) acc[i][j] = zero;

  auto STG = [&](int t, int hrow, int isB) {
    if (t >= nt) return;
    const int kt = zk + t * 64;
    char* base = &lds[(t & 1) * 65536 + isB * 32768];
#pragma unroll
    for (int j = 0; j < 2; ++j) {
      const int rbase = hrow + wid * 16 + j * 8;
      const int r = rbase + srow;
      const __hip_bfloat16* s =
          isB ? Bm + (size_t)(n0 + r) * K + kt + scol
              : A + (size_t)(m0 + r) * K + kt + scol;
      gload_lds16((const void*)s, (void*)(base + rbase * 128));
    }
  };

  // prologue: tile0 fully + tile1's B
  STG(0, 0, 1); STG(0, 128, 1); STG(0, 0, 0); STG(0, 128, 0);
  STG(1, 0, 1); STG(1, 128, 1);
  asm volatile("s_waitcnt vmcnt(0)" ::: "memory");
  __builtin_amdgcn_s_barrier();

  const int ar = lane & 15;
  const int hi = lane >> 4;
  const int a7 = ar & 7;
  const int co0 = (hi ^ a7) * 16;
  const int co1 = ((4 + hi) ^ a7) * 16;

  const char* Ab0 = &lds[0];
  const char* Bb0 = &lds[32768];
  const char* Ab1 = &lds[65536];
  const char* Bb1 = &lds[98304];
  const int arow = (wr * 128 + ar) * 128;
  const int brow = (wc * 64 + ar) * 128;

  // prefetch b0-1 of tile0 into pb0 (resident after prologue drain)
  short8 pb0[2][2], pb1[2][2];
#pragma unroll
  for (int j = 0; j < 2; ++j) {
    pb0[j][0] = *(const short8*)(Bb0 + brow + j * 2048 + co0);
    pb0[j][1] = *(const short8*)(Bb0 + brow + j * 2048 + co1);
  }

  const int niter = nt >> 1;
  for (int it = 0; it < niter; ++it) {
    const int t0 = it * 2;
    const bool lastit = (it == niter - 1);
    short8 a[4][2], b23[2][2];

    // ======================= tile t0 (buf0) =======================
    // ---- P1: reads a0-3 (8); stage A-lo(t0+1); MFMA Q00 (pb0) ----
#pragma unroll
    for (int i = 0; i < 4; ++i) {
      a[i][0] = *(const short8*)(Ab0 + arow + i * 2048 + co0);
      a[i][1] = *(const short8*)(Ab0 + arow + i * 2048 + co1);
    }
    STG(t0 + 1, 0, 0);
    asm volatile("s_waitcnt lgkmcnt(4)" ::: "memory");
    __builtin_amdgcn_sched_barrier(0);
    __builtin_amdgcn_s_barrier();
    asm volatile("s_waitcnt lgkmcnt(0)" ::: "memory");
    __builtin_amdgcn_sched_barrier(0);
    __builtin_amdgcn_s_setprio(1);
#pragma unroll
    for (int i = 0; i < 4; ++i)
#pragma unroll
      for (int j = 0; j < 2; ++j)
#pragma unroll
        for (int ks = 0; ks < 2; ++ks)
          acc[i][j] = __builtin_amdgcn_mfma_f32_16x16x32_bf16(a[i][ks], pb0[j][ks], acc[i][j], 0, 0, 0);
    __builtin_amdgcn_s_setprio(0);
    __builtin_amdgcn_sched_barrier(0);
    __builtin_amdgcn_s_barrier();

    // ---- P2: reads b2-3 (4); stage A-hi(t0+1); MFMA Q01 ----
#pragma unroll
    for (int j = 0; j < 2; ++j) {
      b23[j][0] = *(const short8*)(Bb0 + brow + (2 + j) * 2048 + co0);
      b23[j][1] = *(const short8*)(Bb0 + brow + (2 + j) * 2048 + co1);
    }
    STG(t0 + 1, 128, 0);
    __builtin_amdgcn_sched_barrier(0);
    __builtin_amdgcn_s_barrier();
    asm volatile("s_waitcnt lgkmcnt(0)" ::: "memory");
    __builtin_amdgcn_sched_barrier(0);
    __builtin_amdgcn_s_setprio(1);
#pragma unroll
    for (int i = 0; i < 4; ++i)
#pragma unroll
      for (int j = 0; j < 2; ++j)
#pragma unroll
        for (int ks = 0; ks < 2; ++ks)
          acc[i][2 + j] = __builtin_amdgcn_mfma_f32_16x16x32_bf16(a[i][ks], b23[j][ks], acc[i][2 + j], 0, 0, 0);
    __builtin_amdgcn_s_setprio(0);
    __builtin_amdgcn_sched_barrier(0);
    __builtin_amdgcn_s_barrier();

    // ---- P3: reads a4-7 (8); stage B-lo(t0+2); MFMA Q11 ----
#pragma unroll
    for (int i = 0; i < 4; ++i) {
      a[i][0] = *(const short8*)(Ab0 + arow + (4 + i) * 2048 + co0);
      a[i][1] = *(const short8*)(Ab0 + arow + (4 + i) * 2048 + co1);
    }
    STG(t0 + 2, 0, 1);
    __builtin_amdgcn_sched_barrier(0);
    __builtin_amdgcn_s_barrier();
    asm volatile("s_waitcnt lgkmcnt(0)" ::: "memory");
    __builtin_amdgcn_sched_barrier(0);
    __builtin_amdgcn_s_setprio(1);
#pragma unroll
    for (int i = 0; i < 4; ++i)
#pragma unroll
      for (int j = 0; j < 2; ++j)
#pragma unroll
        for (int ks = 0; ks < 2; ++ks)
          acc[4 + i][2 + j] = __builtin_amdgcn_mfma_f32_16x16x32_bf16(a[i][ks], b23[j][ks], acc[4 + i][2 + j], 0, 0, 0);
    __builtin_amdgcn_s_setprio(0);
    __builtin_amdgcn_sched_barrier(0);
    __builtin_amdgcn_s_barrier();

    // ---- P4: stage B-hi(t0+2); vmcnt gate; prefetch pb1<-buf1; MFMA Q10 (pb0) ----
    STG(t0 + 2, 128, 1);
    if (lastit) {
      asm volatile("s_waitcnt vmcnt(0)" ::: "memory");
    } else {
      asm volatile("s_waitcnt vmcnt(4)" ::: "memory");  // drains B(t0+1), A(t0+1)
    }
    __builtin_amdgcn_sched_barrier(0);
    __builtin_amdgcn_s_barrier();
#pragma unroll
    for (int j = 0; j < 2; ++j) {
      pb1[j][0] = *(const short8*)(Bb1 + brow + j * 2048 + co0);
      pb1[j][1] = *(const short8*)(Bb1 + brow + j * 2048 + co1);
    }
    __builtin_amdgcn_s_setprio(1);
#pragma unroll
    for (int i = 0; i < 4; ++i)
#pragma unroll
      for (int j = 0; j < 2; ++j)
#pragma unroll
        for (int ks = 0; ks < 2; ++ks)
          acc[4 + i][j] = __builtin_amdgcn_mfma_f32_16x16x32_bf16(a[i][ks], pb0[j][ks], acc[4 + i][j], 0, 0, 0);
    __builtin_amdgcn_s_setprio(0);
    __builtin_amdgcn_sched_barrier(0);
    __builtin_amdgcn_s_barrier();

    // ======================= tile t0+1 (buf1) =======================
    // ---- P5: reads a0-3 (8); stage A-lo(t0+2); MFMA Q00 (pb1) ----
#pragma unroll
    for (int i = 0; i < 4; ++i) {
      a[i][0] = *(const short8*)(Ab1 + arow + i * 2048 + co0);
      a[i][1] = *(const short8*)(Ab1 + arow + i * 2048 + co1);
    }
    STG(t0 + 2, 0, 0);
    asm volatile("s_waitcnt lgkmcnt(4)" ::: "memory");
    __builtin_amdgcn_sched_barrier(0);
    __builtin_amdgcn_s_barrier();
    asm volatile("s_waitcnt lgkmcnt(0)" ::: "memory");
    __builtin_amdgcn_sched_barrier(0);
    __builtin_amdgcn_s_setprio(1);
#pragma unroll
    for (int i = 0; i < 4; ++i)
#pragma unroll
      for (int j = 0; j < 2; ++j)
#pragma unroll
        for (int ks = 0; ks < 2; ++ks)
          acc[i][j] = __builtin_amdgcn_mfma_f32_16x16x32_bf16(a[i][ks], pb1[j][ks], acc[i][j], 0, 0, 0);
    __builtin_amdgcn_s_setprio(0);
    __builtin_amdgcn_sched_barrier(0);
    __builtin_amdgcn_s_barrier();

    // ---- P6: reads b2-3 (4); stage A-hi(t0+2); MFMA Q01 ----
#pragma unroll
    for (int j = 0; j < 2; ++j) {
      b23[j][0] = *(const short8*)(Bb1 + brow + (2 + j) * 2048 + co0);
      b23[j][1] = *(const short8*)(Bb1 + brow + (2 + j) * 2048 + co1);
    }
    STG(t0 + 2, 128, 0);
    __builtin_amdgcn_sched_barrier(0);
    __builtin_amdgcn_s_barrier();
    asm volatile("s_waitcnt lgkmcnt(0)" ::: "memory");
    __builtin_amdgcn_sched_barrier(0);
    __builtin_amdgcn_s_setprio(1);
#pragma unroll
    for (int i = 0; i < 4; ++i)
#pragma unroll
      for (int j = 0; j < 2; ++j)
#pragma unroll
        for (int ks = 0; ks < 2; ++ks)
          acc[i][2 + j] = __builtin_amdgcn_mfma_f32_16x16x32_bf16(a[i][ks], b23[j][ks], acc[i][2 + j], 0, 0, 0);
    __builtin_amdgcn_s_setprio(0);
    __builtin_amdgcn_sched_barrier(0);
    __builtin_amdgcn_s_barrier();

    // ---- P7: reads a4-7 (8); stage B-lo(t0+3); MFMA Q11 ----
#pragma unroll
    for (int i = 0; i < 4; ++i) {
      a[i][0] = *(const short8*)(Ab1 + arow + (4 + i) * 2048 + co0);
      a[i][1] = *(const short8*)(Ab1 + arow + (4 + i) * 2048 + co1);
    }
    STG(t0 + 3, 0, 1);
    __builtin_amdgcn_sched_barrier(0);
    __builtin_amdgcn_s_barrier();
    asm volatile("s_waitcnt lgkmcnt(0)" ::: "memory");
    __builtin_amdgcn_sched_barrier(0);
    __builtin_amdgcn_s_setprio(1);
#pragma unroll
    for (int i = 0; i < 4; ++i)
#pragma unroll
      for (int j = 0; j < 2; ++j)
#pragma unroll
        for (int ks = 0; ks < 2; ++ks)
          acc[4 + i][2 + j] = __builtin_amdgcn_mfma_f32_16x16x32_bf16(a[i][ks], b23[j][ks], acc[4 + i][2 + j], 0, 0, 0);
    __builtin_amdgcn_s_setprio(0);
    __builtin_amdgcn_sched_barrier(0);
    __builtin_amdgcn_s_barrier();

    // ---- P8: stage B-hi(t0+3); vmcnt(4); prefetch pb0<-buf0; MFMA Q10 (pb1) ----
    STG(t0 + 3, 128, 1);
    asm volatile("s_waitcnt vmcnt(4)" ::: "memory");  // drains B(t0+2), A(t0+2)
    __builtin_amdgcn_sched_barrier(0);
    __builtin_amdgcn_s_barrier();
#pragma unroll
    for (int j = 0; j < 2; ++j) {
      pb0[j][0] = *(const short8*)(Bb0 + brow + j * 2048 + co0);
      pb0[j][1] = *(const short8*)(Bb0 + brow + j * 2048 + co1);
    }
    __builtin_amdgcn_s_setprio(1);
#pragma unroll
    for (int i = 0; i < 4; ++i)
#pragma unroll
      for (int j = 0; j < 2; ++j)
#pragma unroll
        for (int ks = 0; ks < 2; ++ks)
          acc[4 + i][j] = __builtin_amdgcn_mfma_f32_16x16x32_bf16(a[i][ks], pb1[j][ks], acc[4 + i][j], 0, 0, 0);
    __builtin_amdgcn_s_setprio(0);
    __builtin_amdgcn_sched_barrier(0);
    __builtin_amdgcn_s_barrier();
  }

  if (epi == 4) bf16out += (size_t)blockIdx.z * ((size_t)M * N);
  const int rb = hi * 4;
#pragma unroll
  for (int mf = 0; mf < 8; ++mf) {
#pragma unroll
    for (int nf = 0; nf < 4; ++nf) {
      const int col = n0 + wc * 64 + nf * 16 + ar;
      const float bvs = bias ? bias[col] : 0.f;
#pragma unroll
      for (int j = 0; j < 4; ++j) {
        const int row = m0 + wr * 128 + mf * 16 + rb + j;
        float v = acc[mf][nf][j] + bvs;
        if (epi == 1) v = fast_tanh(v);
        bf16out[(size_t)row * N + col] = __float2bfloat16(v);
      }
    }
  }
}

// ---------------------------------------------------------------------------
// m97-style 128x128 bf16 GEMM (one-shot embed/head GEMMs).
// epi: 0 = EMBED (write f32out=h and bf16out=x_emb bf16); 3 = PLAIN (f32out).
// ---------------------------------------------------------------------------
__global__ __launch_bounds__(256) void gemm_bt(
    const __hip_bfloat16* __restrict__ A, const __hip_bfloat16* __restrict__ Bm,
    int M, int N, int K, const float* __restrict__ bias, int epi,
    float* __restrict__ f32out, __hip_bfloat16* __restrict__ bf16out) {
  __shared__ __align__(16) short As[128 * 32];
  __shared__ __align__(16) short Bs[128 * 32];
  const int tid = threadIdx.x;
  const int lane = tid & 63;
  const int wid = tid >> 6;
  const int wr = wid >> 1, wc = wid & 1;

  const int gx = gridDim.x;
  const int nwg = gx * gridDim.y;
  const int wg = blockIdx.y * gx + blockIdx.x;
  const int cpx = nwg >> 3;
  const int swz = (wg & 7) * cpx + (wg >> 3);
  const int bx = swz % gx, by = swz / gx;

  const int m0 = by * 128, n0 = bx * 128;
  const int ldsrow = lane >> 2;
  const int col8 = (lane & 3) * 8;

  f32x4 acc[4][4];
  const f32x4 zero = {0.f, 0.f, 0.f, 0.f};
#pragma unroll
  for (int i = 0; i < 4; ++i)
#pragma unroll
    for (int j = 0; j < 4; ++j) acc[i][j] = zero;

  for (int kt = 0; kt < K; kt += 32) {
#pragma unroll
    for (int i = 0; i < 2; ++i) {
      const int seg = wid * 2 + i;
      gload_lds16(A + (size_t)(m0 + seg * 16 + ldsrow) * K + kt + col8,
                  (void*)(As + seg * 512));
      gload_lds16(Bm + (size_t)(n0 + seg * 16 + ldsrow) * K + kt + col8,
                  (void*)(Bs + seg * 512));
    }
    __syncthreads();
    short8 a[4], b[4];
#pragma unroll
    for (int mf = 0; mf < 4; ++mf)
      a[mf] = *(const short8*)&As[(wr * 64 + mf * 16 + (lane & 15)) * 32 + (lane >> 4) * 8];
#pragma unroll
    for (int nf = 0; nf < 4; ++nf)
      b[nf] = *(const short8*)&Bs[(wc * 64 + nf * 16 + (lane & 15)) * 32 + (lane >> 4) * 8];
#pragma unroll
    for (int mf = 0; mf < 4; ++mf)
#pragma unroll
      for (int nf = 0; nf < 4; ++nf)
        acc[mf][nf] = __builtin_amdgcn_mfma_f32_16x16x32_bf16(a[mf], b[nf], acc[mf][nf], 0, 0, 0);
    __syncthreads();
  }

  const int rbase = (lane >> 4) * 4;
  const int cin = lane & 15;
#pragma unroll
  for (int mf = 0; mf < 4; ++mf) {
#pragma unroll
    for (int nf = 0; nf < 4; ++nf) {
      const int col = n0 + wc * 64 + nf * 16 + cin;
      const float bv = bias[col];
#pragma unroll
      for (int j = 0; j < 4; ++j) {
        const int row = m0 + wr * 64 + mf * 16 + rbase + j;
        const float v = acc[mf][nf][j] + bv;
        const size_t idx = (size_t)row * N + col;
        f32out[idx] = v;
        if (epi == 0) bf16out[idx] = __float2bfloat16(v);
      }
    }
  }
}

// ---------------------------------------------------------------------------
// Fused: h = (1-g)h + g*(sum of 4 bf16 partial slabs + b2 + xe);
// then LN+cast (do_ln) or plain bf16 cast (last step). Block per row.
// ---------------------------------------------------------------------------
__global__ __launch_bounds__(256) void reduce_ln_kernel(
    const __hip_bfloat16* __restrict__ ps, const float* __restrict__ b2,
    const __hip_bfloat16* __restrict__ xe, float* __restrict__ h,
    const float* __restrict__ g, const float* __restrict__ be,
    __hip_bfloat16* __restrict__ outbf, int do_ln) {
  const int row = blockIdx.x, tid = threadIdx.x;
  const size_t base = (size_t)row * DH_;
  const size_t slab = (size_t)B_ * DH_;
  float pv0 = 0.f, pv1 = 0.f, pv2 = 0.f, pv3 = 0.f;
#pragma unroll
  for (int z = 0; z < 4; ++z) {
    const ushort4 q = ((const ushort4*)(ps + z * slab + base))[tid];
    pv0 += bf2f(q.x); pv1 += bf2f(q.y); pv2 += bf2f(q.z); pv3 += bf2f(q.w);
  }
  const ushort4 xq = ((const ushort4*)(xe + base))[tid];
  const float4 hv = ((const float4*)(h + base))[tid];
  const float4 bv = ((const float4*)b2)[tid];
  float4 nv;
  nv.x = (1.f - GAMMA_) * hv.x + GAMMA_ * (pv0 + bv.x + bf2f(xq.x));
  nv.y = (1.f - GAMMA_) * hv.y + GAMMA_ * (pv1 + bv.y + bf2f(xq.y));
  nv.z = (1.f - GAMMA_) * hv.z + GAMMA_ * (pv2 + bv.z + bf2f(xq.z));
  nv.w = (1.f - GAMMA_) * hv.w + GAMMA_ * (pv3 + bv.w + bf2f(xq.w));
  ((float4*)(h + base))[tid] = nv;

  __hip_bfloat16* out = outbf + base + tid * 4;
  if (!do_ln) {
    out[0] = __float2bfloat16(nv.x);
    out[1] = __float2bfloat16(nv.y);
    out[2] = __float2bfloat16(nv.z);
    out[3] = __float2bfloat16(nv.w);
    return;
  }
  float s = nv.x + nv.y + nv.z + nv.w;
  float ss = nv.x * nv.x + nv.y * nv.y + nv.z * nv.z + nv.w * nv.w;
#pragma unroll
  for (int o = 32; o > 0; o >>= 1) {
    s += __shfl_down(s, o, 64);
    ss += __shfl_down(ss, o, 64);
  }
  __shared__ float rs_[4], rss_[4];
  const int lane = tid & 63, wid = tid >> 6;
  if (lane == 0) { rs_[wid] = s; rss_[wid] = ss; }
  __syncthreads();
  const float tot = rs_[0] + rs_[1] + rs_[2] + rs_[3];
  const float tots = rss_[0] + rss_[1] + rss_[2] + rss_[3];
  const float mu = tot * (1.f / DH_);
  const float var = tots * (1.f / DH_) - mu * mu;
  const float rstd = rsqrtf(var + LN_EPS_);
  const float4 gv = ((const float4*)g)[tid];
  const float4 bev = ((const float4*)be)[tid];
  out[0] = __float2bfloat16((nv.x - mu) * rstd * gv.x + bev.x);
  out[1] = __float2bfloat16((nv.y - mu) * rstd * gv.y + bev.y);
  out[2] = __float2bfloat16((nv.z - mu) * rstd * gv.z + bev.z);
  out[3] = __float2bfloat16((nv.w - mu) * rstd * gv.w + bev.w);
}

// ---------------------------------------------------------------------------
// LayerNorm + cast (step 0 only).
// ---------------------------------------------------------------------------
__global__ __launch_bounds__(256) void ln_cast_kernel(
    const float* __restrict__ h, const float* __restrict__ g,
    const float* __restrict__ be, __hip_bfloat16* __restrict__ hn) {
  const int row = blockIdx.x;
  const int tid = threadIdx.x;
  const float4 v = ((const float4*)(h + (size_t)row * DH_))[tid];
  float s = v.x + v.y + v.z + v.w;
  float ss = v.x * v.x + v.y * v.y + v.z * v.z + v.w * v.w;
#pragma unroll
  for (int o = 32; o > 0; o >>= 1) {
    s += __shfl_down(s, o, 64);
    ss += __shfl_down(ss, o, 64);
  }
  __shared__ float rs_[4], rss_[4];
  const int lane = tid & 63, wid = tid >> 6;
  if (lane == 0) { rs_[wid] = s; rss_[wid] = ss; }
  __syncthreads();
  const float tot = rs_[0] + rs_[1] + rs_[2] + rs_[3];
  const float tots = rss_[0] + rss_[1] + rss_[2] + rss_[3];
  const float mu = tot * (1.f / DH_);
  const float var = tots * (1.f / DH_) - mu * mu;
  const float rstd = rsqrtf(var + LN_EPS_);
  const float4 gv = ((const float4*)g)[tid];
  const float4 bv = ((const float4*)be)[tid];
  __hip_bfloat16* out = hn + (size_t)row * DH_ + tid * 4;
  out[0] = __float2bfloat16((v.x - mu) * rstd * gv.x + bv.x);
  out[1] = __float2bfloat16((v.y - mu) * rstd * gv.y + bv.y);
  out[2] = __float2bfloat16((v.z - mu) * rstd * gv.z + bv.z);
  out[3] = __float2bfloat16((v.w - mu) * rstd * gv.w + bv.w);
}

// ---------------------------------------------------------------------------
// Paired fp32 matvec (power iteration).
// ---------------------------------------------------------------------------
__global__ __launch_bounds__(256) void matvec2_kernel(
    const float* __restrict__ Wa, const float* __restrict__ xa,
    float* __restrict__ ya, int rowsA, int colsA,
    const float* __restrict__ Wb, const float* __restrict__ xb,
    float* __restrict__ yb, int rowsB, int colsB) {
  const int gw = (int)(blockIdx.x * 256 + threadIdx.x) >> 6;
  const int lane = threadIdx.x & 63;
  const float* W;
  const float* x;
  float* y;
  int row, cols;
  if (gw < rowsA) {
    W = Wa; x = xa; y = ya; row = gw; cols = colsA;
  } else {
    row = gw - rowsA;
    if (row >= rowsB) return;
    W = Wb; x = xb; y = yb; cols = colsB;
  }
  const float4* wr = (const float4*)(W + (size_t)row * cols);
  const float4* xv = (const float4*)x;
  const int n4 = cols >> 2;
  float s = 0.f;
  for (int c = lane; c < n4; c += 64) {
    const float4 wv = wr[c];
    const float4 vv = xv[c];
    s += wv.x * vv.x + wv.y * vv.y + wv.z * vv.z + wv.w * vv.w;
  }
#pragma unroll
  for (int o = 32; o > 0; o >>= 1) s += __shfl_down(s, o, 64);
  if (lane == 0) y[row] = s;
}

__global__ __launch_bounds__(256) void transpose_kernel(
    const float* __restrict__ in, float* __restrict__ out, int R, int C) {
  __shared__ float t[32][33];
  const int lx = threadIdx.x & 31, ly = threadIdx.x >> 5;
  const int r0 = blockIdx.y * 32, c0 = blockIdx.x * 32;
#pragma unroll
  for (int j = 0; j < 32; j += 8) t[ly + j][lx] = in[(size_t)(r0 + ly + j) * C + c0 + lx];
  __syncthreads();
#pragma unroll
  for (int j = 0; j < 32; j += 8) out[(size_t)(c0 + ly + j) * R + r0 + lx] = t[lx][ly + j];
}

__global__ void init_v_kernel(float* v1, float* v2) {
  const int i = blockIdx.x * 256 + threadIdx.x;
  if (i < 1024) v1[i] = 0.03125f;
  if (i < 4096) v2[i] = 0.015625f;
}

__global__ __launch_bounds__(256) void cast_kernel(
    const float* __restrict__ s, __hip_bfloat16* __restrict__ d, int n) {
  const int b = (blockIdx.x * 256 + threadIdx.x) * 4;
  if (b < n) {
    const float4 v = *(const float4*)(s + b);
    d[b] = __float2bfloat16(v.x);
    d[b + 1] = __float2bfloat16(v.y);
    d[b + 2] = __float2bfloat16(v.z);
    d[b + 3] = __float2bfloat16(v.w);
  }
}

__global__ __launch_bounds__(256) void cast_scaled_kernel(
    const float* __restrict__ s, __hip_bfloat16* __restrict__ d, int n,
    const float* __restrict__ rs) {
  const float r = rs[0];
  const int b = (blockIdx.x * 256 + threadIdx.x) * 4;
  if (b < n) {
    const float4 v = *(const float4*)(s + b);
    d[b] = __float2bfloat16(v.x * r);
    d[b + 1] = __float2bfloat16(v.y * r);
    d[b + 2] = __float2bfloat16(v.z * r);
    d[b + 3] = __float2bfloat16(v.w * r);
  }
}

// rs = |c| / |d|  (= 1/sigma)
__global__ __launch_bounds__(256) void sigma_rs_kernel(
    const float* __restrict__ c, int m, const float* __restrict__ dv, int n,
    float* __restrict__ rs) {
  const int tid = threadIdx.x;
  float sc = 0.f, sd = 0.f;
  for (int i = tid; i < m; i += 256) { const float v = c[i]; sc += v * v; }
  for (int i = tid; i < n; i += 256) { const float v = dv[i]; sd += v * v; }
#pragma unroll
  for (int o = 32; o > 0; o >>= 1) {
    sc += __shfl_down(sc, o, 64);
    sd += __shfl_down(sd, o, 64);
  }
  __shared__ float a[4], b[4];
  const int lane = tid & 63, wid = tid >> 6;
  if (lane == 0) { a[wid] = sc; b[wid] = sd; }
  __syncthreads();
  if (tid == 0) {
    const float tc = a[0] + a[1] + a[2] + a[3];
    const float td = b[0] + b[1] + b[2] + b[3];
    rs[0] = sqrtf(tc / td);
  }
}

extern "C" void kernel_launch(void* const* d_in, const int* in_sizes, int n_in,
                              void* d_out, int out_size, void* d_ws, size_t ws_size,
                              hipStream_t stream) {
  const float* x       = (const float*)d_in[0];
  const float* embed_w = (const float*)d_in[1];
  const float* embed_b = (const float*)d_in[2];
  const float* W1      = (const float*)d_in[3];
  const float* b1      = (const float*)d_in[4];
  const float* W2      = (const float*)d_in[5];
  const float* b2      = (const float*)d_in[6];
  const float* ln_g    = (const float*)d_in[7];
  const float* ln_b    = (const float*)d_in[8];
  const float* head_w  = (const float*)d_in[9];
  const float* head_b  = (const float*)d_in[10];
  float* out = (float*)d_out;

  char* p = (char*)d_ws;
  auto carve = [&](size_t bytes) {
    char* r = p;
    p += (bytes + 255) & ~(size_t)255;
    return (void*)r;
  };
  float* h = (float*)carve((size_t)B_ * DH_ * 4);
  // W1T/W2T (33.6 MB) are dead after the power iteration; the 4 bf16 K-split
  // partial slabs (4 x 8.4 MB = 33.6 MB) alias this region during the steps.
  float* W1T   = (float*)carve((size_t)DFF_ * DH_ * 4);
  float* W2T   = (float*)carve((size_t)DH_ * DFF_ * 4);
  __hip_bfloat16* ps = (__hip_bfloat16*)W1T;  // [4][B_][DH_] bf16
  __hip_bfloat16* xebf = (__hip_bfloat16*)carve((size_t)B_ * DH_ * 2);
  __hip_bfloat16* hn   = (__hip_bfloat16*)carve((size_t)B_ * DH_ * 2);
  __hip_bfloat16* hid  = (__hip_bfloat16*)carve((size_t)B_ * DFF_ * 2);
  __hip_bfloat16* W1n  = (__hip_bfloat16*)carve((size_t)DFF_ * DH_ * 2);
  __hip_bfloat16* W2n  = (__hip_bfloat16*)carve((size_t)DH_ * DFF_ * 2);
  __hip_bfloat16* xbf  = (__hip_bfloat16*)carve((size_t)B_ * DIN_ * 2);
  __hip_bfloat16* ewbf = (__hip_bfloat16*)carve((size_t)DH_ * DIN_ * 2);
  __hip_bfloat16* hwbf = (__hip_bfloat16*)carve((size_t)DOUT_ * DH_ * 2);
  __hip_bfloat16* hbf  = (__hip_bfloat16*)carve((size_t)B_ * DH_ * 2);
  float* v1a = (float*)carve(4096 * 4);
  float* v1b = (float*)carve(4096 * 4);
  float* c1  = (float*)carve(4096 * 4);
  float* v2a = (float*)carve(4096 * 4);
  float* v2b = (float*)carve(4096 * 4);
  float* c2  = (float*)carve(4096 * 4);
  float* rs1 = (float*)carve(256);
  float* rs2 = (float*)carve(256);

  // --- prep: transposes, inits, input casts ---
  transpose_kernel<<<dim3(DH_ / 32, DFF_ / 32), 256, 0, stream>>>(W1, W1T, DFF_, DH_);
  transpose_kernel<<<dim3(DFF_ / 32, DH_ / 32), 256, 0, stream>>>(W2, W2T, DH_, DFF_);
  init_v_kernel<<<16, 256, 0, stream>>>(v1a, v2a);
  cast_kernel<<<(B_ * DIN_ / 4) / 256, 256, 0, stream>>>(x, xbf, B_ * DIN_);
  cast_kernel<<<(DH_ * DIN_ / 4) / 256, 256, 0, stream>>>(embed_w, ewbf, DH_ * DIN_);
  cast_kernel<<<(DOUT_ * DH_ / 4) / 256, 256, 0, stream>>>(head_w, hwbf, DOUT_ * DH_);

  // --- h = x_emb = x @ embed_w^T + embed_b ; xebf = bf16(x_emb) ---
  gemm_bt<<<dim3(DH_ / 128, B_ / 128), 256, 0, stream>>>(
      xbf, ewbf, B_, DH_, DIN_, embed_b, 0, h, xebf);

  // --- power iteration (unnormalized), W1 & W2 paired ---
  for (int it = 0; it < 15; ++it) {
    const float* vin1 = (it & 1) ? v1b : v1a;
    float* vout1 = (it & 1) ? v1a : v1b;
    const float* vin2 = (it & 1) ? v2b : v2a;
    float* vout2 = (it & 1) ? v2a : v2b;
    matvec2_kernel<<<((DFF_ + DH_) * 64) / 256, 256, 0, stream>>>(
        W1, vin1, c1, DFF_, DH_, W2, vin2, c2, DH_, DFF_);
    matvec2_kernel<<<((DH_ + DFF_) * 64) / 256, 256, 0, stream>>>(
        W1T, c1, vout1, DH_, DFF_, W2T, c2, vout2, DFF_, DH_);
  }
  sigma_rs_kernel<<<1, 256, 0, stream>>>(c1, DFF_, v1b, DH_, rs1);
  sigma_rs_kernel<<<1, 256, 0, stream>>>(c2, DH_, v2b, DFF_, rs2);
  cast_scaled_kernel<<<(DFF_ * DH_ / 4) / 256, 256, 0, stream>>>(W1, W1n, DFF_ * DH_, rs1);
  cast_scaled_kernel<<<(DH_ * DFF_ / 4) / 256, 256, 0, stream>>>(W2, W2n, DH_ * DFF_, rs2);
  // (W1T/W2T dead from here; ps aliases them)

  // --- step 0 LN (h == x_emb) ---
  ln_cast_kernel<<<B_, 256, 0, stream>>>(h, ln_g, ln_b, hn);

  // --- 30 equilibrium steps ---
  for (int s = 0; s < STEPS_; ++s) {
    // hid = tanh(hn @ W1n^T + b1)   [4096 x 4096, K=1024, nt=16]
    gemm256<<<dim3(DFF_ / 256, B_ / 256, 1), 512, 0, stream>>>(
        hn, W1n, B_, DFF_, DH_, DH_, DH_ / 64, b1, 1, hid);
    // ps[z] = hid @ W2n^T (K-chunk z) [4096 x 1024, K=4096, split 4, nt=16]
    gemm256<<<dim3(DH_ / 256, B_ / 256, 4), 512, 0, stream>>>(
        hid, W2n, B_, DH_, DFF_, DFF_ / 4, DFF_ / 4 / 64, nullptr, 4, ps);
    const int last = (s == STEPS_ - 1);
    reduce_ln_kernel<<<B_, 256, 0, stream>>>(
        ps, b2, xebf, h, ln_g, ln_b, last ? hbf : hn, last ? 0 : 1);
  }

  // --- head ---
  gemm_bt<<<dim3(DOUT_ / 128, B_ / 128), 256, 0, stream>>>(
      hbf, hwbf, B_, DOUT_, DH_, head_b, 3, out, nullptr);
}

// Round 10
// 3196.381 us; speedup vs baseline: 1.9237x; 1.0063x over previous
//
#include <hip/hip_runtime.h>
#include <hip/hip_bf16.h>
#include <math.h>

#define B_    4096
#define DIN_  512
#define DH_   1024
#define DOUT_ 256
#define DFF_  4096
#define STEPS_ 30
#define GAMMA_ 0.17677669529663687f
#define LN_EPS_ 1e-5f

typedef __attribute__((ext_vector_type(8))) short short8;
typedef __attribute__((ext_vector_type(4))) float f32x4;

__device__ inline void gload_lds16(const void* g, void* l) {
  __builtin_amdgcn_global_load_lds(
      (const __attribute__((address_space(1))) unsigned int*)g,
      (__attribute__((address_space(3))) unsigned int*)l, 16, 0, 0);
}

__device__ inline float fast_tanh(float v) {
  const float e = __expf(2.f * v);
  return 1.f - 2.f * __builtin_amdgcn_rcpf(e + 1.f);
}

__device__ inline float bf2f(unsigned short u) {
  return __uint_as_float((unsigned)u << 16);
}

// ---------------------------------------------------------------------------
// 256x256-tile bf16 GEMM, 8 waves (2Mx4N), BK=64, 2x64KiB LDS double-buffer,
// 8-phase schedule + cross-buffer B-prefetch (pb0/pb1), counted vmcnt(4) at
// P4/P8 (vmcnt(0) at P4 of last iter).  XOR chunk-swizzle both sides
// (0 bank conflicts, verified r7).  2 K-tiles per iteration.
// C[M,N] = A[M,K] @ Bm[N,K]^T.  K-chunk per blockIdx.z: [z*kc, z*kc+nt*64).
// epi: 1 = bf16out = bf16(tanh(v + bias)); 4 = bf16 partial slab z (no bias).
// nt must be even and >= 4.
// ---------------------------------------------------------------------------
__global__ __launch_bounds__(512, 2) void gemm256(
    const __hip_bfloat16* __restrict__ A, const __hip_bfloat16* __restrict__ Bm,
    int M, int N, int K, int kc, int nt, const float* __restrict__ bias,
    int epi, __hip_bfloat16* __restrict__ bf16out) {
  // buf b at b*65536: A[256][64]bf16 at +0, B[256][64] at +32768
  __shared__ __align__(16) char lds[131072];
  const int tid = threadIdx.x;
  const int lane = tid & 63;
  const int wid = tid >> 6;
  const int wr = wid >> 2;      // 0..1  (M half)
  const int wc = wid & 3;       // 0..3  (N quarter)

  // XCD-aware bijective swizzle (nwg % 8 == 0 in all uses)
  const int gx = gridDim.x;
  const int nwg = gx * gridDim.y;
  const int wg = blockIdx.y * gx + blockIdx.x;
  const int cpx = nwg >> 3;
  const int swz = (wg & 7) * cpx + (wg >> 3);
  const int bx = swz % gx, by = swz / gx;
  const int m0 = by * 256, n0 = bx * 256;
  const int zk = blockIdx.z * kc;

  const int scol = ((lane & 7) ^ (lane >> 3)) * 8;  // inverse-swizzled src col
  const int srow = lane >> 3;

  f32x4 acc[8][4];
  const f32x4 zero = {0.f, 0.f, 0.f, 0.f};
#pragma unroll
  for (int i = 0; i < 8; ++i)
#pragma unroll
    for (int j = 0; j < 4; ++j) acc[i][j] = zero;

  auto STG = [&](int t, int hrow, int isB) {
    if (t >= nt) return;
    const int kt = zk + t * 64;
    char* base = &lds[(t & 1) * 65536 + isB * 32768];
#pragma unroll
    for (int j = 0; j < 2; ++j) {
      const int rbase = hrow + wid * 16 + j * 8;
      const int r = rbase + srow;
      const __hip_bfloat16* s =
          isB ? Bm + (size_t)(n0 + r) * K + kt + scol
              : A + (size_t)(m0 + r) * K + kt + scol;
      gload_lds16((const void*)s, (void*)(base + rbase * 128));
    }
  };

  // prologue: tile0 fully + tile1's B
  STG(0, 0, 1); STG(0, 128, 1); STG(0, 0, 0); STG(0, 128, 0);
  STG(1, 0, 1); STG(1, 128, 1);
  asm volatile("s_waitcnt vmcnt(0)" ::: "memory");
  __builtin_amdgcn_s_barrier();

  const int ar = lane & 15;
  const int hi = lane >> 4;
  const int a7 = ar & 7;
  const int co0 = (hi ^ a7) * 16;
  const int co1 = ((4 + hi) ^ a7) * 16;

  const char* Ab0 = &lds[0];
  const char* Bb0 = &lds[32768];
  const char* Ab1 = &lds[65536];
  const char* Bb1 = &lds[98304];
  const int arow = (wr * 128 + ar) * 128;
  const int brow = (wc * 64 + ar) * 128;

  // prefetch b0-1 of tile0 into pb0 (resident after prologue drain)
  short8 pb0[2][2], pb1[2][2];
#pragma unroll
  for (int j = 0; j < 2; ++j) {
    pb0[j][0] = *(const short8*)(Bb0 + brow + j * 2048 + co0);
    pb0[j][1] = *(const short8*)(Bb0 + brow + j * 2048 + co1);
  }

  const int niter = nt >> 1;
  for (int it = 0; it < niter; ++it) {
    const int t0 = it * 2;
    const bool lastit = (it == niter - 1);
    short8 a[4][2], b23[2][2];

    // ======================= tile t0 (buf0) =======================
    // ---- P1: reads a0-3 (8); stage A-lo(t0+1); MFMA Q00 (pb0) ----
#pragma unroll
    for (int i = 0; i < 4; ++i) {
      a[i][0] = *(const short8*)(Ab0 + arow + i * 2048 + co0);
      a[i][1] = *(const short8*)(Ab0 + arow + i * 2048 + co1);
    }
    STG(t0 + 1, 0, 0);
    asm volatile("s_waitcnt lgkmcnt(4)" ::: "memory");
    __builtin_amdgcn_sched_barrier(0);
    __builtin_amdgcn_s_barrier();
    asm volatile("s_waitcnt lgkmcnt(0)" ::: "memory");
    __builtin_amdgcn_sched_barrier(0);
    __builtin_amdgcn_s_setprio(1);
#pragma unroll
    for (int i = 0; i < 4; ++i)
#pragma unroll
      for (int j = 0; j < 2; ++j)
#pragma unroll
        for (int ks = 0; ks < 2; ++ks)
          acc[i][j] = __builtin_amdgcn_mfma_f32_16x16x32_bf16(a[i][ks], pb0[j][ks], acc[i][j], 0, 0, 0);
    __builtin_amdgcn_s_setprio(0);
    __builtin_amdgcn_sched_barrier(0);
    __builtin_amdgcn_s_barrier();

    // ---- P2: reads b2-3 (4); stage A-hi(t0+1); MFMA Q01 ----
#pragma unroll
    for (int j = 0; j < 2; ++j) {
      b23[j][0] = *(const short8*)(Bb0 + brow + (2 + j) * 2048 + co0);
      b23[j][1] = *(const short8*)(Bb0 + brow + (2 + j) * 2048 + co1);
    }
    STG(t0 + 1, 128, 0);
    __builtin_amdgcn_sched_barrier(0);
    __builtin_amdgcn_s_barrier();
    asm volatile("s_waitcnt lgkmcnt(0)" ::: "memory");
    __builtin_amdgcn_sched_barrier(0);
    __builtin_amdgcn_s_setprio(1);
#pragma unroll
    for (int i = 0; i < 4; ++i)
#pragma unroll
      for (int j = 0; j < 2; ++j)
#pragma unroll
        for (int ks = 0; ks < 2; ++ks)
          acc[i][2 + j] = __builtin_amdgcn_mfma_f32_16x16x32_bf16(a[i][ks], b23[j][ks], acc[i][2 + j], 0, 0, 0);
    __builtin_amdgcn_s_setprio(0);
    __builtin_amdgcn_sched_barrier(0);
    __builtin_amdgcn_s_barrier();

    // ---- P3: reads a4-7 (8); stage B-lo(t0+2); MFMA Q11 ----
#pragma unroll
    for (int i = 0; i < 4; ++i) {
      a[i][0] = *(const short8*)(Ab0 + arow + (4 + i) * 2048 + co0);
      a[i][1] = *(const short8*)(Ab0 + arow + (4 + i) * 2048 + co1);
    }
    STG(t0 + 2, 0, 1);
    __builtin_amdgcn_sched_barrier(0);
    __builtin_amdgcn_s_barrier();
    asm volatile("s_waitcnt lgkmcnt(0)" ::: "memory");
    __builtin_amdgcn_sched_barrier(0);
    __builtin_amdgcn_s_setprio(1);
#pragma unroll
    for (int i = 0; i < 4; ++i)
#pragma unroll
      for (int j = 0; j < 2; ++j)
#pragma unroll
        for (int ks = 0; ks < 2; ++ks)
          acc[4 + i][2 + j] = __builtin_amdgcn_mfma_f32_16x16x32_bf16(a[i][ks], b23[j][ks], acc[4 + i][2 + j], 0, 0, 0);
    __builtin_amdgcn_s_setprio(0);
    __builtin_amdgcn_sched_barrier(0);
    __builtin_amdgcn_s_barrier();

    // ---- P4: stage B-hi(t0+2); vmcnt gate; prefetch pb1<-buf1; MFMA Q10 (pb0) ----
    STG(t0 + 2, 128, 1);
    if (lastit) {
      asm volatile("s_waitcnt vmcnt(0)" ::: "memory");
    } else {
      asm volatile("s_waitcnt vmcnt(4)" ::: "memory");  // drains B(t0+1), A(t0+1)
    }
    __builtin_amdgcn_sched_barrier(0);
    __builtin_amdgcn_s_barrier();
#pragma unroll
    for (int j = 0; j < 2; ++j) {
      pb1[j][0] = *(const short8*)(Bb1 + brow + j * 2048 + co0);
      pb1[j][1] = *(const short8*)(Bb1 + brow + j * 2048 + co1);
    }
    __builtin_amdgcn_s_setprio(1);
#pragma unroll
    for (int i = 0; i < 4; ++i)
#pragma unroll
      for (int j = 0; j < 2; ++j)
#pragma unroll
        for (int ks = 0; ks < 2; ++ks)
          acc[4 + i][j] = __builtin_amdgcn_mfma_f32_16x16x32_bf16(a[i][ks], pb0[j][ks], acc[4 + i][j], 0, 0, 0);
    __builtin_amdgcn_s_setprio(0);
    __builtin_amdgcn_sched_barrier(0);
    __builtin_amdgcn_s_barrier();

    // ======================= tile t0+1 (buf1) =======================
    // ---- P5: reads a0-3 (8); stage A-lo(t0+2); MFMA Q00 (pb1) ----
#pragma unroll
    for (int i = 0; i < 4; ++i) {
      a[i][0] = *(const short8*)(Ab1 + arow + i * 2048 + co0);
      a[i][1] = *(const short8*)(Ab1 + arow + i * 2048 + co1);
    }
    STG(t0 + 2, 0, 0);
    asm volatile("s_waitcnt lgkmcnt(4)" ::: "memory");
    __builtin_amdgcn_sched_barrier(0);
    __builtin_amdgcn_s_barrier();
    asm volatile("s_waitcnt lgkmcnt(0)" ::: "memory");
    __builtin_amdgcn_sched_barrier(0);
    __builtin_amdgcn_s_setprio(1);
#pragma unroll
    for (int i = 0; i < 4; ++i)
#pragma unroll
      for (int j = 0; j < 2; ++j)
#pragma unroll
        for (int ks = 0; ks < 2; ++ks)
          acc[i][j] = __builtin_amdgcn_mfma_f32_16x16x32_bf16(a[i][ks], pb1[j][ks], acc[i][j], 0, 0, 0);
    __builtin_amdgcn_s_setprio(0);
    __builtin_amdgcn_sched_barrier(0);
    __builtin_amdgcn_s_barrier();

    // ---- P6: reads b2-3 (4); stage A-hi(t0+2); MFMA Q01 ----
#pragma unroll
    for (int j = 0; j < 2; ++j) {
      b23[j][0] = *(const short8*)(Bb1 + brow + (2 + j) * 2048 + co0);
      b23[j][1] = *(const short8*)(Bb1 + brow + (2 + j) * 2048 + co1);
    }
    STG(t0 + 2, 128, 0);
    __builtin_amdgcn_sched_barrier(0);
    __builtin_amdgcn_s_barrier();
    asm volatile("s_waitcnt lgkmcnt(0)" ::: "memory");
    __builtin_amdgcn_sched_barrier(0);
    __builtin_amdgcn_s_setprio(1);
#pragma unroll
    for (int i = 0; i < 4; ++i)
#pragma unroll
      for (int j = 0; j < 2; ++j)
#pragma unroll
        for (int ks = 0; ks < 2; ++ks)
          acc[i][2 + j] = __builtin_amdgcn_mfma_f32_16x16x32_bf16(a[i][ks], b23[j][ks], acc[i][2 + j], 0, 0, 0);
    __builtin_amdgcn_s_setprio(0);
    __builtin_amdgcn_sched_barrier(0);
    __builtin_amdgcn_s_barrier();

    // ---- P7: reads a4-7 (8); stage B-lo(t0+3); MFMA Q11 ----
#pragma unroll
    for (int i = 0; i < 4; ++i) {
      a[i][0] = *(const short8*)(Ab1 + arow + (4 + i) * 2048 + co0);
      a[i][1] = *(const short8*)(Ab1 + arow + (4 + i) * 2048 + co1);
    }
    STG(t0 + 3, 0, 1);
    __builtin_amdgcn_sched_barrier(0);
    __builtin_amdgcn_s_barrier();
    asm volatile("s_waitcnt lgkmcnt(0)" ::: "memory");
    __builtin_amdgcn_sched_barrier(0);
    __builtin_amdgcn_s_setprio(1);
#pragma unroll
    for (int i = 0; i < 4; ++i)
#pragma unroll
      for (int j = 0; j < 2; ++j)
#pragma unroll
        for (int ks = 0; ks < 2; ++ks)
          acc[4 + i][2 + j] = __builtin_amdgcn_mfma_f32_16x16x32_bf16(a[i][ks], b23[j][ks], acc[4 + i][2 + j], 0, 0, 0);
    __builtin_amdgcn_s_setprio(0);
    __builtin_amdgcn_sched_barrier(0);
    __builtin_amdgcn_s_barrier();

    // ---- P8: stage B-hi(t0+3); vmcnt(4); prefetch pb0<-buf0; MFMA Q10 (pb1) ----
    STG(t0 + 3, 128, 1);
    asm volatile("s_waitcnt vmcnt(4)" ::: "memory");  // drains B(t0+2), A(t0+2)
    __builtin_amdgcn_sched_barrier(0);
    __builtin_amdgcn_s_barrier();
#pragma unroll
    for (int j = 0; j < 2; ++j) {
      pb0[j][0] = *(const short8*)(Bb0 + brow + j * 2048 + co0);
      pb0[j][1] = *(const short8*)(Bb0 + brow + j * 2048 + co1);
    }
    __builtin_amdgcn_s_setprio(1);
#pragma unroll
    for (int i = 0; i < 4; ++i)
#pragma unroll
      for (int j = 0; j < 2; ++j)
#pragma unroll
        for (int ks = 0; ks < 2; ++ks)
          acc[4 + i][j] = __builtin_amdgcn_mfma_f32_16x16x32_bf16(a[i][ks], pb1[j][ks], acc[4 + i][j], 0, 0, 0);
    __builtin_amdgcn_s_setprio(0);
    __builtin_amdgcn_sched_barrier(0);
    __builtin_amdgcn_s_barrier();
  }

  if (epi == 4) bf16out += (size_t)blockIdx.z * ((size_t)M * N);
  const int rb = hi * 4;
#pragma unroll
  for (int mf = 0; mf < 8; ++mf) {
#pragma unroll
    for (int nf = 0; nf < 4; ++nf) {
      const int col = n0 + wc * 64 + nf * 16 + ar;
      const float bvs = bias ? bias[col] : 0.f;
#pragma unroll
      for (int j = 0; j < 4; ++j) {
        const int row = m0 + wr * 128 + mf * 16 + rb + j;
        float v = acc[mf][nf][j] + bvs;
        if (epi == 1) v = fast_tanh(v);
        bf16out[(size_t)row * N + col] = __float2bfloat16(v);
      }
    }
  }
}

// ---------------------------------------------------------------------------
// m97-style 128x128 bf16 GEMM (one-shot embed/head GEMMs).
// epi: 0 = EMBED (write bf16out=xebf and bf16out2=h, both bf16);
//      3 = PLAIN (f32out).
// ---------------------------------------------------------------------------
__global__ __launch_bounds__(256) void gemm_bt(
    const __hip_bfloat16* __restrict__ A, const __hip_bfloat16* __restrict__ Bm,
    int M, int N, int K, const float* __restrict__ bias, int epi,
    float* __restrict__ f32out, __hip_bfloat16* __restrict__ bf16out,
    __hip_bfloat16* __restrict__ bf16out2) {
  __shared__ __align__(16) short As[128 * 32];
  __shared__ __align__(16) short Bs[128 * 32];
  const int tid = threadIdx.x;
  const int lane = tid & 63;
  const int wid = tid >> 6;
  const int wr = wid >> 1, wc = wid & 1;

  const int gx = gridDim.x;
  const int nwg = gx * gridDim.y;
  const int wg = blockIdx.y * gx + blockIdx.x;
  const int cpx = nwg >> 3;
  const int swz = (wg & 7) * cpx + (wg >> 3);
  const int bx = swz % gx, by = swz / gx;

  const int m0 = by * 128, n0 = bx * 128;
  const int ldsrow = lane >> 2;
  const int col8 = (lane & 3) * 8;

  f32x4 acc[4][4];
  const f32x4 zero = {0.f, 0.f, 0.f, 0.f};
#pragma unroll
  for (int i = 0; i < 4; ++i)
#pragma unroll
    for (int j = 0; j < 4; ++j) acc[i][j] = zero;

  for (int kt = 0; kt < K; kt += 32) {
#pragma unroll
    for (int i = 0; i < 2; ++i) {
      const int seg = wid * 2 + i;
      gload_lds16(A + (size_t)(m0 + seg * 16 + ldsrow) * K + kt + col8,
                  (void*)(As + seg * 512));
      gload_lds16(Bm + (size_t)(n0 + seg * 16 + ldsrow) * K + kt + col8,
                  (void*)(Bs + seg * 512));
    }
    __syncthreads();
    short8 a[4], b[4];
#pragma unroll
    for (int mf = 0; mf < 4; ++mf)
      a[mf] = *(const short8*)&As[(wr * 64 + mf * 16 + (lane & 15)) * 32 + (lane >> 4) * 8];
#pragma unroll
    for (int nf = 0; nf < 4; ++nf)
      b[nf] = *(const short8*)&Bs[(wc * 64 + nf * 16 + (lane & 15)) * 32 + (lane >> 4) * 8];
#pragma unroll
    for (int mf = 0; mf < 4; ++mf)
#pragma unroll
      for (int nf = 0; nf < 4; ++nf)
        acc[mf][nf] = __builtin_amdgcn_mfma_f32_16x16x32_bf16(a[mf], b[nf], acc[mf][nf], 0, 0, 0);
    __syncthreads();
  }

  const int rbase = (lane >> 4) * 4;
  const int cin = lane & 15;
#pragma unroll
  for (int mf = 0; mf < 4; ++mf) {
#pragma unroll
    for (int nf = 0; nf < 4; ++nf) {
      const int col = n0 + wc * 64 + nf * 16 + cin;
      const float bv = bias[col];
#pragma unroll
      for (int j = 0; j < 4; ++j) {
        const int row = m0 + wr * 64 + mf * 16 + rbase + j;
        const float v = acc[mf][nf][j] + bv;
        const size_t idx = (size_t)row * N + col;
        if (epi == 0) {
          bf16out[idx] = __float2bfloat16(v);
          bf16out2[idx] = __float2bfloat16(v);
        } else {
          f32out[idx] = v;
        }
      }
    }
  }
}

// ---------------------------------------------------------------------------
// Fused: h(bf16) = (1-g)h + g*(sum of 4 bf16 partial slabs + b2 + xe);
// LN stats on fp32 pre-rounding values; write hn (do_ln) or h only (last).
// One block (256 thr) per row of 1024.
// ---------------------------------------------------------------------------
__global__ __launch_bounds__(256) void reduce_ln_kernel(
    const __hip_bfloat16* __restrict__ ps, const float* __restrict__ b2,
    const __hip_bfloat16* __restrict__ xe, __hip_bfloat16* __restrict__ h,
    const float* __restrict__ g, const float* __restrict__ be,
    __hip_bfloat16* __restrict__ outbf, int do_ln) {
  const int row = blockIdx.x, tid = threadIdx.x;
  const size_t base = (size_t)row * DH_;
  const size_t slab = (size_t)B_ * DH_;
  float pv0 = 0.f, pv1 = 0.f, pv2 = 0.f, pv3 = 0.f;
#pragma unroll
  for (int z = 0; z < 4; ++z) {
    const ushort4 q = ((const ushort4*)(ps + z * slab + base))[tid];
    pv0 += bf2f(q.x); pv1 += bf2f(q.y); pv2 += bf2f(q.z); pv3 += bf2f(q.w);
  }
  const ushort4 xq = ((const ushort4*)(xe + base))[tid];
  const ushort4 hq = ((const ushort4*)(h + base))[tid];
  const float4 bv = ((const float4*)b2)[tid];
  float4 nv;
  nv.x = (1.f - GAMMA_) * bf2f(hq.x) + GAMMA_ * (pv0 + bv.x + bf2f(xq.x));
  nv.y = (1.f - GAMMA_) * bf2f(hq.y) + GAMMA_ * (pv1 + bv.y + bf2f(xq.y));
  nv.z = (1.f - GAMMA_) * bf2f(hq.z) + GAMMA_ * (pv2 + bv.z + bf2f(xq.z));
  nv.w = (1.f - GAMMA_) * bf2f(hq.w) + GAMMA_ * (pv3 + bv.w + bf2f(xq.w));
  __hip_bfloat16* hp = h + base + tid * 4;
  hp[0] = __float2bfloat16(nv.x);
  hp[1] = __float2bfloat16(nv.y);
  hp[2] = __float2bfloat16(nv.z);
  hp[3] = __float2bfloat16(nv.w);

  if (!do_ln) return;  // last step: head reads h directly

  float s = nv.x + nv.y + nv.z + nv.w;
  float ss = nv.x * nv.x + nv.y * nv.y + nv.z * nv.z + nv.w * nv.w;
#pragma unroll
  for (int o = 32; o > 0; o >>= 1) {
    s += __shfl_down(s, o, 64);
    ss += __shfl_down(ss, o, 64);
  }
  __shared__ float rs_[4], rss_[4];
  const int lane = tid & 63, wid = tid >> 6;
  if (lane == 0) { rs_[wid] = s; rss_[wid] = ss; }
  __syncthreads();
  const float tot = rs_[0] + rs_[1] + rs_[2] + rs_[3];
  const float tots = rss_[0] + rss_[1] + rss_[2] + rss_[3];
  const float mu = tot * (1.f / DH_);
  const float var = tots * (1.f / DH_) - mu * mu;
  const float rstd = rsqrtf(var + LN_EPS_);
  const float4 gv = ((const float4*)g)[tid];
  const float4 bev = ((const float4*)be)[tid];
  __hip_bfloat16* out = outbf + base + tid * 4;
  out[0] = __float2bfloat16((nv.x - mu) * rstd * gv.x + bev.x);
  out[1] = __float2bfloat16((nv.y - mu) * rstd * gv.y + bev.y);
  out[2] = __float2bfloat16((nv.z - mu) * rstd * gv.z + bev.z);
  out[3] = __float2bfloat16((nv.w - mu) * rstd * gv.w + bev.w);
}

// ---------------------------------------------------------------------------
// LayerNorm + cast (step 0 only): h is bf16.
// ---------------------------------------------------------------------------
__global__ __launch_bounds__(256) void ln_cast_kernel(
    const __hip_bfloat16* __restrict__ h, const float* __restrict__ g,
    const float* __restrict__ be, __hip_bfloat16* __restrict__ hn) {
  const int row = blockIdx.x;
  const int tid = threadIdx.x;
  const ushort4 q = ((const ushort4*)(h + (size_t)row * DH_))[tid];
  const float vx = bf2f(q.x), vy = bf2f(q.y), vz = bf2f(q.z), vw = bf2f(q.w);
  float s = vx + vy + vz + vw;
  float ss = vx * vx + vy * vy + vz * vz + vw * vw;
#pragma unroll
  for (int o = 32; o > 0; o >>= 1) {
    s += __shfl_down(s, o, 64);
    ss += __shfl_down(ss, o, 64);
  }
  __shared__ float rs_[4], rss_[4];
  const int lane = tid & 63, wid = tid >> 6;
  if (lane == 0) { rs_[wid] = s; rss_[wid] = ss; }
  __syncthreads();
  const float tot = rs_[0] + rs_[1] + rs_[2] + rs_[3];
  const float tots = rss_[0] + rss_[1] + rss_[2] + rss_[3];
  const float mu = tot * (1.f / DH_);
  const float var = tots * (1.f / DH_) - mu * mu;
  const float rstd = rsqrtf(var + LN_EPS_);
  const float4 gv = ((const float4*)g)[tid];
  const float4 bv = ((const float4*)be)[tid];
  __hip_bfloat16* out = hn + (size_t)row * DH_ + tid * 4;
  out[0] = __float2bfloat16((vx - mu) * rstd * gv.x + bv.x);
  out[1] = __float2bfloat16((vy - mu) * rstd * gv.y + bv.y);
  out[2] = __float2bfloat16((vz - mu) * rstd * gv.z + bv.z);
  out[3] = __float2bfloat16((vw - mu) * rstd * gv.w + bv.w);
}

// ---------------------------------------------------------------------------
// Paired fp32 matvec (power iteration).
// ---------------------------------------------------------------------------
__global__ __launch_bounds__(256) void matvec2_kernel(
    const float* __restrict__ Wa, const float* __restrict__ xa,
    float* __restrict__ ya, int rowsA, int colsA,
    const float* __restrict__ Wb, const float* __restrict__ xb,
    float* __restrict__ yb, int rowsB, int colsB) {
  const int gw = (int)(blockIdx.x * 256 + threadIdx.x) >> 6;
  const int lane = threadIdx.x & 63;
  const float* W;
  const float* x;
  float* y;
  int row, cols;
  if (gw < rowsA) {
    W = Wa; x = xa; y = ya; row = gw; cols = colsA;
  } else {
    row = gw - rowsA;
    if (row >= rowsB) return;
    W = Wb; x = xb; y = yb; cols = colsB;
  }
  const float4* wr = (const float4*)(W + (size_t)row * cols);
  const float4* xv = (const float4*)x;
  const int n4 = cols >> 2;
  float s = 0.f;
  for (int c = lane; c < n4; c += 64) {
    const float4 wv = wr[c];
    const float4 vv = xv[c];
    s += wv.x * vv.x + wv.y * vv.y + wv.z * vv.z + wv.w * vv.w;
  }
#pragma unroll
  for (int o = 32; o > 0; o >>= 1) s += __shfl_down(s, o, 64);
  if (lane == 0) y[row] = s;
}

__global__ __launch_bounds__(256) void transpose_kernel(
    const float* __restrict__ in, float* __restrict__ out, int R, int C) {
  __shared__ float t[32][33];
  const int lx = threadIdx.x & 31, ly = threadIdx.x >> 5;
  const int r0 = blockIdx.y * 32, c0 = blockIdx.x * 32;
#pragma unroll
  for (int j = 0; j < 32; j += 8) t[ly + j][lx] = in[(size_t)(r0 + ly + j) * C + c0 + lx];
  __syncthreads();
#pragma unroll
  for (int j = 0; j < 32; j += 8) out[(size_t)(c0 + ly + j) * R + r0 + lx] = t[lx][ly + j];
}

__global__ void init_v_kernel(float* v1, float* v2) {
  const int i = blockIdx.x * 256 + threadIdx.x;
  if (i < 1024) v1[i] = 0.03125f;
  if (i < 4096) v2[i] = 0.015625f;
}

__global__ __launch_bounds__(256) void cast_kernel(
    const float* __restrict__ s, __hip_bfloat16* __restrict__ d, int n) {
  const int b = (blockIdx.x * 256 + threadIdx.x) * 4;
  if (b < n) {
    const float4 v = *(const float4*)(s + b);
    d[b] = __float2bfloat16(v.x);
    d[b + 1] = __float2bfloat16(v.y);
    d[b + 2] = __float2bfloat16(v.z);
    d[b + 3] = __float2bfloat16(v.w);
  }
}

__global__ __launch_bounds__(256) void cast_scaled_kernel(
    const float* __restrict__ s, __hip_bfloat16* __restrict__ d, int n,
    const float* __restrict__ rs) {
  const float r = rs[0];
  const int b = (blockIdx.x * 256 + threadIdx.x) * 4;
  if (b < n) {
    const float4 v = *(const float4*)(s + b);
    d[b] = __float2bfloat16(v.x * r);
    d[b + 1] = __float2bfloat16(v.y * r);
    d[b + 2] = __float2bfloat16(v.z * r);
    d[b + 3] = __float2bfloat16(v.w * r);
  }
}

// rs = |c| / |d|  (= 1/sigma)
__global__ __launch_bounds__(256) void sigma_rs_kernel(
    const float* __restrict__ c, int m, const float* __restrict__ dv, int n,
    float* __restrict__ rs) {
  const int tid = threadIdx.x;
  float sc = 0.f, sd = 0.f;
  for (int i = tid; i < m; i += 256) { const float v = c[i]; sc += v * v; }
  for (int i = tid; i < n; i += 256) { const float v = dv[i]; sd += v * v; }
#pragma unroll
  for (int o = 32; o > 0; o >>= 1) {
    sc += __shfl_down(sc, o, 64);
    sd += __shfl_down(sd, o, 64);
  }
  __shared__ float a[4], b[4];
  const int lane = tid & 63, wid = tid >> 6;
  if (lane == 0) { a[wid] = sc; b[wid] = sd; }
  __syncthreads();
  if (tid == 0) {
    const float tc = a[0] + a[1] + a[2] + a[3];
    const float td = b[0] + b[1] + b[2] + b[3];
    rs[0] = sqrtf(tc / td);
  }
}

extern "C" void kernel_launch(void* const* d_in, const int* in_sizes, int n_in,
                              void* d_out, int out_size, void* d_ws, size_t ws_size,
                              hipStream_t stream) {
  const float* x       = (const float*)d_in[0];
  const float* embed_w = (const float*)d_in[1];
  const float* embed_b = (const float*)d_in[2];
  const float* W1      = (const float*)d_in[3];
  const float* b1      = (const float*)d_in[4];
  const float* W2      = (const float*)d_in[5];
  const float* b2      = (const float*)d_in[6];
  const float* ln_g    = (const float*)d_in[7];
  const float* ln_b    = (const float*)d_in[8];
  const float* head_w  = (const float*)d_in[9];
  const float* head_b  = (const float*)d_in[10];
  float* out = (float*)d_out;

  char* p = (char*)d_ws;
  auto carve = [&](size_t bytes) {
    char* r = p;
    p += (bytes + 255) & ~(size_t)255;
    return (void*)r;
  };
  // W1T/W2T (33.6 MB) are dead after the power iteration; the 4 bf16 K-split
  // partial slabs (4 x 8.4 MB = 33.6 MB) alias this region during the steps.
  float* W1T   = (float*)carve((size_t)DFF_ * DH_ * 4);
  float* W2T   = (float*)carve((size_t)DH_ * DFF_ * 4);
  __hip_bfloat16* ps = (__hip_bfloat16*)W1T;  // [4][B_][DH_] bf16
  __hip_bfloat16* h    = (__hip_bfloat16*)carve((size_t)B_ * DH_ * 2);
  __hip_bfloat16* xebf = (__hip_bfloat16*)carve((size_t)B_ * DH_ * 2);
  __hip_bfloat16* hn   = (__hip_bfloat16*)carve((size_t)B_ * DH_ * 2);
  __hip_bfloat16* hid  = (__hip_bfloat16*)carve((size_t)B_ * DFF_ * 2);
  __hip_bfloat16* W1n  = (__hip_bfloat16*)carve((size_t)DFF_ * DH_ * 2);
  __hip_bfloat16* W2n  = (__hip_bfloat16*)carve((size_t)DH_ * DFF_ * 2);
  __hip_bfloat16* xbf  = (__hip_bfloat16*)carve((size_t)B_ * DIN_ * 2);
  __hip_bfloat16* ewbf = (__hip_bfloat16*)carve((size_t)DH_ * DIN_ * 2);
  __hip_bfloat16* hwbf = (__hip_bfloat16*)carve((size_t)DOUT_ * DH_ * 2);
  float* v1a = (float*)carve(4096 * 4);
  float* v1b = (float*)carve(4096 * 4);
  float* c1  = (float*)carve(4096 * 4);
  float* v2a = (float*)carve(4096 * 4);
  float* v2b = (float*)carve(4096 * 4);
  float* c2  = (float*)carve(4096 * 4);
  float* rs1 = (float*)carve(256);
  float* rs2 = (float*)carve(256);

  // --- prep: transposes, inits, input casts ---
  transpose_kernel<<<dim3(DH_ / 32, DFF_ / 32), 256, 0, stream>>>(W1, W1T, DFF_, DH_);
  transpose_kernel<<<dim3(DFF_ / 32, DH_ / 32), 256, 0, stream>>>(W2, W2T, DH_, DFF_);
  init_v_kernel<<<16, 256, 0, stream>>>(v1a, v2a);
  cast_kernel<<<(B_ * DIN_ / 4) / 256, 256, 0, stream>>>(x, xbf, B_ * DIN_);
  cast_kernel<<<(DH_ * DIN_ / 4) / 256, 256, 0, stream>>>(embed_w, ewbf, DH_ * DIN_);
  cast_kernel<<<(DOUT_ * DH_ / 4) / 256, 256, 0, stream>>>(head_w, hwbf, DOUT_ * DH_);

  // --- x_emb = x @ embed_w^T + embed_b ; xebf = h = bf16(x_emb) ---
  gemm_bt<<<dim3(DH_ / 128, B_ / 128), 256, 0, stream>>>(
      xbf, ewbf, B_, DH_, DIN_, embed_b, 0, nullptr, xebf, h);

  // --- power iteration (unnormalized), W1 & W2 paired ---
  for (int it = 0; it < 15; ++it) {
    const float* vin1 = (it & 1) ? v1b : v1a;
    float* vout1 = (it & 1) ? v1a : v1b;
    const float* vin2 = (it & 1) ? v2b : v2a;
    float* vout2 = (it & 1) ? v2a : v2b;
    matvec2_kernel<<<((DFF_ + DH_) * 64) / 256, 256, 0, stream>>>(
        W1, vin1, c1, DFF_, DH_, W2, vin2, c2, DH_, DFF_);
    matvec2_kernel<<<((DH_ + DFF_) * 64) / 256, 256, 0, stream>>>(
        W1T, c1, vout1, DH_, DFF_, W2T, c2, vout2, DFF_, DH_);
  }
  sigma_rs_kernel<<<1, 256, 0, stream>>>(c1, DFF_, v1b, DH_, rs1);
  sigma_rs_kernel<<<1, 256, 0, stream>>>(c2, DH_, v2b, DFF_, rs2);
  cast_scaled_kernel<<<(DFF_ * DH_ / 4) / 256, 256, 0, stream>>>(W1, W1n, DFF_ * DH_, rs1);
  cast_scaled_kernel<<<(DH_ * DFF_ / 4) / 256, 256, 0, stream>>>(W2, W2n, DH_ * DFF_, rs2);
  // (W1T/W2T dead from here; ps aliases them)

  // --- step 0 LN (h == x_emb) ---
  ln_cast_kernel<<<B_, 256, 0, stream>>>(h, ln_g, ln_b, hn);

  // --- 30 equilibrium steps ---
  for (int s = 0; s < STEPS_; ++s) {
    // hid = tanh(hn @ W1n^T + b1)   [4096 x 4096, K=1024, nt=16]
    gemm256<<<dim3(DFF_ / 256, B_ / 256, 1), 512, 0, stream>>>(
        hn, W1n, B_, DFF_, DH_, DH_, DH_ / 64, b1, 1, hid);
    // ps[z] = hid @ W2n^T (K-chunk z) [4096 x 1024, K=4096, split 4, nt=16]
    gemm256<<<dim3(DH_ / 256, B_ / 256, 4), 512, 0, stream>>>(
        hid, W2n, B_, DH_, DFF_, DFF_ / 4, DFF_ / 4 / 64, nullptr, 4, ps);
    const int last = (s == STEPS_ - 1);
    reduce_ln_kernel<<<B_, 256, 0, stream>>>(
        ps, b2, xebf, h, ln_g, ln_b, hn, last ? 0 : 1);
  }

  // --- head: out = h @ head_w^T + head_b (h is bf16 state) ---
  gemm_bt<<<dim3(DOUT_ / 128, B_ / 128), 256, 0, stream>>>(
      h, hwbf, B_, DOUT_, DH_, head_b, 3, out, nullptr, nullptr);
}